// Round 6
// baseline (1203.366 us; speedup 1.0000x reference)
//
#include <hip/hip_runtime.h>
#include <math.h>

// ---------------- problem constants ----------------
#define NUSERS   100000
#define NITEMS   100000
#define NNODES   200000
#define DD       64
#define NI       128
#define E_UI     1000000
#define E_MP     500000
#define BB       4096
#define NSTRIP   6250          // 100000 / 16

// ---------------- workspace layout (float/int elements, 4B each) ----------------
#define O_CNT       0LL
#define O_OUTCNT    600000LL
#define O_CURSOR    1000000LL
#define O_PARTIALS  1600000LL   // 25000 used (4 graphs x 6250 strips)
#define O_UITB_U    1625600LL   // 4096 f32 slots = 8192 bf16 (UI^T j-major)
#define O_UITB_I    1629696LL
#define O_UIB_U     1633792LL   // 4096 (UI d-major)
#define O_UIB_I     1637888LL
#define O_W1B_U     1641984LL   // 4096 (W1^T j-major)
#define O_W1B_I     1646080LL
#define O_SUMEXP    1700000LL
#define O_POS       1708192LL
#define ZEND        1716384LL
#define O_OFF       1716384LL
#define O_BSUM      2316448LL
#define O_DINV      2317472LL
#define O_OINV      2517472LL
#define O_IINV      2917472LL
#define O_ADJ       3317472LL
#define O_WSUM      7317472LL
#define O_EMBA      7317480LL   // 12.8M: layer ping; reused as zbuf for mp graphs 0,1
#define O_TOTAL     20117480LL
#define O_EMBB      32917480LL  // 12.8M: layer pong; reused as zbuf for mp graphs 2,3
#define O_E1U       45717480LL  // stored as bf16 shorts
#define O_E2U       45979624LL
#define O_E1I       46241768LL
#define O_E2I       46503912LL

typedef __attribute__((ext_vector_type(8))) short short8;
typedef __attribute__((ext_vector_type(4))) float f32x4;

__device__ __forceinline__ short f2bf(float x) {
  unsigned u = __float_as_uint(x);
  unsigned r = (u + 0x7FFFu + ((u >> 16) & 1u)) >> 16;
  return (short)r;
}

// ---------------- degree histograms ----------------
__global__ void k_hist_main(const int* __restrict__ src, const int* __restrict__ dst,
                            int* __restrict__ cnt) {
  int e = blockIdx.x * 256 + threadIdx.x;
  if (e < E_UI) {
    atomicAdd(&cnt[src[e]], 1);
    atomicAdd(&cnt[NUSERS + dst[e]], 1);
  }
}

__global__ void k_hist_mp(const int* __restrict__ mpu, const int* __restrict__ mpi,
                          int* __restrict__ cnt, int* __restrict__ outcnt) {
  int e = blockIdx.x * 256 + threadIdx.x;
  int g = blockIdx.y;
  if (e < E_MP) {
    const int* base = (g < 2) ? (mpu + (long long)g * 2 * E_MP)
                              : (mpi + (long long)(g - 2) * 2 * E_MP);
    int s = base[e];
    int d = base[E_MP + e];
    atomicAdd(&outcnt[g * NUSERS + s], 1);
    atomicAdd(&cnt[NNODES + g * NUSERS + d], 1);
  }
}

// ---------------- exclusive scan ----------------
__global__ __launch_bounds__(1024) void k_scan1(const int* __restrict__ in, int* __restrict__ out,
                                                int* __restrict__ bsum, int n) {
  __shared__ int s[1024];
  int i = blockIdx.x * 1024 + threadIdx.x;
  int v = (i < n) ? in[i] : 0;
  s[threadIdx.x] = v;
  __syncthreads();
  for (int off = 1; off < 1024; off <<= 1) {
    int x = (threadIdx.x >= off) ? s[threadIdx.x - off] : 0;
    __syncthreads();
    s[threadIdx.x] += x;
    __syncthreads();
  }
  if (i < n) out[i] = s[threadIdx.x] - v;
  if (threadIdx.x == 1023) bsum[blockIdx.x] = s[1023];
}

__global__ __launch_bounds__(1024) void k_scan2(int* __restrict__ bsum, int nb) {
  __shared__ int s[1024];
  int v = (threadIdx.x < nb) ? bsum[threadIdx.x] : 0;
  s[threadIdx.x] = v;
  __syncthreads();
  for (int off = 1; off < 1024; off <<= 1) {
    int x = (threadIdx.x >= off) ? s[threadIdx.x - off] : 0;
    __syncthreads();
    s[threadIdx.x] += x;
    __syncthreads();
  }
  if (threadIdx.x < nb) bsum[threadIdx.x] = s[threadIdx.x] - v;
}

__global__ __launch_bounds__(1024) void k_scan3(int* __restrict__ out, const int* __restrict__ bsum, int n) {
  int i = blockIdx.x * 1024 + threadIdx.x;
  if (i < n) out[i] += bsum[blockIdx.x];
}

// ---------------- inverse-sqrt degrees ----------------
__global__ void k_inv(const int* __restrict__ cnt, const int* __restrict__ outcnt,
                      float* __restrict__ dinv, float* __restrict__ iinv, float* __restrict__ oinv) {
  int i = blockIdx.x * 256 + threadIdx.x;
  if (i < NNODES) {
    int c = cnt[i]; if (c < 1) c = 1;
    dinv[i] = 1.0f / sqrtf((float)c);
  } else if (i < 600000) {
    int c = cnt[i]; if (c < 1) c = 1;
    iinv[i - NNODES] = 1.0f / sqrtf((float)c);
  }
  if (i < 400000) {
    int c = outcnt[i]; if (c < 1) c = 1;
    oinv[i] = 1.0f / sqrtf((float)c);
  }
}

// ---------------- CSR scatter ----------------
__global__ void k_scatter_main(const int* __restrict__ src, const int* __restrict__ dst,
                               const int* __restrict__ off, int* __restrict__ cursor,
                               int* __restrict__ adj) {
  int e = blockIdx.x * 256 + threadIdx.x;
  if (e < E_UI) {
    int u = src[e];
    int it = NUSERS + dst[e];
    int p = atomicAdd(&cursor[u], 1);
    adj[off[u] + p] = it;
    int q = atomicAdd(&cursor[it], 1);
    adj[off[it] + q] = u;
  }
}

__global__ void k_scatter_mp(const int* __restrict__ mpu, const int* __restrict__ mpi,
                             const int* __restrict__ off, int* __restrict__ cursor,
                             int* __restrict__ adj) {
  int e = blockIdx.x * 256 + threadIdx.x;
  int g = blockIdx.y;
  if (e < E_MP) {
    const int* base = (g < 2) ? (mpu + (long long)g * 2 * E_MP)
                              : (mpi + (long long)(g - 2) * 2 * E_MP);
    int s = base[e];
    int d = base[E_MP + e];
    int node = NNODES + g * NUSERS + d;
    int p = atomicAdd(&cursor[node], 1);
    adj[off[node] + p] = s;
  }
}

// ---------------- emb init ----------------
__global__ void k_init(const float4* __restrict__ uf, const float4* __restrict__ itf,
                       float4* __restrict__ emb) {
  int i = blockIdx.x * 256 + threadIdx.x;
  if (i < 3200000) {
    emb[i] = (i < 1600000) ? uf[i] : itf[i - 1600000];
  }
}

// ---------------- weight prep (bf16 variants) ----------------
__global__ void k_tw(const float* __restrict__ UIu, const float* __restrict__ UIi,
                     const float* __restrict__ W1u, const float* __restrict__ W1i,
                     short* __restrict__ UITBu, short* __restrict__ UITBi,
                     short* __restrict__ UIBu,  short* __restrict__ UIBi,
                     short* __restrict__ W1Bu,  short* __restrict__ W1Bi) {
  int t = blockIdx.x * 256 + threadIdx.x;
  if (t < 8192) {
    int d = t >> 7, j = t & 127;
    UITBu[j * 64 + d] = f2bf(UIu[t]);
    UITBi[j * 64 + d] = f2bf(UIi[t]);
    UIBu[t] = f2bf(UIu[t]);
    UIBi[t] = f2bf(UIi[t]);
    W1Bu[j * 64 + d] = f2bf(W1u[t]);
    W1Bi[j * 64 + d] = f2bf(W1i[t]);
  }
}

// ---------------- 8-row accumulate via readlane (wave-uniform broadcast -> SGPR base) ----------------
// Best for deg ~10 full-wave rows (k_layer): scalar-base loads, no LDS-pipe bpermute on
// the address path. [R0/R2: 189-193 us; shfl/float4 form regressed to 219.]
// Runtime-rem version (fallback for deg > 24).
__device__ __forceinline__ float acc8(const float* __restrict__ tbl, int miv, float mwv,
                                      int rem, int lane, float acc) {
  unsigned wb = __float_as_uint(mwv);
  for (int k = 0; k < rem; k += 8) {
    int n0 = __builtin_amdgcn_readlane(miv, k + 0);
    int n1 = __builtin_amdgcn_readlane(miv, k + 1);
    int n2 = __builtin_amdgcn_readlane(miv, k + 2);
    int n3 = __builtin_amdgcn_readlane(miv, k + 3);
    int n4 = __builtin_amdgcn_readlane(miv, k + 4);
    int n5 = __builtin_amdgcn_readlane(miv, k + 5);
    int n6 = __builtin_amdgcn_readlane(miv, k + 6);
    int n7 = __builtin_amdgcn_readlane(miv, k + 7);
    float w0 = __uint_as_float(__builtin_amdgcn_readlane(wb, k + 0));
    float w1 = __uint_as_float(__builtin_amdgcn_readlane(wb, k + 1));
    float w2 = __uint_as_float(__builtin_amdgcn_readlane(wb, k + 2));
    float w3 = __uint_as_float(__builtin_amdgcn_readlane(wb, k + 3));
    float w4 = __uint_as_float(__builtin_amdgcn_readlane(wb, k + 4));
    float w5 = __uint_as_float(__builtin_amdgcn_readlane(wb, k + 5));
    float w6 = __uint_as_float(__builtin_amdgcn_readlane(wb, k + 6));
    float w7 = __uint_as_float(__builtin_amdgcn_readlane(wb, k + 7));
    float v0 = tbl[((long long)n0 << 6) + lane], v1 = tbl[((long long)n1 << 6) + lane];
    float v2 = tbl[((long long)n2 << 6) + lane], v3 = tbl[((long long)n3 << 6) + lane];
    float v4 = tbl[((long long)n4 << 6) + lane], v5 = tbl[((long long)n5 << 6) + lane];
    float v6 = tbl[((long long)n6 << 6) + lane], v7 = tbl[((long long)n7 << 6) + lane];
    acc += w0 * v0; acc += w1 * v1; acc += w2 * v2; acc += w3 * v3;
    acc += w4 * v4; acc += w5 * v5; acc += w6 * v6; acc += w7 * v7;
  }
  return acc;
}

// Fixed-trip straight-line version: all R loads issue back-to-back (no runtime loop
// boundary). Padded lanes carry mi=0/mw=0 -> exact +0 adds, order identical.
template <int R>
__device__ __forceinline__ float acc8f(const float* __restrict__ tbl, int miv, float mwv,
                                       int lane) {
  unsigned wb = __float_as_uint(mwv);
  float acc = 0.0f;
#pragma unroll
  for (int k = 0; k < R; k += 8) {
    int n0 = __builtin_amdgcn_readlane(miv, k + 0);
    int n1 = __builtin_amdgcn_readlane(miv, k + 1);
    int n2 = __builtin_amdgcn_readlane(miv, k + 2);
    int n3 = __builtin_amdgcn_readlane(miv, k + 3);
    int n4 = __builtin_amdgcn_readlane(miv, k + 4);
    int n5 = __builtin_amdgcn_readlane(miv, k + 5);
    int n6 = __builtin_amdgcn_readlane(miv, k + 6);
    int n7 = __builtin_amdgcn_readlane(miv, k + 7);
    float w0 = __uint_as_float(__builtin_amdgcn_readlane(wb, k + 0));
    float w1 = __uint_as_float(__builtin_amdgcn_readlane(wb, k + 1));
    float w2 = __uint_as_float(__builtin_amdgcn_readlane(wb, k + 2));
    float w3 = __uint_as_float(__builtin_amdgcn_readlane(wb, k + 3));
    float w4 = __uint_as_float(__builtin_amdgcn_readlane(wb, k + 4));
    float w5 = __uint_as_float(__builtin_amdgcn_readlane(wb, k + 5));
    float w6 = __uint_as_float(__builtin_amdgcn_readlane(wb, k + 6));
    float w7 = __uint_as_float(__builtin_amdgcn_readlane(wb, k + 7));
    float v0 = tbl[((long long)n0 << 6) + lane], v1 = tbl[((long long)n1 << 6) + lane];
    float v2 = tbl[((long long)n2 << 6) + lane], v3 = tbl[((long long)n3 << 6) + lane];
    float v4 = tbl[((long long)n4 << 6) + lane], v5 = tbl[((long long)n5 << 6) + lane];
    float v6 = tbl[((long long)n6 << 6) + lane], v7 = tbl[((long long)n7 << 6) + lane];
    acc += w0 * v0; acc += w1 * v1; acc += w2 * v2; acc += w3 * v3;
    acc += w4 * v4; acc += w5 * v5; acc += w6 * v6; acc += w7 * v7;
  }
  return acc;
}

// tail for degree > 64 (rare)
__device__ __forceinline__ float gather_tail(const float* __restrict__ tbl,
                                             const int* __restrict__ adj,
                                             int start, int c,
                                             const float* __restrict__ warr, int wofs,
                                             int lane, float acc) {
  for (int kb = 64; kb < c; kb += 64) {
    int rem = c - kb; if (rem > 64) rem = 64;
    int ti = 0; float tw = 0.0f;
    if (lane < rem) { ti = adj[start + kb + lane]; tw = warr[wofs + ti]; }
    acc = acc8(tbl, ti, tw, rem, lane, acc);
  }
  return acc;
}

// Tiered dispatch: wave-uniform scalar branch to straight-line bodies.
// Poisson(10): P(c<=8)=0.33, P(<=16)=0.97, P(<=24)=0.9996.
__device__ __forceinline__ float gather_node(const float* __restrict__ tbl,
                                             const int* __restrict__ adj,
                                             int ofs, int c, int miv, float mwv,
                                             const float* __restrict__ warr, int wofs,
                                             int lane) {
  if (c <= 8)  return acc8f<8>(tbl, miv, mwv, lane);
  if (c <= 16) return acc8f<16>(tbl, miv, mwv, lane);
  if (c <= 24) return acc8f<24>(tbl, miv, mwv, lane);
  int rem = c < 64 ? c : 64;
  float acc = acc8(tbl, miv, mwv, rem, lane, 0.0f);
  if (c > 64) acc = gather_tail(tbl, adj, ofs, c, warr, wofs, lane, acc);
  return acc;
}

// ---------------- float4 group gather (16-lane group owns a row, lane loads 16B) ----------------
// Best for deg ~5 overhead-bound gathers (k_mp_gather). [R1: -65 us @ 4 nodes/wave;
// R2: 8 nodes/wave regressed -> keep 4.] Runtime-rem fallback.
__device__ __forceinline__ void acc4x(const float* __restrict__ tbl, int miv, float mwv,
                                      int rem, int grp, int dq, f32x4& acc) {
  for (int k = 0; k < rem; k += 16) {
    int s0 = k + grp, s1 = k + 4 + grp, s2 = k + 8 + grp, s3 = k + 12 + grp;
    int n0 = __shfl(miv, s0), n1 = __shfl(miv, s1);
    int n2 = __shfl(miv, s2), n3 = __shfl(miv, s3);
    float w0 = __shfl(mwv, s0), w1 = __shfl(mwv, s1);
    float w2 = __shfl(mwv, s2), w3 = __shfl(mwv, s3);
    float4 v0 = *(const float4*)(tbl + ((long long)n0 << 6) + dq);
    float4 v1 = *(const float4*)(tbl + ((long long)n1 << 6) + dq);
    float4 v2 = *(const float4*)(tbl + ((long long)n2 << 6) + dq);
    float4 v3 = *(const float4*)(tbl + ((long long)n3 << 6) + dq);
    acc.x += w0 * v0.x; acc.y += w0 * v0.y; acc.z += w0 * v0.z; acc.w += w0 * v0.w;
    acc.x += w1 * v1.x; acc.y += w1 * v1.y; acc.z += w1 * v1.z; acc.w += w1 * v1.w;
    acc.x += w2 * v2.x; acc.y += w2 * v2.y; acc.z += w2 * v2.z; acc.w += w2 * v2.w;
    acc.x += w3 * v3.x; acc.y += w3 * v3.y; acc.z += w3 * v3.z; acc.w += w3 * v3.w;
  }
}

__device__ __forceinline__ void gather_tail4(const float* __restrict__ tbl,
                                             const int* __restrict__ adj,
                                             int start, int c,
                                             const float* __restrict__ warr, int wofs,
                                             int lane, int grp, int dq, f32x4& acc) {
  for (int kb = 64; kb < c; kb += 64) {
    int rem = c - kb; if (rem > 64) rem = 64;
    int ti = 0; float tw = 0.0f;
    if (lane < rem) { ti = adj[start + kb + lane]; tw = warr[wofs + ti]; }
    acc4x(tbl, ti, tw, rem, grp, dq, acc);
  }
}

__device__ __forceinline__ float bcastf(float x) {
  return __uint_as_float(__builtin_amdgcn_readfirstlane(__float_as_uint(x)));
}

// ---------------- fused layer: MFMA intent attention + spmm + residual + total ----------------
// Block = 2 waves; wave = one 16-node strip (16 | 100000 so strips never straddle sides).
// KEY (R5): attention runs FIRST (sP in LDS, output O kept in registers), then the SAME
// 4352B buffer is reused as sZ for the gather, then combine. LDS/wave halves 8704->4352B
// -> occupancy cap moves from 18 waves (56%) to 28 waves (87%, launch_bounds(128,7)).
// Gather metadata/edges are prefetched before the attention so their HBM latency hides
// under the MFMA/exp work. Bit-exact reorder of R4's arithmetic.
__global__ __launch_bounds__(128, 7) void k_layer(
    const float* __restrict__ ecur, float* __restrict__ enext, float* __restrict__ total,
    const int* __restrict__ adj, const int* __restrict__ off, const int* __restrict__ cnt,
    const float* __restrict__ dinv,
    const short* __restrict__ UITBu, const short* __restrict__ UITBi,
    const short* __restrict__ UIBu,  const short* __restrict__ UIBi, int layer) {
  __shared__ float sBuf[2][16 * 68];   // 4352 B/wave: bf16 P (stride 136 shorts) then f32 Z (stride 68)
  int w = threadIdx.x >> 6, lane = threadIdx.x & 63;
  int nb = blockIdx.x * 32 + w * 16;
  const short* UITB = (nb < NUSERS) ? UITBu : UITBi;
  const short* UIB  = (nb < NUSERS) ? UIBu  : UIBi;
  float* rowZ = sBuf[w];
  short* rowP = (short*)sBuf[w];
  int quad = lane >> 4, mrow = lane & 15;

  // ---- phase-1 row loads issued FIRST (phase 1 waits only on these, vmcnt-ordered) ----
  const float* vrow = ecur + (((long long)(nb + mrow)) << 6) + quad * 8;
  float4 va0 = *(const float4*)(vrow);
  float4 va1 = *(const float4*)(vrow + 4);
  float4 vc0 = *(const float4*)(vrow + 32);
  float4 vc1 = *(const float4*)(vrow + 36);

  // ---- gather metadata + edge prefetch (in flight across the attention phases) ----
  int ofs[16], cns[16];
  float dn[16];
  int mi[16]; float mw[16];
#pragma unroll
  for (int m = 0; m < 16; m++) {
    ofs[m] = __builtin_amdgcn_readfirstlane(off[nb + m]);
    cns[m] = __builtin_amdgcn_readfirstlane(cnt[nb + m]);
    dn[m]  = bcastf(dinv[nb + m]);
  }
#pragma unroll
  for (int m = 0; m < 16; m++)
    mi[m] = (lane < cns[m]) ? adj[ofs[m] + lane] : 0;
#pragma unroll
  for (int m = 0; m < 16; m++)
    mw[m] = (lane < cns[m]) ? dinv[mi[m]] : 0.0f;

  short8 a0 = { f2bf(va0.x), f2bf(va0.y), f2bf(va0.z), f2bf(va0.w),
                f2bf(va1.x), f2bf(va1.y), f2bf(va1.z), f2bf(va1.w) };
  short8 a1 = { f2bf(vc0.x), f2bf(vc0.y), f2bf(vc0.z), f2bf(vc0.w),
                f2bf(vc1.x), f2bf(vc1.y), f2bf(vc1.z), f2bf(vc1.w) };

  // ---- phase 1: S = v @ UI ; P = exp(S) -> sP (bf16) ; den per node ----
  float den0 = 0.f, den1 = 0.f, den2 = 0.f, den3 = 0.f;
  short* pw = rowP + (quad * 4) * 136 + mrow;
#pragma unroll
  for (int jt = 0; jt < 8; jt++) {
    const short* wr = UITB + ((jt * 16 + mrow) << 6) + quad * 8;
    short8 b0 = *(const short8*)(wr);
    short8 bh = *(const short8*)(wr + 32);
    f32x4 acc = {0.f, 0.f, 0.f, 0.f};
    acc = __builtin_amdgcn_mfma_f32_16x16x32_bf16(a0, b0, acc, 0, 0, 0);
    acc = __builtin_amdgcn_mfma_f32_16x16x32_bf16(a1, bh, acc, 0, 0, 0);
    float e0 = __expf(acc[0]), e1 = __expf(acc[1]);
    float e2 = __expf(acc[2]), e3 = __expf(acc[3]);
    den0 += e0; den1 += e1; den2 += e2; den3 += e3;
    short* pj = pw + jt * 16;
    pj[0] = f2bf(e0); pj[136] = f2bf(e1); pj[272] = f2bf(e2); pj[408] = f2bf(e3);
  }
  for (int mask = 1; mask <= 8; mask <<= 1) {
    den0 += __shfl_xor(den0, mask); den1 += __shfl_xor(den1, mask);
    den2 += __shfl_xor(den2, mask); den3 += __shfl_xor(den3, mask);
  }
  float rd0 = 1.f / den0, rd1 = 1.f / den1, rd2 = 1.f / den2, rd3 = 1.f / den3;

  // ---- phase 2: O = P @ UI^T (K=128) -> registers ----
  f32x4 accs[4];
#pragma unroll
  for (int dt = 0; dt < 4; dt++) {
    f32x4 acc = {0.f, 0.f, 0.f, 0.f};
#pragma unroll
    for (int c = 0; c < 4; c++) {
      const short* pr = rowP + mrow * 136 + c * 32 + quad * 8;
      short8 af = *(const short8*)(pr);
      const short* br = UIB + ((dt * 16 + mrow) << 7) + c * 32 + quad * 8;
      short8 bf = *(const short8*)(br);
      acc = __builtin_amdgcn_mfma_f32_16x16x32_bf16(af, bf, acc, 0, 0, 0);
    }
    accs[dt] = acc;
  }

  __syncthreads();   // drain sP reads before the buffer is overwritten as sZ

  // ---- gather: gnn rows -> sZ (reused buffer), tiered straight-line bodies ----
#pragma unroll
  for (int m = 0; m < 16; m++) {
    float acc = gather_node(ecur, adj, ofs[m], cns[m], mi[m], mw[m], dinv, 0, lane);
    rowZ[m * 68 + lane] = dn[m] * acc;
  }

  // ---- combine + store ----
#pragma unroll
  for (int dt = 0; dt < 4; dt++) {
    int d = dt * 16 + mrow;
#define COMB(r, rd)                                                            \
    { int node = nb + quad * 4 + r;                                            \
      long long base = (((long long)node) << 6) + d;                           \
      float o = accs[dt][r] * rd;                                              \
      float gn = rowZ[(quad * 4 + r) * 68 + d];                                \
      float vv = ecur[base];                                                   \
      float ne = gn + o + vv;                                                  \
      enext[base] = ne;                                                        \
      total[base] = (layer == 0) ? (vv + ne) : (total[base] + ne); }
    COMB(0, rd0) COMB(1, rd1) COMB(2, rd2) COMB(3, rd3)
#undef COMB
  }
}

// ---------------- metapath graphconv gather: z (x iinv) -> zbuf ----------------
// 4 nodes per wave, float4 group-gather; fixed-16 straight-line fast path
// (Poisson(5): P(c<=16)=0.9998). launch_bounds (256,8): 32-wave ceiling (was 24).
__global__ __launch_bounds__(256, 8) void k_mp_gather(
    const float* __restrict__ uf, const float* __restrict__ itf,
    const int* __restrict__ adj, const int* __restrict__ off, const int* __restrict__ cnt,
    const float* __restrict__ oinv, const float* __restrict__ iinv,
    float* __restrict__ zu, float* __restrict__ zi) {
  int g = blockIdx.y;
  const float* feat = (g < 2) ? uf : itf;
  float* zb = (g < 2) ? zu + ((long long)g * NUSERS << 6)
                      : zi + ((long long)(g - 2) * NUSERS << 6);
  int w = threadIdx.x >> 6, lane = threadIdx.x & 63;
  int n0 = (blockIdx.x * 4 + w) * 4;
  int gofs = g * NUSERS;
  int grp = lane >> 4, dq = (lane & 15) << 2;
  int ofs[4], cns[4];
  float iv[4];
  int mi[4]; float mw[4];
#pragma unroll
  for (int m = 0; m < 4; m++) {
    int node = NNODES + gofs + n0 + m;
    ofs[m] = __builtin_amdgcn_readfirstlane(off[node]);
    cns[m] = __builtin_amdgcn_readfirstlane(cnt[node]);
    iv[m]  = bcastf(iinv[gofs + n0 + m]);
  }
#pragma unroll
  for (int m = 0; m < 4; m++)
    mi[m] = (lane < cns[m]) ? adj[ofs[m] + lane] : 0;
#pragma unroll
  for (int m = 0; m < 4; m++)
    mw[m] = (lane < cns[m]) ? oinv[gofs + mi[m]] : 0.0f;
#pragma unroll
  for (int m = 0; m < 4; m++) {
    int c = cns[m];
    f32x4 acc = {0.f, 0.f, 0.f, 0.f};
    if (c <= 16) {
      acc4x(feat, mi[m], mw[m], 16, grp, dq, acc);   // compile-time trip -> unrolled
    } else {
      int rem = c < 64 ? c : 64;
      acc4x(feat, mi[m], mw[m], rem, grp, dq, acc);
      if (c > 64) gather_tail4(feat, adj, ofs[m], c, oinv, gofs, lane, grp, dq, acc);
    }
    acc.x += __shfl_xor(acc.x, 16); acc.y += __shfl_xor(acc.y, 16);
    acc.z += __shfl_xor(acc.z, 16); acc.w += __shfl_xor(acc.w, 16);
    acc.x += __shfl_xor(acc.x, 32); acc.y += __shfl_xor(acc.y, 32);
    acc.z += __shfl_xor(acc.z, 32); acc.w += __shfl_xor(acc.w, 32);
    if (lane < 16) {
      float s = iv[m];
      float4 o = { acc.x * s, acc.y * s, acc.z * s, acc.w * s };
      *(float4*)&zb[((long long)(n0 + m) << 6) + dq] = o;
    }
  }
}

// ---------------- metapath MLP score via MFMA ----------------
__global__ __launch_bounds__(256, 4) void k_mp_mlp(
    const float* __restrict__ zu, const float* __restrict__ zi,
    const short* __restrict__ W1Bu, const float* __restrict__ b1u, const float* __restrict__ w2u,
    const short* __restrict__ W1Bi, const float* __restrict__ b1i, const float* __restrict__ w2i,
    float* __restrict__ partials) {
  int g = blockIdx.y;
  const short* W1B = (g < 2) ? W1Bu : W1Bi;
  const float* b1  = (g < 2) ? b1u : b1i;
  const float* w2  = (g < 2) ? w2u : w2i;
  const float* zb  = (g < 2) ? zu + ((long long)g * NUSERS << 6)
                             : zi + ((long long)(g - 2) * NUSERS << 6);
  int w = threadIdx.x >> 6, lane = threadIdx.x & 63;
  int strip = blockIdx.x * 4 + w;
  if (strip >= NSTRIP) return;
  int quad = lane >> 4, mrow = lane & 15;
  const float* zrow = zb + (((long long)(strip * 16 + mrow)) << 6) + quad * 8;
  float4 za0 = *(const float4*)(zrow);
  float4 za1 = *(const float4*)(zrow + 4);
  float4 zc0 = *(const float4*)(zrow + 32);
  float4 zc1 = *(const float4*)(zrow + 36);
  short8 a0 = { f2bf(za0.x), f2bf(za0.y), f2bf(za0.z), f2bf(za0.w),
                f2bf(za1.x), f2bf(za1.y), f2bf(za1.z), f2bf(za1.w) };
  short8 a1 = { f2bf(zc0.x), f2bf(zc0.y), f2bf(zc0.z), f2bf(zc0.w),
                f2bf(zc1.x), f2bf(zc1.y), f2bf(zc1.z), f2bf(zc1.w) };
  float psum = 0.0f;
#pragma unroll
  for (int jt = 0; jt < 8; jt++) {
    const short* wr = W1B + ((jt * 16 + mrow) << 6) + quad * 8;
    short8 b0 = *(const short8*)(wr);
    short8 bh = *(const short8*)(wr + 32);
    f32x4 acc = {0.f, 0.f, 0.f, 0.f};
    acc = __builtin_amdgcn_mfma_f32_16x16x32_bf16(a0, b0, acc, 0, 0, 0);
    acc = __builtin_amdgcn_mfma_f32_16x16x32_bf16(a1, bh, acc, 0, 0, 0);
    int j = jt * 16 + mrow;
    float bj = b1[j], wj = w2[j];
#pragma unroll
    for (int r = 0; r < 4; r++) {
      float s = acc[r] + bj;
      psum += wj * (1.0f - 2.0f / (__expf(2.0f * s) + 1.0f));
    }
  }
  for (int m = 32; m; m >>= 1) psum += __shfl_xor(psum, m);
  if (lane == 0) partials[g * NSTRIP + strip] = psum;
}

__global__ void k_beta(const float* __restrict__ partials, float* __restrict__ wsum) {
  int g = blockIdx.x;
  float s = 0.0f;
  for (int i = threadIdx.x; i < NSTRIP; i += 256) s += partials[g * NSTRIP + i];
  for (int m = 32; m; m >>= 1) s += __shfl_xor(s, m);
  __shared__ float r[4];
  if ((threadIdx.x & 63) == 0) r[threadIdx.x >> 6] = s;
  __syncthreads();
  if (threadIdx.x == 0) wsum[g] = r[0] + r[1] + r[2] + r[3];
}

// ---------------- gather outputs + ssl embedding prep (z precomputed) ----------------
// e1/e2 stored as bf16 for the MFMA similarity GEMM.
__global__ __launch_bounds__(256) void k_h2out(
    const float* __restrict__ zu, const float* __restrict__ zi,
    const int* __restrict__ user_idx, const int* __restrict__ item_idx, const int* __restrict__ neg_idx,
    const float* __restrict__ total,
    const float* __restrict__ wsum, float* __restrict__ out,
    short* __restrict__ e1u, short* __restrict__ e2u,
    short* __restrict__ e1i, short* __restrict__ e2i, float* __restrict__ pos) {
  int lane = threadIdx.x & 63;
  int row = (blockIdx.x << 2) + (threadIdx.x >> 6);
  int seg = row >> 12;
  int r = row & 4095;
  int idx;
  const float* zb;
  int gbase;
  if (seg == 0)      { idx = user_idx[r]; zb = zu; gbase = 0; }
  else if (seg == 1) { idx = item_idx[r]; zb = zi; gbase = 2; }
  else               { idx = neg_idx[r];  zb = zi; gbase = 2; }
  int tnode = gbase ? (NUSERS + idx) : idx;
  float t = total[((long long)tnode << 6) + lane];
  float w0 = wsum[gbase] * (1.0f / 100000.0f);
  float w1 = wsum[gbase + 1] * (1.0f / 100000.0f);
  float mb = fmaxf(w0, w1);
  float b0 = expf(w0 - mb), b1 = expf(w1 - mb);
  float bs = b0 + b1;
  b0 /= bs; b1 /= bs;
  float z0 = zb[((long long)idx << 6) + lane];
  float z1 = zb[(((long long)NUSERS + idx) << 6) + lane];
  float h2 = b0 * z0 + b1 * z1;
  out[((long long)row << 6) + lane] = 0.5f * t + 0.5f * h2;
  if (seg < 2) {
    float n1 = h2 * h2, n2 = t * t;
    for (int m = 32; m; m >>= 1) { n1 += __shfl_xor(n1, m); n2 += __shfl_xor(n2, m); }
    n1 = sqrtf(n1); n2 = sqrtf(n2);
    float a = h2 / n1, b = t / n2;
    float d = a * b;
    for (int m = 32; m; m >>= 1) d += __shfl_xor(d, m);
    short* e1 = seg ? e1i : e1u;
    short* e2 = seg ? e2i : e2u;
    e1[((long long)r << 6) + lane] = f2bf(a);
    e2[((long long)r << 6) + lane] = f2bf(b);
    if (lane == 0) pos[seg * BB + r] = 2.0f * d;
  }
}

// ---------------- ssl similarity via MFMA: wave = 64 rows x 64 cols of S ----------------
__global__ __launch_bounds__(256) void k_gemm(const short* __restrict__ e1u, const short* __restrict__ e2u,
                                              const short* __restrict__ e1i, const short* __restrict__ e2i,
                                              float* __restrict__ sumexp) {
  int side = blockIdx.z;
  const short* A = side ? e1i : e1u;
  const short* B = side ? e2i : e2u;
  int w = threadIdx.x >> 6, lane = threadIdx.x & 63;
  int quad = lane >> 4, mrow = lane & 15;
  int rbase = blockIdx.y * 64;
  int cbase = blockIdx.x * 256 + w * 64;

  short8 a0[4], a1[4], b0[4], b1[4];
#pragma unroll
  for (int ri = 0; ri < 4; ri++) {
    const short* ar = A + ((long long)(rbase + ri * 16 + mrow) << 6) + quad * 8;
    a0[ri] = *(const short8*)ar;
    a1[ri] = *(const short8*)(ar + 32);
  }
#pragma unroll
  for (int ci = 0; ci < 4; ci++) {
    const short* br = B + ((long long)(cbase + ci * 16 + mrow) << 6) + quad * 8;
    b0[ci] = *(const short8*)br;
    b1[ci] = *(const short8*)(br + 32);
  }
  float rs0[4] = {0.f, 0.f, 0.f, 0.f};
  float rs1[4] = {0.f, 0.f, 0.f, 0.f};
  float rs2[4] = {0.f, 0.f, 0.f, 0.f};
  float rs3[4] = {0.f, 0.f, 0.f, 0.f};
#pragma unroll
  for (int ri = 0; ri < 4; ri++) {
#pragma unroll
    for (int ci = 0; ci < 4; ci++) {
      f32x4 acc = {0.f, 0.f, 0.f, 0.f};
      acc = __builtin_amdgcn_mfma_f32_16x16x32_bf16(a0[ri], b0[ci], acc, 0, 0, 0);
      acc = __builtin_amdgcn_mfma_f32_16x16x32_bf16(a1[ri], b1[ci], acc, 0, 0, 0);
      float e0 = __expf(2.0f * acc[0]);
      float e1 = __expf(2.0f * acc[1]);
      float e2 = __expf(2.0f * acc[2]);
      float e3 = __expf(2.0f * acc[3]);
      if (ri == 0) { rs0[0] += e0; rs0[1] += e1; rs0[2] += e2; rs0[3] += e3; }
      if (ri == 1) { rs1[0] += e0; rs1[1] += e1; rs1[2] += e2; rs1[3] += e3; }
      if (ri == 2) { rs2[0] += e0; rs2[1] += e1; rs2[2] += e2; rs2[3] += e3; }
      if (ri == 3) { rs3[0] += e0; rs3[1] += e1; rs3[2] += e2; rs3[3] += e3; }
    }
  }
#pragma unroll
  for (int mask = 1; mask <= 8; mask <<= 1) {
#pragma unroll
    for (int r = 0; r < 4; r++) {
      rs0[r] += __shfl_xor(rs0[r], mask);
      rs1[r] += __shfl_xor(rs1[r], mask);
      rs2[r] += __shfl_xor(rs2[r], mask);
      rs3[r] += __shfl_xor(rs3[r], mask);
    }
  }
  if (mrow == 0) {
    float* sb = sumexp + side * BB + rbase + quad * 4;
#pragma unroll
    for (int r = 0; r < 4; r++) {
      __hip_atomic_fetch_add(&sb[r], rs0[r], __ATOMIC_RELAXED, __HIP_MEMORY_SCOPE_AGENT);
      __hip_atomic_fetch_add(&sb[16 + r], rs1[r], __ATOMIC_RELAXED, __HIP_MEMORY_SCOPE_AGENT);
      __hip_atomic_fetch_add(&sb[32 + r], rs2[r], __ATOMIC_RELAXED, __HIP_MEMORY_SCOPE_AGENT);
      __hip_atomic_fetch_add(&sb[48 + r], rs3[r], __ATOMIC_RELAXED, __HIP_MEMORY_SCOPE_AGENT);
    }
  }
}

__global__ void k_loss(const float* __restrict__ sumexp, const float* __restrict__ pos,
                       float* __restrict__ out) {
  float s = 0.0f;
  for (int i = threadIdx.x; i < 2 * BB; i += 256) s += logf(sumexp[i]) - pos[i];
  for (int m = 32; m; m >>= 1) s += __shfl_xor(s, m);
  __shared__ float r[4];
  if ((threadIdx.x & 63) == 0) r[threadIdx.x >> 6] = s;
  __syncthreads();
  if (threadIdx.x == 0) out[3 * BB * DD] = (r[0] + r[1] + r[2] + r[3]) * (1.0f / (float)BB);
}

// ---------------- launch ----------------
extern "C" void kernel_launch(void* const* d_in, const int* in_sizes, int n_in,
                              void* d_out, int out_size, void* d_ws, size_t ws_size,
                              hipStream_t stream) {
  const float* uf  = (const float*)d_in[0];
  const float* itf = (const float*)d_in[1];
  const float* UIu = (const float*)d_in[2];
  const float* UIi = (const float*)d_in[3];
  const float* W1u = (const float*)d_in[4];
  const float* b1u = (const float*)d_in[5];
  const float* w2u = (const float*)d_in[6];
  const float* W1i = (const float*)d_in[7];
  const float* b1i = (const float*)d_in[8];
  const float* w2i = (const float*)d_in[9];
  const int* ui_src   = (const int*)d_in[10];
  const int* ui_dst   = (const int*)d_in[11];
  const int* mpu      = (const int*)d_in[12];
  const int* mpi      = (const int*)d_in[13];
  const int* user_idx = (const int*)d_in[14];
  const int* item_idx = (const int*)d_in[15];
  const int* neg_idx  = (const int*)d_in[16];
  float* out = (float*)d_out;

  float* wf = (float*)d_ws;
  int*   wi = (int*)d_ws;

  int*   cnt      = wi + O_CNT;
  int*   outcnt   = wi + O_OUTCNT;
  int*   cursor   = wi + O_CURSOR;
  float* partials = wf + O_PARTIALS;
  short* UITBu    = (short*)(wf + O_UITB_U);
  short* UITBi    = (short*)(wf + O_UITB_I);
  short* UIBu     = (short*)(wf + O_UIB_U);
  short* UIBi     = (short*)(wf + O_UIB_I);
  short* W1Bu     = (short*)(wf + O_W1B_U);
  short* W1Bi     = (short*)(wf + O_W1B_I);
  float* sumexp   = wf + O_SUMEXP;
  float* pos      = wf + O_POS;
  int*   off      = wi + O_OFF;
  int*   bsum     = wi + O_BSUM;
  float* dinv     = wf + O_DINV;
  float* oinv     = wf + O_OINV;
  float* iinv     = wf + O_IINV;
  int*   adj      = wi + O_ADJ;
  float* wsum     = wf + O_WSUM;
  float* emba     = wf + O_EMBA;
  float* total    = wf + O_TOTAL;
  float* embb     = wf + O_EMBB;
  short* e1u      = (short*)(wf + O_E1U);
  short* e2u      = (short*)(wf + O_E2U);
  short* e1i      = (short*)(wf + O_E1I);
  short* e2i      = (short*)(wf + O_E2I);

  hipMemsetAsync(d_ws, 0, (size_t)ZEND * 4, stream);

  k_hist_main<<<(E_UI + 255) / 256, 256, 0, stream>>>(ui_src, ui_dst, cnt);
  k_hist_mp<<<dim3((E_MP + 255) / 256, 4), 256, 0, stream>>>(mpu, mpi, cnt, outcnt);

  const int NSCAN = 600000;
  const int NB = (NSCAN + 1023) / 1024;
  k_scan1<<<NB, 1024, 0, stream>>>(cnt, off, bsum, NSCAN);
  k_scan2<<<1, 1024, 0, stream>>>(bsum, NB);
  k_scan3<<<NB, 1024, 0, stream>>>(off, bsum, NSCAN);

  k_inv<<<(600000 + 255) / 256, 256, 0, stream>>>(cnt, outcnt, dinv, iinv, oinv);

  k_scatter_main<<<(E_UI + 255) / 256, 256, 0, stream>>>(ui_src, ui_dst, off, cursor, adj);
  k_scatter_mp<<<dim3((E_MP + 255) / 256, 4), 256, 0, stream>>>(mpu, mpi, off, cursor, adj);

  k_init<<<(3200000 + 255) / 256, 256, 0, stream>>>((const float4*)uf, (const float4*)itf,
                                                    (float4*)emba);
  k_tw<<<32, 256, 0, stream>>>(UIu, UIi, W1u, W1i, UITBu, UITBi, UIBu, UIBi, W1Bu, W1Bi);

  // fused layers (attention-first + buffer-reuse gather), 2-wave blocks
  k_layer<<<6250, 128, 0, stream>>>(emba, embb, total, adj, off, cnt, dinv,
                                    UITBu, UITBi, UIBu, UIBi, 0);
  k_layer<<<6250, 128, 0, stream>>>(embb, emba, total, adj, off, cnt, dinv,
                                    UITBu, UITBi, UIBu, UIBi, 1);

  // metapath: gather z into reused emba (graphs 0,1) / embb (graphs 2,3), then MFMA MLP score
  k_mp_gather<<<dim3(6250, 4), 256, 0, stream>>>(uf, itf, adj, off, cnt, oinv, iinv,
                                                 emba, embb);
  k_mp_mlp<<<dim3((NSTRIP + 3) / 4, 4), 256, 0, stream>>>(emba, embb, W1Bu, b1u, w2u,
                                                          W1Bi, b1i, w2i, partials);
  k_beta<<<4, 256, 0, stream>>>(partials, wsum);

  k_h2out<<<3072, 256, 0, stream>>>(emba, embb, user_idx, item_idx, neg_idx, total,
                                    wsum, out, e1u, e2u, e1i, e2i, pos);

  k_gemm<<<dim3(16, 64, 2), 256, 0, stream>>>(e1u, e2u, e1i, e2i, sumexp);
  k_loss<<<1, 256, 0, stream>>>(sumexp, pos, out);
}

// Round 7
// 1181.375 us; speedup vs baseline: 1.0186x; 1.0186x over previous
//
#include <hip/hip_runtime.h>
#include <math.h>

// ---------------- problem constants ----------------
#define NUSERS   100000
#define NITEMS   100000
#define NNODES   200000
#define DD       64
#define NI       128
#define E_UI     1000000
#define E_MP     500000
#define BB       4096
#define NSTRIP   6250          // 100000 / 16

// ---------------- workspace layout (float/int elements, 4B each) ----------------
#define O_CNT       0LL
#define O_OUTCNT    600000LL
#define O_CURSOR    1000000LL
#define O_PARTIALS  1600000LL   // 25000 used (4 graphs x 6250 strips)
#define O_UITB_U    1625600LL   // 4096 f32 slots = 8192 bf16 (UI^T j-major)
#define O_UITB_I    1629696LL
#define O_UIB_U     1633792LL   // 4096 (UI d-major)
#define O_UIB_I     1637888LL
#define O_W1B_U     1641984LL   // 4096 (W1^T j-major)
#define O_W1B_I     1646080LL
#define O_SUMEXP    1700000LL
#define O_POS       1708192LL
#define ZEND        1716384LL
#define O_OFF       1716384LL
#define O_BSUM      2316448LL
#define O_DINV      2317472LL
#define O_OINV      2517472LL
#define O_IINV      2917472LL
#define O_ADJ       3317472LL
#define O_WSUM      7317472LL
#define O_EMBA      7317480LL   // 12.8M: layer ping; reused as zbuf for mp graphs 0,1
#define O_TOTAL     20117480LL
#define O_EMBB      32917480LL  // 12.8M: layer pong; reused as zbuf for mp graphs 2,3
#define O_E1U       45717480LL  // stored as bf16 shorts
#define O_E2U       45979624LL
#define O_E1I       46241768LL
#define O_E2I       46503912LL

typedef __attribute__((ext_vector_type(8))) short short8;
typedef __attribute__((ext_vector_type(4))) float f32x4;

__device__ __forceinline__ short f2bf(float x) {
  unsigned u = __float_as_uint(x);
  unsigned r = (u + 0x7FFFu + ((u >> 16) & 1u)) >> 16;
  return (short)r;
}

// ---------------- degree histograms ----------------
__global__ void k_hist_main(const int* __restrict__ src, const int* __restrict__ dst,
                            int* __restrict__ cnt) {
  int e = blockIdx.x * 256 + threadIdx.x;
  if (e < E_UI) {
    atomicAdd(&cnt[src[e]], 1);
    atomicAdd(&cnt[NUSERS + dst[e]], 1);
  }
}

__global__ void k_hist_mp(const int* __restrict__ mpu, const int* __restrict__ mpi,
                          int* __restrict__ cnt, int* __restrict__ outcnt) {
  int e = blockIdx.x * 256 + threadIdx.x;
  int g = blockIdx.y;
  if (e < E_MP) {
    const int* base = (g < 2) ? (mpu + (long long)g * 2 * E_MP)
                              : (mpi + (long long)(g - 2) * 2 * E_MP);
    int s = base[e];
    int d = base[E_MP + e];
    atomicAdd(&outcnt[g * NUSERS + s], 1);
    atomicAdd(&cnt[NNODES + g * NUSERS + d], 1);
  }
}

// ---------------- exclusive scan ----------------
__global__ __launch_bounds__(1024) void k_scan1(const int* __restrict__ in, int* __restrict__ out,
                                                int* __restrict__ bsum, int n) {
  __shared__ int s[1024];
  int i = blockIdx.x * 1024 + threadIdx.x;
  int v = (i < n) ? in[i] : 0;
  s[threadIdx.x] = v;
  __syncthreads();
  for (int off = 1; off < 1024; off <<= 1) {
    int x = (threadIdx.x >= off) ? s[threadIdx.x - off] : 0;
    __syncthreads();
    s[threadIdx.x] += x;
    __syncthreads();
  }
  if (i < n) out[i] = s[threadIdx.x] - v;
  if (threadIdx.x == 1023) bsum[blockIdx.x] = s[1023];
}

__global__ __launch_bounds__(1024) void k_scan2(int* __restrict__ bsum, int nb) {
  __shared__ int s[1024];
  int v = (threadIdx.x < nb) ? bsum[threadIdx.x] : 0;
  s[threadIdx.x] = v;
  __syncthreads();
  for (int off = 1; off < 1024; off <<= 1) {
    int x = (threadIdx.x >= off) ? s[threadIdx.x - off] : 0;
    __syncthreads();
    s[threadIdx.x] += x;
    __syncthreads();
  }
  if (threadIdx.x < nb) bsum[threadIdx.x] = s[threadIdx.x] - v;
}

__global__ __launch_bounds__(1024) void k_scan3(int* __restrict__ out, const int* __restrict__ bsum, int n) {
  int i = blockIdx.x * 1024 + threadIdx.x;
  if (i < n) out[i] += bsum[blockIdx.x];
}

// ---------------- inverse-sqrt degrees ----------------
__global__ void k_inv(const int* __restrict__ cnt, const int* __restrict__ outcnt,
                      float* __restrict__ dinv, float* __restrict__ iinv, float* __restrict__ oinv) {
  int i = blockIdx.x * 256 + threadIdx.x;
  if (i < NNODES) {
    int c = cnt[i]; if (c < 1) c = 1;
    dinv[i] = 1.0f / sqrtf((float)c);
  } else if (i < 600000) {
    int c = cnt[i]; if (c < 1) c = 1;
    iinv[i - NNODES] = 1.0f / sqrtf((float)c);
  }
  if (i < 400000) {
    int c = outcnt[i]; if (c < 1) c = 1;
    oinv[i] = 1.0f / sqrtf((float)c);
  }
}

// ---------------- CSR scatter ----------------
__global__ void k_scatter_main(const int* __restrict__ src, const int* __restrict__ dst,
                               const int* __restrict__ off, int* __restrict__ cursor,
                               int* __restrict__ adj) {
  int e = blockIdx.x * 256 + threadIdx.x;
  if (e < E_UI) {
    int u = src[e];
    int it = NUSERS + dst[e];
    int p = atomicAdd(&cursor[u], 1);
    adj[off[u] + p] = it;
    int q = atomicAdd(&cursor[it], 1);
    adj[off[it] + q] = u;
  }
}

__global__ void k_scatter_mp(const int* __restrict__ mpu, const int* __restrict__ mpi,
                             const int* __restrict__ off, int* __restrict__ cursor,
                             int* __restrict__ adj) {
  int e = blockIdx.x * 256 + threadIdx.x;
  int g = blockIdx.y;
  if (e < E_MP) {
    const int* base = (g < 2) ? (mpu + (long long)g * 2 * E_MP)
                              : (mpi + (long long)(g - 2) * 2 * E_MP);
    int s = base[e];
    int d = base[E_MP + e];
    int node = NNODES + g * NUSERS + d;
    int p = atomicAdd(&cursor[node], 1);
    adj[off[node] + p] = s;
  }
}

// ---------------- emb init ----------------
__global__ void k_init(const float4* __restrict__ uf, const float4* __restrict__ itf,
                       float4* __restrict__ emb) {
  int i = blockIdx.x * 256 + threadIdx.x;
  if (i < 3200000) {
    emb[i] = (i < 1600000) ? uf[i] : itf[i - 1600000];
  }
}

// ---------------- weight prep (bf16 variants) ----------------
__global__ void k_tw(const float* __restrict__ UIu, const float* __restrict__ UIi,
                     const float* __restrict__ W1u, const float* __restrict__ W1i,
                     short* __restrict__ UITBu, short* __restrict__ UITBi,
                     short* __restrict__ UIBu,  short* __restrict__ UIBi,
                     short* __restrict__ W1Bu,  short* __restrict__ W1Bi) {
  int t = blockIdx.x * 256 + threadIdx.x;
  if (t < 8192) {
    int d = t >> 7, j = t & 127;
    UITBu[j * 64 + d] = f2bf(UIu[t]);
    UITBi[j * 64 + d] = f2bf(UIi[t]);
    UIBu[t] = f2bf(UIu[t]);
    UIBi[t] = f2bf(UIi[t]);
    W1Bu[j * 64 + d] = f2bf(W1u[t]);
    W1Bi[j * 64 + d] = f2bf(W1i[t]);
  }
}

// ---------------- 8-row accumulate via readlane (wave-uniform broadcast -> SGPR base) ----------------
// Best for deg ~10 full-wave rows (k_layer): scalar-base loads, no LDS-pipe bpermute on
// the address path. Runtime-rem version (fallback for deg > 24).
__device__ __forceinline__ float acc8(const float* __restrict__ tbl, int miv, float mwv,
                                      int rem, int lane, float acc) {
  unsigned wb = __float_as_uint(mwv);
  for (int k = 0; k < rem; k += 8) {
    int n0 = __builtin_amdgcn_readlane(miv, k + 0);
    int n1 = __builtin_amdgcn_readlane(miv, k + 1);
    int n2 = __builtin_amdgcn_readlane(miv, k + 2);
    int n3 = __builtin_amdgcn_readlane(miv, k + 3);
    int n4 = __builtin_amdgcn_readlane(miv, k + 4);
    int n5 = __builtin_amdgcn_readlane(miv, k + 5);
    int n6 = __builtin_amdgcn_readlane(miv, k + 6);
    int n7 = __builtin_amdgcn_readlane(miv, k + 7);
    float w0 = __uint_as_float(__builtin_amdgcn_readlane(wb, k + 0));
    float w1 = __uint_as_float(__builtin_amdgcn_readlane(wb, k + 1));
    float w2 = __uint_as_float(__builtin_amdgcn_readlane(wb, k + 2));
    float w3 = __uint_as_float(__builtin_amdgcn_readlane(wb, k + 3));
    float w4 = __uint_as_float(__builtin_amdgcn_readlane(wb, k + 4));
    float w5 = __uint_as_float(__builtin_amdgcn_readlane(wb, k + 5));
    float w6 = __uint_as_float(__builtin_amdgcn_readlane(wb, k + 6));
    float w7 = __uint_as_float(__builtin_amdgcn_readlane(wb, k + 7));
    float v0 = tbl[((long long)n0 << 6) + lane], v1 = tbl[((long long)n1 << 6) + lane];
    float v2 = tbl[((long long)n2 << 6) + lane], v3 = tbl[((long long)n3 << 6) + lane];
    float v4 = tbl[((long long)n4 << 6) + lane], v5 = tbl[((long long)n5 << 6) + lane];
    float v6 = tbl[((long long)n6 << 6) + lane], v7 = tbl[((long long)n7 << 6) + lane];
    acc += w0 * v0; acc += w1 * v1; acc += w2 * v2; acc += w3 * v3;
    acc += w4 * v4; acc += w5 * v5; acc += w6 * v6; acc += w7 * v7;
  }
  return acc;
}

// Fixed-trip straight-line version: all R loads issue back-to-back (no runtime loop
// boundary). Padded lanes carry mi=0/mw=0 -> exact +0 adds, order identical.
template <int R>
__device__ __forceinline__ float acc8f(const float* __restrict__ tbl, int miv, float mwv,
                                       int lane) {
  unsigned wb = __float_as_uint(mwv);
  float acc = 0.0f;
#pragma unroll
  for (int k = 0; k < R; k += 8) {
    int n0 = __builtin_amdgcn_readlane(miv, k + 0);
    int n1 = __builtin_amdgcn_readlane(miv, k + 1);
    int n2 = __builtin_amdgcn_readlane(miv, k + 2);
    int n3 = __builtin_amdgcn_readlane(miv, k + 3);
    int n4 = __builtin_amdgcn_readlane(miv, k + 4);
    int n5 = __builtin_amdgcn_readlane(miv, k + 5);
    int n6 = __builtin_amdgcn_readlane(miv, k + 6);
    int n7 = __builtin_amdgcn_readlane(miv, k + 7);
    float w0 = __uint_as_float(__builtin_amdgcn_readlane(wb, k + 0));
    float w1 = __uint_as_float(__builtin_amdgcn_readlane(wb, k + 1));
    float w2 = __uint_as_float(__builtin_amdgcn_readlane(wb, k + 2));
    float w3 = __uint_as_float(__builtin_amdgcn_readlane(wb, k + 3));
    float w4 = __uint_as_float(__builtin_amdgcn_readlane(wb, k + 4));
    float w5 = __uint_as_float(__builtin_amdgcn_readlane(wb, k + 5));
    float w6 = __uint_as_float(__builtin_amdgcn_readlane(wb, k + 6));
    float w7 = __uint_as_float(__builtin_amdgcn_readlane(wb, k + 7));
    float v0 = tbl[((long long)n0 << 6) + lane], v1 = tbl[((long long)n1 << 6) + lane];
    float v2 = tbl[((long long)n2 << 6) + lane], v3 = tbl[((long long)n3 << 6) + lane];
    float v4 = tbl[((long long)n4 << 6) + lane], v5 = tbl[((long long)n5 << 6) + lane];
    float v6 = tbl[((long long)n6 << 6) + lane], v7 = tbl[((long long)n7 << 6) + lane];
    acc += w0 * v0; acc += w1 * v1; acc += w2 * v2; acc += w3 * v3;
    acc += w4 * v4; acc += w5 * v5; acc += w6 * v6; acc += w7 * v7;
  }
  return acc;
}

// tail for degree > 64 (rare)
__device__ __forceinline__ float gather_tail(const float* __restrict__ tbl,
                                             const int* __restrict__ adj,
                                             int start, int c,
                                             const float* __restrict__ warr, int wofs,
                                             int lane, float acc) {
  for (int kb = 64; kb < c; kb += 64) {
    int rem = c - kb; if (rem > 64) rem = 64;
    int ti = 0; float tw = 0.0f;
    if (lane < rem) { ti = adj[start + kb + lane]; tw = warr[wofs + ti]; }
    acc = acc8(tbl, ti, tw, rem, lane, acc);
  }
  return acc;
}

// Tiered dispatch: wave-uniform scalar branch to straight-line bodies.
// Poisson(10): P(c<=8)=0.33, P(<=16)=0.97, P(<=24)=0.9996.
__device__ __forceinline__ float gather_node(const float* __restrict__ tbl,
                                             const int* __restrict__ adj,
                                             int ofs, int c, int miv, float mwv,
                                             const float* __restrict__ warr, int wofs,
                                             int lane) {
  if (c <= 8)  return acc8f<8>(tbl, miv, mwv, lane);
  if (c <= 16) return acc8f<16>(tbl, miv, mwv, lane);
  if (c <= 24) return acc8f<24>(tbl, miv, mwv, lane);
  int rem = c < 64 ? c : 64;
  float acc = acc8(tbl, miv, mwv, rem, lane, 0.0f);
  if (c > 64) acc = gather_tail(tbl, adj, ofs, c, warr, wofs, lane, acc);
  return acc;
}

// ---------------- float4 group gather (16-lane group owns a row, lane loads 16B) ----------------
// Best for deg ~5 overhead-bound gathers (k_mp_gather). Runtime-rem fallback.
__device__ __forceinline__ void acc4x(const float* __restrict__ tbl, int miv, float mwv,
                                      int rem, int grp, int dq, f32x4& acc) {
  for (int k = 0; k < rem; k += 16) {
    int s0 = k + grp, s1 = k + 4 + grp, s2 = k + 8 + grp, s3 = k + 12 + grp;
    int n0 = __shfl(miv, s0), n1 = __shfl(miv, s1);
    int n2 = __shfl(miv, s2), n3 = __shfl(miv, s3);
    float w0 = __shfl(mwv, s0), w1 = __shfl(mwv, s1);
    float w2 = __shfl(mwv, s2), w3 = __shfl(mwv, s3);
    float4 v0 = *(const float4*)(tbl + ((long long)n0 << 6) + dq);
    float4 v1 = *(const float4*)(tbl + ((long long)n1 << 6) + dq);
    float4 v2 = *(const float4*)(tbl + ((long long)n2 << 6) + dq);
    float4 v3 = *(const float4*)(tbl + ((long long)n3 << 6) + dq);
    acc.x += w0 * v0.x; acc.y += w0 * v0.y; acc.z += w0 * v0.z; acc.w += w0 * v0.w;
    acc.x += w1 * v1.x; acc.y += w1 * v1.y; acc.z += w1 * v1.z; acc.w += w1 * v1.w;
    acc.x += w2 * v2.x; acc.y += w2 * v2.y; acc.z += w2 * v2.z; acc.w += w2 * v2.w;
    acc.x += w3 * v3.x; acc.y += w3 * v3.y; acc.z += w3 * v3.z; acc.w += w3 * v3.w;
  }
}

__device__ __forceinline__ void gather_tail4(const float* __restrict__ tbl,
                                             const int* __restrict__ adj,
                                             int start, int c,
                                             const float* __restrict__ warr, int wofs,
                                             int lane, int grp, int dq, f32x4& acc) {
  for (int kb = 64; kb < c; kb += 64) {
    int rem = c - kb; if (rem > 64) rem = 64;
    int ti = 0; float tw = 0.0f;
    if (lane < rem) { ti = adj[start + kb + lane]; tw = warr[wofs + ti]; }
    acc4x(tbl, ti, tw, rem, grp, dq, acc);
  }
}

__device__ __forceinline__ float bcastf(float x) {
  return __uint_as_float(__builtin_amdgcn_readfirstlane(__float_as_uint(x)));
}

// ---------------- fused layer: MFMA intent attention + spmm + residual + total ----------------
// Block = 2 waves; wave = one 16-node strip. R5 structure (attention first, O in regs,
// 4352B LDS buffer reused as sP then sZ) BUT edge prefetch moved AFTER the attention:
// mi/mw (32 VGPR) never coexist with attention temporaries -> no spill (R5 lesson:
// launch_bounds(128,7) squeezed VGPR to 36, spilled, +110MB scratch traffic, 212us).
// launch_bounds(128,5): VGPR cap ~102 (peak est ~80), 10 blocks/CU = 20 waves (62.5%).
__global__ __launch_bounds__(128, 5) void k_layer(
    const float* __restrict__ ecur, float* __restrict__ enext, float* __restrict__ total,
    const int* __restrict__ adj, const int* __restrict__ off, const int* __restrict__ cnt,
    const float* __restrict__ dinv,
    const short* __restrict__ UITBu, const short* __restrict__ UITBi,
    const short* __restrict__ UIBu,  const short* __restrict__ UIBi, int layer) {
  __shared__ float sBuf[2][16 * 68];   // 4352 B/wave: bf16 P (stride 136 shorts) then f32 Z (stride 68)
  int w = threadIdx.x >> 6, lane = threadIdx.x & 63;
  int nb = blockIdx.x * 32 + w * 16;
  const short* UITB = (nb < NUSERS) ? UITBu : UITBi;
  const short* UIB  = (nb < NUSERS) ? UIBu  : UIBi;
  float* rowZ = sBuf[w];
  short* rowP = (short*)sBuf[w];
  int quad = lane >> 4, mrow = lane & 15;

  // ---- phase-1 row loads + bf16 convert ----
  const float* vrow = ecur + (((long long)(nb + mrow)) << 6) + quad * 8;
  float4 va0 = *(const float4*)(vrow);
  float4 va1 = *(const float4*)(vrow + 4);
  float4 vc0 = *(const float4*)(vrow + 32);
  float4 vc1 = *(const float4*)(vrow + 36);
  short8 a0 = { f2bf(va0.x), f2bf(va0.y), f2bf(va0.z), f2bf(va0.w),
                f2bf(va1.x), f2bf(va1.y), f2bf(va1.z), f2bf(va1.w) };
  short8 a1 = { f2bf(vc0.x), f2bf(vc0.y), f2bf(vc0.z), f2bf(vc0.w),
                f2bf(vc1.x), f2bf(vc1.y), f2bf(vc1.z), f2bf(vc1.w) };

  // ---- phase 1: S = v @ UI ; P = exp(S) -> sP (bf16) ; den per node ----
  float den0 = 0.f, den1 = 0.f, den2 = 0.f, den3 = 0.f;
  short* pw = rowP + (quad * 4) * 136 + mrow;
#pragma unroll
  for (int jt = 0; jt < 8; jt++) {
    const short* wr = UITB + ((jt * 16 + mrow) << 6) + quad * 8;
    short8 b0 = *(const short8*)(wr);
    short8 bh = *(const short8*)(wr + 32);
    f32x4 acc = {0.f, 0.f, 0.f, 0.f};
    acc = __builtin_amdgcn_mfma_f32_16x16x32_bf16(a0, b0, acc, 0, 0, 0);
    acc = __builtin_amdgcn_mfma_f32_16x16x32_bf16(a1, bh, acc, 0, 0, 0);
    float e0 = __expf(acc[0]), e1 = __expf(acc[1]);
    float e2 = __expf(acc[2]), e3 = __expf(acc[3]);
    den0 += e0; den1 += e1; den2 += e2; den3 += e3;
    short* pj = pw + jt * 16;
    pj[0] = f2bf(e0); pj[136] = f2bf(e1); pj[272] = f2bf(e2); pj[408] = f2bf(e3);
  }
  for (int mask = 1; mask <= 8; mask <<= 1) {
    den0 += __shfl_xor(den0, mask); den1 += __shfl_xor(den1, mask);
    den2 += __shfl_xor(den2, mask); den3 += __shfl_xor(den3, mask);
  }
  float rd0 = 1.f / den0, rd1 = 1.f / den1, rd2 = 1.f / den2, rd3 = 1.f / den3;

  // ---- phase 2: O = P @ UI^T (K=128) -> registers ----
  f32x4 accs[4];
#pragma unroll
  for (int dt = 0; dt < 4; dt++) {
    f32x4 acc = {0.f, 0.f, 0.f, 0.f};
#pragma unroll
    for (int c = 0; c < 4; c++) {
      const short* pr = rowP + mrow * 136 + c * 32 + quad * 8;
      short8 af = *(const short8*)(pr);
      const short* br = UIB + ((dt * 16 + mrow) << 7) + c * 32 + quad * 8;
      short8 bf = *(const short8*)(br);
      acc = __builtin_amdgcn_mfma_f32_16x16x32_bf16(af, bf, acc, 0, 0, 0);
    }
    accs[dt] = acc;
  }

  __syncthreads();   // drain sP reads before the buffer is overwritten as sZ

  // ---- gather metadata + edge prefetch (now: no overlap with attention regs) ----
  int ofs[16], cns[16];
  float dn[16];
  int mi[16]; float mw[16];
#pragma unroll
  for (int m = 0; m < 16; m++) {
    ofs[m] = __builtin_amdgcn_readfirstlane(off[nb + m]);
    cns[m] = __builtin_amdgcn_readfirstlane(cnt[nb + m]);
    dn[m]  = bcastf(dinv[nb + m]);
  }
#pragma unroll
  for (int m = 0; m < 16; m++)
    mi[m] = (lane < cns[m]) ? adj[ofs[m] + lane] : 0;
#pragma unroll
  for (int m = 0; m < 16; m++)
    mw[m] = (lane < cns[m]) ? dinv[mi[m]] : 0.0f;

  // ---- gather: gnn rows -> sZ (reused buffer), tiered straight-line bodies ----
#pragma unroll
  for (int m = 0; m < 16; m++) {
    float acc = gather_node(ecur, adj, ofs[m], cns[m], mi[m], mw[m], dinv, 0, lane);
    rowZ[m * 68 + lane] = dn[m] * acc;
  }

  // ---- combine + store ----
#pragma unroll
  for (int dt = 0; dt < 4; dt++) {
    int d = dt * 16 + mrow;
#define COMB(r, rd)                                                            \
    { int node = nb + quad * 4 + r;                                            \
      long long base = (((long long)node) << 6) + d;                           \
      float o = accs[dt][r] * rd;                                              \
      float gn = rowZ[(quad * 4 + r) * 68 + d];                                \
      float vv = ecur[base];                                                   \
      float ne = gn + o + vv;                                                  \
      enext[base] = ne;                                                        \
      total[base] = (layer == 0) ? (vv + ne) : (total[base] + ne); }
    COMB(0, rd0) COMB(1, rd1) COMB(2, rd2) COMB(3, rd3)
#undef COMB
  }
}

// ---------------- metapath graphconv gather: z (x iinv) -> zbuf ----------------
// 4 nodes per wave, float4 group-gather; fixed-16 straight-line fast path.
__global__ __launch_bounds__(256, 8) void k_mp_gather(
    const float* __restrict__ uf, const float* __restrict__ itf,
    const int* __restrict__ adj, const int* __restrict__ off, const int* __restrict__ cnt,
    const float* __restrict__ oinv, const float* __restrict__ iinv,
    float* __restrict__ zu, float* __restrict__ zi) {
  int g = blockIdx.y;
  const float* feat = (g < 2) ? uf : itf;
  float* zb = (g < 2) ? zu + ((long long)g * NUSERS << 6)
                      : zi + ((long long)(g - 2) * NUSERS << 6);
  int w = threadIdx.x >> 6, lane = threadIdx.x & 63;
  int n0 = (blockIdx.x * 4 + w) * 4;
  int gofs = g * NUSERS;
  int grp = lane >> 4, dq = (lane & 15) << 2;
  int ofs[4], cns[4];
  float iv[4];
  int mi[4]; float mw[4];
#pragma unroll
  for (int m = 0; m < 4; m++) {
    int node = NNODES + gofs + n0 + m;
    ofs[m] = __builtin_amdgcn_readfirstlane(off[node]);
    cns[m] = __builtin_amdgcn_readfirstlane(cnt[node]);
    iv[m]  = bcastf(iinv[gofs + n0 + m]);
  }
#pragma unroll
  for (int m = 0; m < 4; m++)
    mi[m] = (lane < cns[m]) ? adj[ofs[m] + lane] : 0;
#pragma unroll
  for (int m = 0; m < 4; m++)
    mw[m] = (lane < cns[m]) ? oinv[gofs + mi[m]] : 0.0f;
#pragma unroll
  for (int m = 0; m < 4; m++) {
    int c = cns[m];
    f32x4 acc = {0.f, 0.f, 0.f, 0.f};
    if (c <= 16) {
      acc4x(feat, mi[m], mw[m], 16, grp, dq, acc);   // compile-time trip -> unrolled
    } else {
      int rem = c < 64 ? c : 64;
      acc4x(feat, mi[m], mw[m], rem, grp, dq, acc);
      if (c > 64) gather_tail4(feat, adj, ofs[m], c, oinv, gofs, lane, grp, dq, acc);
    }
    acc.x += __shfl_xor(acc.x, 16); acc.y += __shfl_xor(acc.y, 16);
    acc.z += __shfl_xor(acc.z, 16); acc.w += __shfl_xor(acc.w, 16);
    acc.x += __shfl_xor(acc.x, 32); acc.y += __shfl_xor(acc.y, 32);
    acc.z += __shfl_xor(acc.z, 32); acc.w += __shfl_xor(acc.w, 32);
    if (lane < 16) {
      float s = iv[m];
      float4 o = { acc.x * s, acc.y * s, acc.z * s, acc.w * s };
      *(float4*)&zb[((long long)(n0 + m) << 6) + dq] = o;
    }
  }
}

// ---------------- metapath MLP score via MFMA ----------------
__global__ __launch_bounds__(256, 4) void k_mp_mlp(
    const float* __restrict__ zu, const float* __restrict__ zi,
    const short* __restrict__ W1Bu, const float* __restrict__ b1u, const float* __restrict__ w2u,
    const short* __restrict__ W1Bi, const float* __restrict__ b1i, const float* __restrict__ w2i,
    float* __restrict__ partials) {
  int g = blockIdx.y;
  const short* W1B = (g < 2) ? W1Bu : W1Bi;
  const float* b1  = (g < 2) ? b1u : b1i;
  const float* w2  = (g < 2) ? w2u : w2i;
  const float* zb  = (g < 2) ? zu + ((long long)g * NUSERS << 6)
                             : zi + ((long long)(g - 2) * NUSERS << 6);
  int w = threadIdx.x >> 6, lane = threadIdx.x & 63;
  int strip = blockIdx.x * 4 + w;
  if (strip >= NSTRIP) return;
  int quad = lane >> 4, mrow = lane & 15;
  const float* zrow = zb + (((long long)(strip * 16 + mrow)) << 6) + quad * 8;
  float4 za0 = *(const float4*)(zrow);
  float4 za1 = *(const float4*)(zrow + 4);
  float4 zc0 = *(const float4*)(zrow + 32);
  float4 zc1 = *(const float4*)(zrow + 36);
  short8 a0 = { f2bf(za0.x), f2bf(za0.y), f2bf(za0.z), f2bf(za0.w),
                f2bf(za1.x), f2bf(za1.y), f2bf(za1.z), f2bf(za1.w) };
  short8 a1 = { f2bf(zc0.x), f2bf(zc0.y), f2bf(zc0.z), f2bf(zc0.w),
                f2bf(zc1.x), f2bf(zc1.y), f2bf(zc1.z), f2bf(zc1.w) };
  float psum = 0.0f;
#pragma unroll
  for (int jt = 0; jt < 8; jt++) {
    const short* wr = W1B + ((jt * 16 + mrow) << 6) + quad * 8;
    short8 b0 = *(const short8*)(wr);
    short8 bh = *(const short8*)(wr + 32);
    f32x4 acc = {0.f, 0.f, 0.f, 0.f};
    acc = __builtin_amdgcn_mfma_f32_16x16x32_bf16(a0, b0, acc, 0, 0, 0);
    acc = __builtin_amdgcn_mfma_f32_16x16x32_bf16(a1, bh, acc, 0, 0, 0);
    int j = jt * 16 + mrow;
    float bj = b1[j], wj = w2[j];
#pragma unroll
    for (int r = 0; r < 4; r++) {
      float s = acc[r] + bj;
      psum += wj * (1.0f - 2.0f / (__expf(2.0f * s) + 1.0f));
    }
  }
  for (int m = 32; m; m >>= 1) psum += __shfl_xor(psum, m);
  if (lane == 0) partials[g * NSTRIP + strip] = psum;
}

__global__ void k_beta(const float* __restrict__ partials, float* __restrict__ wsum) {
  int g = blockIdx.x;
  float s = 0.0f;
  for (int i = threadIdx.x; i < NSTRIP; i += 256) s += partials[g * NSTRIP + i];
  for (int m = 32; m; m >>= 1) s += __shfl_xor(s, m);
  __shared__ float r[4];
  if ((threadIdx.x & 63) == 0) r[threadIdx.x >> 6] = s;
  __syncthreads();
  if (threadIdx.x == 0) wsum[g] = r[0] + r[1] + r[2] + r[3];
}

// ---------------- gather outputs + ssl embedding prep (z precomputed) ----------------
// e1/e2 stored as bf16 for the MFMA similarity GEMM.
__global__ __launch_bounds__(256) void k_h2out(
    const float* __restrict__ zu, const float* __restrict__ zi,
    const int* __restrict__ user_idx, const int* __restrict__ item_idx, const int* __restrict__ neg_idx,
    const float* __restrict__ total,
    const float* __restrict__ wsum, float* __restrict__ out,
    short* __restrict__ e1u, short* __restrict__ e2u,
    short* __restrict__ e1i, short* __restrict__ e2i, float* __restrict__ pos) {
  int lane = threadIdx.x & 63;
  int row = (blockIdx.x << 2) + (threadIdx.x >> 6);
  int seg = row >> 12;
  int r = row & 4095;
  int idx;
  const float* zb;
  int gbase;
  if (seg == 0)      { idx = user_idx[r]; zb = zu; gbase = 0; }
  else if (seg == 1) { idx = item_idx[r]; zb = zi; gbase = 2; }
  else               { idx = neg_idx[r];  zb = zi; gbase = 2; }
  int tnode = gbase ? (NUSERS + idx) : idx;
  float t = total[((long long)tnode << 6) + lane];
  float w0 = wsum[gbase] * (1.0f / 100000.0f);
  float w1 = wsum[gbase + 1] * (1.0f / 100000.0f);
  float mb = fmaxf(w0, w1);
  float b0 = expf(w0 - mb), b1 = expf(w1 - mb);
  float bs = b0 + b1;
  b0 /= bs; b1 /= bs;
  float z0 = zb[((long long)idx << 6) + lane];
  float z1 = zb[(((long long)NUSERS + idx) << 6) + lane];
  float h2 = b0 * z0 + b1 * z1;
  out[((long long)row << 6) + lane] = 0.5f * t + 0.5f * h2;
  if (seg < 2) {
    float n1 = h2 * h2, n2 = t * t;
    for (int m = 32; m; m >>= 1) { n1 += __shfl_xor(n1, m); n2 += __shfl_xor(n2, m); }
    n1 = sqrtf(n1); n2 = sqrtf(n2);
    float a = h2 / n1, b = t / n2;
    float d = a * b;
    for (int m = 32; m; m >>= 1) d += __shfl_xor(d, m);
    short* e1 = seg ? e1i : e1u;
    short* e2 = seg ? e2i : e2u;
    e1[((long long)r << 6) + lane] = f2bf(a);
    e2[((long long)r << 6) + lane] = f2bf(b);
    if (lane == 0) pos[seg * BB + r] = 2.0f * d;
  }
}

// ---------------- ssl similarity via MFMA: wave = 64 rows x 64 cols of S ----------------
__global__ __launch_bounds__(256) void k_gemm(const short* __restrict__ e1u, const short* __restrict__ e2u,
                                              const short* __restrict__ e1i, const short* __restrict__ e2i,
                                              float* __restrict__ sumexp) {
  int side = blockIdx.z;
  const short* A = side ? e1i : e1u;
  const short* B = side ? e2i : e2u;
  int w = threadIdx.x >> 6, lane = threadIdx.x & 63;
  int quad = lane >> 4, mrow = lane & 15;
  int rbase = blockIdx.y * 64;
  int cbase = blockIdx.x * 256 + w * 64;

  short8 a0[4], a1[4], b0[4], b1[4];
#pragma unroll
  for (int ri = 0; ri < 4; ri++) {
    const short* ar = A + ((long long)(rbase + ri * 16 + mrow) << 6) + quad * 8;
    a0[ri] = *(const short8*)ar;
    a1[ri] = *(const short8*)(ar + 32);
  }
#pragma unroll
  for (int ci = 0; ci < 4; ci++) {
    const short* br = B + ((long long)(cbase + ci * 16 + mrow) << 6) + quad * 8;
    b0[ci] = *(const short8*)br;
    b1[ci] = *(const short8*)(br + 32);
  }
  float rs0[4] = {0.f, 0.f, 0.f, 0.f};
  float rs1[4] = {0.f, 0.f, 0.f, 0.f};
  float rs2[4] = {0.f, 0.f, 0.f, 0.f};
  float rs3[4] = {0.f, 0.f, 0.f, 0.f};
#pragma unroll
  for (int ri = 0; ri < 4; ri++) {
#pragma unroll
    for (int ci = 0; ci < 4; ci++) {
      f32x4 acc = {0.f, 0.f, 0.f, 0.f};
      acc = __builtin_amdgcn_mfma_f32_16x16x32_bf16(a0[ri], b0[ci], acc, 0, 0, 0);
      acc = __builtin_amdgcn_mfma_f32_16x16x32_bf16(a1[ri], b1[ci], acc, 0, 0, 0);
      float e0 = __expf(2.0f * acc[0]);
      float e1 = __expf(2.0f * acc[1]);
      float e2 = __expf(2.0f * acc[2]);
      float e3 = __expf(2.0f * acc[3]);
      if (ri == 0) { rs0[0] += e0; rs0[1] += e1; rs0[2] += e2; rs0[3] += e3; }
      if (ri == 1) { rs1[0] += e0; rs1[1] += e1; rs1[2] += e2; rs1[3] += e3; }
      if (ri == 2) { rs2[0] += e0; rs2[1] += e1; rs2[2] += e2; rs2[3] += e3; }
      if (ri == 3) { rs3[0] += e0; rs3[1] += e1; rs3[2] += e2; rs3[3] += e3; }
    }
  }
#pragma unroll
  for (int mask = 1; mask <= 8; mask <<= 1) {
#pragma unroll
    for (int r = 0; r < 4; r++) {
      rs0[r] += __shfl_xor(rs0[r], mask);
      rs1[r] += __shfl_xor(rs1[r], mask);
      rs2[r] += __shfl_xor(rs2[r], mask);
      rs3[r] += __shfl_xor(rs3[r], mask);
    }
  }
  if (mrow == 0) {
    float* sb = sumexp + side * BB + rbase + quad * 4;
#pragma unroll
    for (int r = 0; r < 4; r++) {
      __hip_atomic_fetch_add(&sb[r], rs0[r], __ATOMIC_RELAXED, __HIP_MEMORY_SCOPE_AGENT);
      __hip_atomic_fetch_add(&sb[16 + r], rs1[r], __ATOMIC_RELAXED, __HIP_MEMORY_SCOPE_AGENT);
      __hip_atomic_fetch_add(&sb[32 + r], rs2[r], __ATOMIC_RELAXED, __HIP_MEMORY_SCOPE_AGENT);
      __hip_atomic_fetch_add(&sb[48 + r], rs3[r], __ATOMIC_RELAXED, __HIP_MEMORY_SCOPE_AGENT);
    }
  }
}

__global__ void k_loss(const float* __restrict__ sumexp, const float* __restrict__ pos,
                       float* __restrict__ out) {
  float s = 0.0f;
  for (int i = threadIdx.x; i < 2 * BB; i += 256) s += logf(sumexp[i]) - pos[i];
  for (int m = 32; m; m >>= 1) s += __shfl_xor(s, m);
  __shared__ float r[4];
  if ((threadIdx.x & 63) == 0) r[threadIdx.x >> 6] = s;
  __syncthreads();
  if (threadIdx.x == 0) out[3 * BB * DD] = (r[0] + r[1] + r[2] + r[3]) * (1.0f / (float)BB);
}

// ---------------- launch ----------------
extern "C" void kernel_launch(void* const* d_in, const int* in_sizes, int n_in,
                              void* d_out, int out_size, void* d_ws, size_t ws_size,
                              hipStream_t stream) {
  const float* uf  = (const float*)d_in[0];
  const float* itf = (const float*)d_in[1];
  const float* UIu = (const float*)d_in[2];
  const float* UIi = (const float*)d_in[3];
  const float* W1u = (const float*)d_in[4];
  const float* b1u = (const float*)d_in[5];
  const float* w2u = (const float*)d_in[6];
  const float* W1i = (const float*)d_in[7];
  const float* b1i = (const float*)d_in[8];
  const float* w2i = (const float*)d_in[9];
  const int* ui_src   = (const int*)d_in[10];
  const int* ui_dst   = (const int*)d_in[11];
  const int* mpu      = (const int*)d_in[12];
  const int* mpi      = (const int*)d_in[13];
  const int* user_idx = (const int*)d_in[14];
  const int* item_idx = (const int*)d_in[15];
  const int* neg_idx  = (const int*)d_in[16];
  float* out = (float*)d_out;

  float* wf = (float*)d_ws;
  int*   wi = (int*)d_ws;

  int*   cnt      = wi + O_CNT;
  int*   outcnt   = wi + O_OUTCNT;
  int*   cursor   = wi + O_CURSOR;
  float* partials = wf + O_PARTIALS;
  short* UITBu    = (short*)(wf + O_UITB_U);
  short* UITBi    = (short*)(wf + O_UITB_I);
  short* UIBu     = (short*)(wf + O_UIB_U);
  short* UIBi     = (short*)(wf + O_UIB_I);
  short* W1Bu     = (short*)(wf + O_W1B_U);
  short* W1Bi     = (short*)(wf + O_W1B_I);
  float* sumexp   = wf + O_SUMEXP;
  float* pos      = wf + O_POS;
  int*   off      = wi + O_OFF;
  int*   bsum     = wi + O_BSUM;
  float* dinv     = wf + O_DINV;
  float* oinv     = wf + O_OINV;
  float* iinv     = wf + O_IINV;
  int*   adj      = wi + O_ADJ;
  float* wsum     = wf + O_WSUM;
  float* emba     = wf + O_EMBA;
  float* total    = wf + O_TOTAL;
  float* embb     = wf + O_EMBB;
  short* e1u      = (short*)(wf + O_E1U);
  short* e2u      = (short*)(wf + O_E2U);
  short* e1i      = (short*)(wf + O_E1I);
  short* e2i      = (short*)(wf + O_E2I);

  hipMemsetAsync(d_ws, 0, (size_t)ZEND * 4, stream);

  k_hist_main<<<(E_UI + 255) / 256, 256, 0, stream>>>(ui_src, ui_dst, cnt);
  k_hist_mp<<<dim3((E_MP + 255) / 256, 4), 256, 0, stream>>>(mpu, mpi, cnt, outcnt);

  const int NSCAN = 600000;
  const int NB = (NSCAN + 1023) / 1024;
  k_scan1<<<NB, 1024, 0, stream>>>(cnt, off, bsum, NSCAN);
  k_scan2<<<1, 1024, 0, stream>>>(bsum, NB);
  k_scan3<<<NB, 1024, 0, stream>>>(off, bsum, NSCAN);

  k_inv<<<(600000 + 255) / 256, 256, 0, stream>>>(cnt, outcnt, dinv, iinv, oinv);

  k_scatter_main<<<(E_UI + 255) / 256, 256, 0, stream>>>(ui_src, ui_dst, off, cursor, adj);
  k_scatter_mp<<<dim3((E_MP + 255) / 256, 4), 256, 0, stream>>>(mpu, mpi, off, cursor, adj);

  k_init<<<(3200000 + 255) / 256, 256, 0, stream>>>((const float4*)uf, (const float4*)itf,
                                                    (float4*)emba);
  k_tw<<<32, 256, 0, stream>>>(UIu, UIi, W1u, W1i, UITBu, UITBi, UIBu, UIBi, W1Bu, W1Bi);

  // fused layers (attention-first + buffer-reuse gather), 2-wave blocks
  k_layer<<<6250, 128, 0, stream>>>(emba, embb, total, adj, off, cnt, dinv,
                                    UITBu, UITBi, UIBu, UIBi, 0);
  k_layer<<<6250, 128, 0, stream>>>(embb, emba, total, adj, off, cnt, dinv,
                                    UITBu, UITBi, UIBu, UIBi, 1);

  // metapath: gather z into reused emba (graphs 0,1) / embb (graphs 2,3), then MFMA MLP score
  k_mp_gather<<<dim3(6250, 4), 256, 0, stream>>>(uf, itf, adj, off, cnt, oinv, iinv,
                                                 emba, embb);
  k_mp_mlp<<<dim3((NSTRIP + 3) / 4, 4), 256, 0, stream>>>(emba, embb, W1Bu, b1u, w2u,
                                                          W1Bi, b1i, w2i, partials);
  k_beta<<<4, 256, 0, stream>>>(partials, wsum);

  k_h2out<<<3072, 256, 0, stream>>>(emba, embb, user_idx, item_idx, neg_idx, total,
                                    wsum, out, e1u, e2u, e1i, e2i, pos);

  k_gemm<<<dim3(16, 64, 2), 256, 0, stream>>>(e1u, e2u, e1i, e2i, sumexp);
  k_loss<<<1, 256, 0, stream>>>(sumexp, pos, out);
}

// Round 8
// 1135.149 us; speedup vs baseline: 1.0601x; 1.0407x over previous
//
#include <hip/hip_runtime.h>
#include <math.h>

// ---------------- problem constants ----------------
#define NUSERS   100000
#define NITEMS   100000
#define NNODES   200000
#define DD       64
#define NI       128
#define E_UI     1000000
#define E_MP     500000
#define BB       4096
#define NSTRIP   6250          // 100000 / 16

// ---------------- workspace layout (float/int elements, 4B each) ----------------
#define O_CNT       0LL
#define O_OUTCNT    600000LL
#define O_CURSOR    1000000LL
#define O_PARTIALS  1600000LL   // 25000 used (4 graphs x 6250 strips)
#define O_UITB_U    1625600LL   // 4096 f32 slots = 8192 bf16 (UI^T j-major)
#define O_UITB_I    1629696LL
#define O_UIB_U     1633792LL   // 4096 (UI d-major)
#define O_UIB_I     1637888LL
#define O_W1B_U     1641984LL   // 4096 (W1^T j-major)
#define O_W1B_I     1646080LL
#define O_SUMEXP    1700000LL
#define O_POS       1708192LL
#define ZEND        1716384LL
#define O_OFF       1716384LL
#define O_BSUM      2316448LL
#define O_DINV      2317472LL
#define O_OINV      2517472LL
#define O_IINV      2917472LL
#define O_ADJ       3317472LL
#define O_WSUM      7317472LL
#define O_EMBA      7317480LL   // 12.8M: layer ping; reused as zbuf for mp graphs 0,1
#define O_TOTAL     20117480LL
#define O_EMBB      32917480LL  // 12.8M: layer pong; reused as zbuf for mp graphs 2,3
#define O_E1U       45717480LL  // stored as bf16 shorts
#define O_E2U       45979624LL
#define O_E1I       46241768LL
#define O_E2I       46503912LL

typedef __attribute__((ext_vector_type(8))) short short8;
typedef __attribute__((ext_vector_type(4))) float f32x4;

__device__ __forceinline__ short f2bf(float x) {
  unsigned u = __float_as_uint(x);
  unsigned r = (u + 0x7FFFu + ((u >> 16) & 1u)) >> 16;
  return (short)r;
}

// ---------------- degree histograms ----------------
__global__ void k_hist_main(const int* __restrict__ src, const int* __restrict__ dst,
                            int* __restrict__ cnt) {
  int e = blockIdx.x * 256 + threadIdx.x;
  if (e < E_UI) {
    atomicAdd(&cnt[src[e]], 1);
    atomicAdd(&cnt[NUSERS + dst[e]], 1);
  }
}

__global__ void k_hist_mp(const int* __restrict__ mpu, const int* __restrict__ mpi,
                          int* __restrict__ cnt, int* __restrict__ outcnt) {
  int e = blockIdx.x * 256 + threadIdx.x;
  int g = blockIdx.y;
  if (e < E_MP) {
    const int* base = (g < 2) ? (mpu + (long long)g * 2 * E_MP)
                              : (mpi + (long long)(g - 2) * 2 * E_MP);
    int s = base[e];
    int d = base[E_MP + e];
    atomicAdd(&outcnt[g * NUSERS + s], 1);
    atomicAdd(&cnt[NNODES + g * NUSERS + d], 1);
  }
}

// ---------------- exclusive scan ----------------
__global__ __launch_bounds__(1024) void k_scan1(const int* __restrict__ in, int* __restrict__ out,
                                                int* __restrict__ bsum, int n) {
  __shared__ int s[1024];
  int i = blockIdx.x * 1024 + threadIdx.x;
  int v = (i < n) ? in[i] : 0;
  s[threadIdx.x] = v;
  __syncthreads();
  for (int off = 1; off < 1024; off <<= 1) {
    int x = (threadIdx.x >= off) ? s[threadIdx.x - off] : 0;
    __syncthreads();
    s[threadIdx.x] += x;
    __syncthreads();
  }
  if (i < n) out[i] = s[threadIdx.x] - v;
  if (threadIdx.x == 1023) bsum[blockIdx.x] = s[1023];
}

__global__ __launch_bounds__(1024) void k_scan2(int* __restrict__ bsum, int nb) {
  __shared__ int s[1024];
  int v = (threadIdx.x < nb) ? bsum[threadIdx.x] : 0;
  s[threadIdx.x] = v;
  __syncthreads();
  for (int off = 1; off < 1024; off <<= 1) {
    int x = (threadIdx.x >= off) ? s[threadIdx.x - off] : 0;
    __syncthreads();
    s[threadIdx.x] += x;
    __syncthreads();
  }
  if (threadIdx.x < nb) bsum[threadIdx.x] = s[threadIdx.x] - v;
}

__global__ __launch_bounds__(1024) void k_scan3(int* __restrict__ out, const int* __restrict__ bsum, int n) {
  int i = blockIdx.x * 1024 + threadIdx.x;
  if (i < n) out[i] += bsum[blockIdx.x];
}

// ---------------- inverse-sqrt degrees ----------------
__global__ void k_inv(const int* __restrict__ cnt, const int* __restrict__ outcnt,
                      float* __restrict__ dinv, float* __restrict__ iinv, float* __restrict__ oinv) {
  int i = blockIdx.x * 256 + threadIdx.x;
  if (i < NNODES) {
    int c = cnt[i]; if (c < 1) c = 1;
    dinv[i] = 1.0f / sqrtf((float)c);
  } else if (i < 600000) {
    int c = cnt[i]; if (c < 1) c = 1;
    iinv[i - NNODES] = 1.0f / sqrtf((float)c);
  }
  if (i < 400000) {
    int c = outcnt[i]; if (c < 1) c = 1;
    oinv[i] = 1.0f / sqrtf((float)c);
  }
}

// ---------------- CSR scatter ----------------
__global__ void k_scatter_main(const int* __restrict__ src, const int* __restrict__ dst,
                               const int* __restrict__ off, int* __restrict__ cursor,
                               int* __restrict__ adj) {
  int e = blockIdx.x * 256 + threadIdx.x;
  if (e < E_UI) {
    int u = src[e];
    int it = NUSERS + dst[e];
    int p = atomicAdd(&cursor[u], 1);
    adj[off[u] + p] = it;
    int q = atomicAdd(&cursor[it], 1);
    adj[off[it] + q] = u;
  }
}

__global__ void k_scatter_mp(const int* __restrict__ mpu, const int* __restrict__ mpi,
                             const int* __restrict__ off, int* __restrict__ cursor,
                             int* __restrict__ adj) {
  int e = blockIdx.x * 256 + threadIdx.x;
  int g = blockIdx.y;
  if (e < E_MP) {
    const int* base = (g < 2) ? (mpu + (long long)g * 2 * E_MP)
                              : (mpi + (long long)(g - 2) * 2 * E_MP);
    int s = base[e];
    int d = base[E_MP + e];
    int node = NNODES + g * NUSERS + d;
    int p = atomicAdd(&cursor[node], 1);
    adj[off[node] + p] = s;
  }
}

// ---------------- emb init ----------------
__global__ void k_init(const float4* __restrict__ uf, const float4* __restrict__ itf,
                       float4* __restrict__ emb) {
  int i = blockIdx.x * 256 + threadIdx.x;
  if (i < 3200000) {
    emb[i] = (i < 1600000) ? uf[i] : itf[i - 1600000];
  }
}

// ---------------- weight prep (bf16 variants) ----------------
__global__ void k_tw(const float* __restrict__ UIu, const float* __restrict__ UIi,
                     const float* __restrict__ W1u, const float* __restrict__ W1i,
                     short* __restrict__ UITBu, short* __restrict__ UITBi,
                     short* __restrict__ UIBu,  short* __restrict__ UIBi,
                     short* __restrict__ W1Bu,  short* __restrict__ W1Bi) {
  int t = blockIdx.x * 256 + threadIdx.x;
  if (t < 8192) {
    int d = t >> 7, j = t & 127;
    UITBu[j * 64 + d] = f2bf(UIu[t]);
    UITBi[j * 64 + d] = f2bf(UIi[t]);
    UIBu[t] = f2bf(UIu[t]);
    UIBi[t] = f2bf(UIi[t]);
    W1Bu[j * 64 + d] = f2bf(W1u[t]);
    W1Bi[j * 64 + d] = f2bf(W1i[t]);
  }
}

// ---------------- 8-row accumulate via readlane (wave-uniform broadcast -> SGPR base) ----------------
// Best for deg ~10 full-wave rows (k_layer): scalar-base loads, no LDS-pipe bpermute on
// the address path. [R0/R2: 189-193 us; shfl/float4 form regressed to 219.]
// Runtime-rem version (fallback for deg > 24).
__device__ __forceinline__ float acc8(const float* __restrict__ tbl, int miv, float mwv,
                                      int rem, int lane, float acc) {
  unsigned wb = __float_as_uint(mwv);
  for (int k = 0; k < rem; k += 8) {
    int n0 = __builtin_amdgcn_readlane(miv, k + 0);
    int n1 = __builtin_amdgcn_readlane(miv, k + 1);
    int n2 = __builtin_amdgcn_readlane(miv, k + 2);
    int n3 = __builtin_amdgcn_readlane(miv, k + 3);
    int n4 = __builtin_amdgcn_readlane(miv, k + 4);
    int n5 = __builtin_amdgcn_readlane(miv, k + 5);
    int n6 = __builtin_amdgcn_readlane(miv, k + 6);
    int n7 = __builtin_amdgcn_readlane(miv, k + 7);
    float w0 = __uint_as_float(__builtin_amdgcn_readlane(wb, k + 0));
    float w1 = __uint_as_float(__builtin_amdgcn_readlane(wb, k + 1));
    float w2 = __uint_as_float(__builtin_amdgcn_readlane(wb, k + 2));
    float w3 = __uint_as_float(__builtin_amdgcn_readlane(wb, k + 3));
    float w4 = __uint_as_float(__builtin_amdgcn_readlane(wb, k + 4));
    float w5 = __uint_as_float(__builtin_amdgcn_readlane(wb, k + 5));
    float w6 = __uint_as_float(__builtin_amdgcn_readlane(wb, k + 6));
    float w7 = __uint_as_float(__builtin_amdgcn_readlane(wb, k + 7));
    float v0 = tbl[((long long)n0 << 6) + lane], v1 = tbl[((long long)n1 << 6) + lane];
    float v2 = tbl[((long long)n2 << 6) + lane], v3 = tbl[((long long)n3 << 6) + lane];
    float v4 = tbl[((long long)n4 << 6) + lane], v5 = tbl[((long long)n5 << 6) + lane];
    float v6 = tbl[((long long)n6 << 6) + lane], v7 = tbl[((long long)n7 << 6) + lane];
    acc += w0 * v0; acc += w1 * v1; acc += w2 * v2; acc += w3 * v3;
    acc += w4 * v4; acc += w5 * v5; acc += w6 * v6; acc += w7 * v7;
  }
  return acc;
}

// Fixed-trip straight-line version: all R loads issue back-to-back (no runtime loop
// boundary), ~2x outstanding loads. Padded lanes carry mi=0/mw=0 -> exact +0 adds,
// summation order identical to runtime version.
template <int R>
__device__ __forceinline__ float acc8f(const float* __restrict__ tbl, int miv, float mwv,
                                       int lane) {
  unsigned wb = __float_as_uint(mwv);
  float acc = 0.0f;
#pragma unroll
  for (int k = 0; k < R; k += 8) {
    int n0 = __builtin_amdgcn_readlane(miv, k + 0);
    int n1 = __builtin_amdgcn_readlane(miv, k + 1);
    int n2 = __builtin_amdgcn_readlane(miv, k + 2);
    int n3 = __builtin_amdgcn_readlane(miv, k + 3);
    int n4 = __builtin_amdgcn_readlane(miv, k + 4);
    int n5 = __builtin_amdgcn_readlane(miv, k + 5);
    int n6 = __builtin_amdgcn_readlane(miv, k + 6);
    int n7 = __builtin_amdgcn_readlane(miv, k + 7);
    float w0 = __uint_as_float(__builtin_amdgcn_readlane(wb, k + 0));
    float w1 = __uint_as_float(__builtin_amdgcn_readlane(wb, k + 1));
    float w2 = __uint_as_float(__builtin_amdgcn_readlane(wb, k + 2));
    float w3 = __uint_as_float(__builtin_amdgcn_readlane(wb, k + 3));
    float w4 = __uint_as_float(__builtin_amdgcn_readlane(wb, k + 4));
    float w5 = __uint_as_float(__builtin_amdgcn_readlane(wb, k + 5));
    float w6 = __uint_as_float(__builtin_amdgcn_readlane(wb, k + 6));
    float w7 = __uint_as_float(__builtin_amdgcn_readlane(wb, k + 7));
    float v0 = tbl[((long long)n0 << 6) + lane], v1 = tbl[((long long)n1 << 6) + lane];
    float v2 = tbl[((long long)n2 << 6) + lane], v3 = tbl[((long long)n3 << 6) + lane];
    float v4 = tbl[((long long)n4 << 6) + lane], v5 = tbl[((long long)n5 << 6) + lane];
    float v6 = tbl[((long long)n6 << 6) + lane], v7 = tbl[((long long)n7 << 6) + lane];
    acc += w0 * v0; acc += w1 * v1; acc += w2 * v2; acc += w3 * v3;
    acc += w4 * v4; acc += w5 * v5; acc += w6 * v6; acc += w7 * v7;
  }
  return acc;
}

// tail for degree > 64 (rare)
__device__ __forceinline__ float gather_tail(const float* __restrict__ tbl,
                                             const int* __restrict__ adj,
                                             int start, int c,
                                             const float* __restrict__ warr, int wofs,
                                             int lane, float acc) {
  for (int kb = 64; kb < c; kb += 64) {
    int rem = c - kb; if (rem > 64) rem = 64;
    int ti = 0; float tw = 0.0f;
    if (lane < rem) { ti = adj[start + kb + lane]; tw = warr[wofs + ti]; }
    acc = acc8(tbl, ti, tw, rem, lane, acc);
  }
  return acc;
}

// Tiered dispatch: wave-uniform scalar branch to straight-line bodies.
// Poisson(10): P(c<=8)=0.33, P(<=16)=0.97, P(<=24)=0.9996.
__device__ __forceinline__ float gather_node(const float* __restrict__ tbl,
                                             const int* __restrict__ adj,
                                             int ofs, int c, int miv, float mwv,
                                             const float* __restrict__ warr, int wofs,
                                             int lane) {
  if (c <= 8)  return acc8f<8>(tbl, miv, mwv, lane);
  if (c <= 16) return acc8f<16>(tbl, miv, mwv, lane);
  if (c <= 24) return acc8f<24>(tbl, miv, mwv, lane);
  int rem = c < 64 ? c : 64;
  float acc = acc8(tbl, miv, mwv, rem, lane, 0.0f);
  if (c > 64) acc = gather_tail(tbl, adj, ofs, c, warr, wofs, lane, acc);
  return acc;
}

// ---------------- float4 group gather (16-lane group owns a row, lane loads 16B) ----------------
// Best for deg ~5 overhead-bound gathers (k_mp_gather). [R1: -65 us @ 4 nodes/wave;
// R2: 8 nodes/wave regressed -> keep 4.] Runtime-rem fallback.
__device__ __forceinline__ void acc4x(const float* __restrict__ tbl, int miv, float mwv,
                                      int rem, int grp, int dq, f32x4& acc) {
  for (int k = 0; k < rem; k += 16) {
    int s0 = k + grp, s1 = k + 4 + grp, s2 = k + 8 + grp, s3 = k + 12 + grp;
    int n0 = __shfl(miv, s0), n1 = __shfl(miv, s1);
    int n2 = __shfl(miv, s2), n3 = __shfl(miv, s3);
    float w0 = __shfl(mwv, s0), w1 = __shfl(mwv, s1);
    float w2 = __shfl(mwv, s2), w3 = __shfl(mwv, s3);
    float4 v0 = *(const float4*)(tbl + ((long long)n0 << 6) + dq);
    float4 v1 = *(const float4*)(tbl + ((long long)n1 << 6) + dq);
    float4 v2 = *(const float4*)(tbl + ((long long)n2 << 6) + dq);
    float4 v3 = *(const float4*)(tbl + ((long long)n3 << 6) + dq);
    acc.x += w0 * v0.x; acc.y += w0 * v0.y; acc.z += w0 * v0.z; acc.w += w0 * v0.w;
    acc.x += w1 * v1.x; acc.y += w1 * v1.y; acc.z += w1 * v1.z; acc.w += w1 * v1.w;
    acc.x += w2 * v2.x; acc.y += w2 * v2.y; acc.z += w2 * v2.z; acc.w += w2 * v2.w;
    acc.x += w3 * v3.x; acc.y += w3 * v3.y; acc.z += w3 * v3.z; acc.w += w3 * v3.w;
  }
}

__device__ __forceinline__ void gather_tail4(const float* __restrict__ tbl,
                                             const int* __restrict__ adj,
                                             int start, int c,
                                             const float* __restrict__ warr, int wofs,
                                             int lane, int grp, int dq, f32x4& acc) {
  for (int kb = 64; kb < c; kb += 64) {
    int rem = c - kb; if (rem > 64) rem = 64;
    int ti = 0; float tw = 0.0f;
    if (lane < rem) { ti = adj[start + kb + lane]; tw = warr[wofs + ti]; }
    acc4x(tbl, ti, tw, rem, grp, dq, acc);
  }
}

__device__ __forceinline__ float bcastf(float x) {
  return __uint_as_float(__builtin_amdgcn_readfirstlane(__float_as_uint(x)));
}

// ---------------- fused layer: spmm + MFMA intent attention + residual + total ----------------
// Block = 2 waves; wave = one 16-node strip (16 | 100000 so strips never straddle sides).
// sZ: gathered gnn rows (dim-major). sP: exp(S) rows as bf16 (node-major, stride 136 shorts).
// No __syncthreads needed: all LDS producer/consumer pairs are same-wave.
// LDS = 17.4K/block -> 9 blocks/CU = 18 waves.
// [R4 config measured: 180 us, VGPR 44, no spill, total 1133. R5 (shared-buffer reorder,
//  bounds 7) spilled -> 212; R6 (split prefetch, bounds 5) exposed chain -> 203.
//  Conclusion: latency-chain-bound past ~45% occupancy; this is the proven best point.]
__global__ __launch_bounds__(128, 4) void k_layer(
    const float* __restrict__ ecur, float* __restrict__ enext, float* __restrict__ total,
    const int* __restrict__ adj, const int* __restrict__ off, const int* __restrict__ cnt,
    const float* __restrict__ dinv,
    const short* __restrict__ UITBu, const short* __restrict__ UITBi,
    const short* __restrict__ UIBu,  const short* __restrict__ UIBi, int layer) {
  __shared__ float sZ[2][16 * 68];
  __shared__ short sP[2][16 * 136];
  int w = threadIdx.x >> 6, lane = threadIdx.x & 63;
  int nb = blockIdx.x * 32 + w * 16;
  const short* UITB = (nb < NUSERS) ? UITBu : UITBi;
  const short* UIB  = (nb < NUSERS) ? UIBu  : UIBi;
  float* rowZ = sZ[w];
  short* rowP = sP[w];
  int quad = lane >> 4, mrow = lane & 15;

  // ---- hoisted phase-1 row load + bf16 convert (overlaps gather latency) ----
  const float* vrow = ecur + (((long long)(nb + mrow)) << 6) + quad * 8;
  float4 va0 = *(const float4*)(vrow);
  float4 va1 = *(const float4*)(vrow + 4);
  float4 vc0 = *(const float4*)(vrow + 32);
  float4 vc1 = *(const float4*)(vrow + 36);
  short8 a0 = { f2bf(va0.x), f2bf(va0.y), f2bf(va0.z), f2bf(va0.w),
                f2bf(va1.x), f2bf(va1.y), f2bf(va1.z), f2bf(va1.w) };
  short8 a1 = { f2bf(vc0.x), f2bf(vc0.y), f2bf(vc0.z), f2bf(vc0.w),
                f2bf(vc1.x), f2bf(vc1.y), f2bf(vc1.z), f2bf(vc1.w) };

  // ---- gather: gnn rows -> sZ, single 16-node prefetch batch + tiered bodies ----
  {
    int ofs[16], cns[16];
    float dn[16];
    int mi[16]; float mw[16];
#pragma unroll
    for (int m = 0; m < 16; m++) {
      ofs[m] = __builtin_amdgcn_readfirstlane(off[nb + m]);
      cns[m] = __builtin_amdgcn_readfirstlane(cnt[nb + m]);
      dn[m]  = bcastf(dinv[nb + m]);
    }
#pragma unroll
    for (int m = 0; m < 16; m++)
      mi[m] = (lane < cns[m]) ? adj[ofs[m] + lane] : 0;
#pragma unroll
    for (int m = 0; m < 16; m++)
      mw[m] = (lane < cns[m]) ? dinv[mi[m]] : 0.0f;
#pragma unroll
    for (int m = 0; m < 16; m++) {
      float acc = gather_node(ecur, adj, ofs[m], cns[m], mi[m], mw[m], dinv, 0, lane);
      rowZ[m * 68 + lane] = dn[m] * acc;
    }
  }

  // ---- phase 1: S = v @ UI ; P = exp(S) -> sP (bf16) ; den per node ----
  float den0 = 0.f, den1 = 0.f, den2 = 0.f, den3 = 0.f;
  short* pw = rowP + (quad * 4) * 136 + mrow;
#pragma unroll
  for (int jt = 0; jt < 8; jt++) {
    const short* wr = UITB + ((jt * 16 + mrow) << 6) + quad * 8;
    short8 b0 = *(const short8*)(wr);
    short8 bh = *(const short8*)(wr + 32);
    f32x4 acc = {0.f, 0.f, 0.f, 0.f};
    acc = __builtin_amdgcn_mfma_f32_16x16x32_bf16(a0, b0, acc, 0, 0, 0);
    acc = __builtin_amdgcn_mfma_f32_16x16x32_bf16(a1, bh, acc, 0, 0, 0);
    float e0 = __expf(acc[0]), e1 = __expf(acc[1]);
    float e2 = __expf(acc[2]), e3 = __expf(acc[3]);
    den0 += e0; den1 += e1; den2 += e2; den3 += e3;
    short* pj = pw + jt * 16;
    pj[0] = f2bf(e0); pj[136] = f2bf(e1); pj[272] = f2bf(e2); pj[408] = f2bf(e3);
  }
  for (int mask = 1; mask <= 8; mask <<= 1) {
    den0 += __shfl_xor(den0, mask); den1 += __shfl_xor(den1, mask);
    den2 += __shfl_xor(den2, mask); den3 += __shfl_xor(den3, mask);
  }
  float rd0 = 1.f / den0, rd1 = 1.f / den1, rd2 = 1.f / den2, rd3 = 1.f / den3;

  // ---- phase 2: O = P @ UI^T (K=128) ; combine + store ----
#pragma unroll
  for (int dt = 0; dt < 4; dt++) {
    f32x4 acc = {0.f, 0.f, 0.f, 0.f};
#pragma unroll
    for (int c = 0; c < 4; c++) {
      const short* pr = rowP + mrow * 136 + c * 32 + quad * 8;
      short8 af = *(const short8*)(pr);
      const short* br = UIB + ((dt * 16 + mrow) << 7) + c * 32 + quad * 8;
      short8 bf = *(const short8*)(br);
      acc = __builtin_amdgcn_mfma_f32_16x16x32_bf16(af, bf, acc, 0, 0, 0);
    }
    int d = dt * 16 + mrow;
#define COMB(r, rd)                                                            \
    { int node = nb + quad * 4 + r;                                            \
      long long base = (((long long)node) << 6) + d;                           \
      float o = acc[r] * rd;                                                   \
      float gn = rowZ[(quad * 4 + r) * 68 + d];                                \
      float vv = ecur[base];                                                   \
      float ne = gn + o + vv;                                                  \
      enext[base] = ne;                                                        \
      total[base] = (layer == 0) ? (vv + ne) : (total[base] + ne); }
    COMB(0, rd0) COMB(1, rd1) COMB(2, rd2) COMB(3, rd3)
#undef COMB
  }
}

// ---------------- metapath graphconv gather: z (x iinv) -> zbuf ----------------
// 4 nodes per wave, float4 group-gather; fixed-16 straight-line fast path
// (Poisson(5): P(c<=16)=0.9998).
__global__ __launch_bounds__(256, 6) void k_mp_gather(
    const float* __restrict__ uf, const float* __restrict__ itf,
    const int* __restrict__ adj, const int* __restrict__ off, const int* __restrict__ cnt,
    const float* __restrict__ oinv, const float* __restrict__ iinv,
    float* __restrict__ zu, float* __restrict__ zi) {
  int g = blockIdx.y;
  const float* feat = (g < 2) ? uf : itf;
  float* zb = (g < 2) ? zu + ((long long)g * NUSERS << 6)
                      : zi + ((long long)(g - 2) * NUSERS << 6);
  int w = threadIdx.x >> 6, lane = threadIdx.x & 63;
  int n0 = (blockIdx.x * 4 + w) * 4;
  int gofs = g * NUSERS;
  int grp = lane >> 4, dq = (lane & 15) << 2;
  int ofs[4], cns[4];
  float iv[4];
  int mi[4]; float mw[4];
#pragma unroll
  for (int m = 0; m < 4; m++) {
    int node = NNODES + gofs + n0 + m;
    ofs[m] = __builtin_amdgcn_readfirstlane(off[node]);
    cns[m] = __builtin_amdgcn_readfirstlane(cnt[node]);
    iv[m]  = bcastf(iinv[gofs + n0 + m]);
  }
#pragma unroll
  for (int m = 0; m < 4; m++)
    mi[m] = (lane < cns[m]) ? adj[ofs[m] + lane] : 0;
#pragma unroll
  for (int m = 0; m < 4; m++)
    mw[m] = (lane < cns[m]) ? oinv[gofs + mi[m]] : 0.0f;
#pragma unroll
  for (int m = 0; m < 4; m++) {
    int c = cns[m];
    f32x4 acc = {0.f, 0.f, 0.f, 0.f};
    if (c <= 16) {
      acc4x(feat, mi[m], mw[m], 16, grp, dq, acc);   // compile-time trip -> unrolled
    } else {
      int rem = c < 64 ? c : 64;
      acc4x(feat, mi[m], mw[m], rem, grp, dq, acc);
      if (c > 64) gather_tail4(feat, adj, ofs[m], c, oinv, gofs, lane, grp, dq, acc);
    }
    acc.x += __shfl_xor(acc.x, 16); acc.y += __shfl_xor(acc.y, 16);
    acc.z += __shfl_xor(acc.z, 16); acc.w += __shfl_xor(acc.w, 16);
    acc.x += __shfl_xor(acc.x, 32); acc.y += __shfl_xor(acc.y, 32);
    acc.z += __shfl_xor(acc.z, 32); acc.w += __shfl_xor(acc.w, 32);
    if (lane < 16) {
      float s = iv[m];
      float4 o = { acc.x * s, acc.y * s, acc.z * s, acc.w * s };
      *(float4*)&zb[((long long)(n0 + m) << 6) + dq] = o;
    }
  }
}

// ---------------- metapath MLP score via MFMA ----------------
__global__ __launch_bounds__(256, 4) void k_mp_mlp(
    const float* __restrict__ zu, const float* __restrict__ zi,
    const short* __restrict__ W1Bu, const float* __restrict__ b1u, const float* __restrict__ w2u,
    const short* __restrict__ W1Bi, const float* __restrict__ b1i, const float* __restrict__ w2i,
    float* __restrict__ partials) {
  int g = blockIdx.y;
  const short* W1B = (g < 2) ? W1Bu : W1Bi;
  const float* b1  = (g < 2) ? b1u : b1i;
  const float* w2  = (g < 2) ? w2u : w2i;
  const float* zb  = (g < 2) ? zu + ((long long)g * NUSERS << 6)
                             : zi + ((long long)(g - 2) * NUSERS << 6);
  int w = threadIdx.x >> 6, lane = threadIdx.x & 63;
  int strip = blockIdx.x * 4 + w;
  if (strip >= NSTRIP) return;
  int quad = lane >> 4, mrow = lane & 15;
  const float* zrow = zb + (((long long)(strip * 16 + mrow)) << 6) + quad * 8;
  float4 za0 = *(const float4*)(zrow);
  float4 za1 = *(const float4*)(zrow + 4);
  float4 zc0 = *(const float4*)(zrow + 32);
  float4 zc1 = *(const float4*)(zrow + 36);
  short8 a0 = { f2bf(za0.x), f2bf(za0.y), f2bf(za0.z), f2bf(za0.w),
                f2bf(za1.x), f2bf(za1.y), f2bf(za1.z), f2bf(za1.w) };
  short8 a1 = { f2bf(zc0.x), f2bf(zc0.y), f2bf(zc0.z), f2bf(zc0.w),
                f2bf(zc1.x), f2bf(zc1.y), f2bf(zc1.z), f2bf(zc1.w) };
  float psum = 0.0f;
#pragma unroll
  for (int jt = 0; jt < 8; jt++) {
    const short* wr = W1B + ((jt * 16 + mrow) << 6) + quad * 8;
    short8 b0 = *(const short8*)(wr);
    short8 bh = *(const short8*)(wr + 32);
    f32x4 acc = {0.f, 0.f, 0.f, 0.f};
    acc = __builtin_amdgcn_mfma_f32_16x16x32_bf16(a0, b0, acc, 0, 0, 0);
    acc = __builtin_amdgcn_mfma_f32_16x16x32_bf16(a1, bh, acc, 0, 0, 0);
    int j = jt * 16 + mrow;
    float bj = b1[j], wj = w2[j];
#pragma unroll
    for (int r = 0; r < 4; r++) {
      float s = acc[r] + bj;
      psum += wj * (1.0f - 2.0f / (__expf(2.0f * s) + 1.0f));
    }
  }
  for (int m = 32; m; m >>= 1) psum += __shfl_xor(psum, m);
  if (lane == 0) partials[g * NSTRIP + strip] = psum;
}

__global__ void k_beta(const float* __restrict__ partials, float* __restrict__ wsum) {
  int g = blockIdx.x;
  float s = 0.0f;
  for (int i = threadIdx.x; i < NSTRIP; i += 256) s += partials[g * NSTRIP + i];
  for (int m = 32; m; m >>= 1) s += __shfl_xor(s, m);
  __shared__ float r[4];
  if ((threadIdx.x & 63) == 0) r[threadIdx.x >> 6] = s;
  __syncthreads();
  if (threadIdx.x == 0) wsum[g] = r[0] + r[1] + r[2] + r[3];
}

// ---------------- gather outputs + ssl embedding prep (z precomputed) ----------------
// e1/e2 stored as bf16 for the MFMA similarity GEMM.
__global__ __launch_bounds__(256) void k_h2out(
    const float* __restrict__ zu, const float* __restrict__ zi,
    const int* __restrict__ user_idx, const int* __restrict__ item_idx, const int* __restrict__ neg_idx,
    const float* __restrict__ total,
    const float* __restrict__ wsum, float* __restrict__ out,
    short* __restrict__ e1u, short* __restrict__ e2u,
    short* __restrict__ e1i, short* __restrict__ e2i, float* __restrict__ pos) {
  int lane = threadIdx.x & 63;
  int row = (blockIdx.x << 2) + (threadIdx.x >> 6);
  int seg = row >> 12;
  int r = row & 4095;
  int idx;
  const float* zb;
  int gbase;
  if (seg == 0)      { idx = user_idx[r]; zb = zu; gbase = 0; }
  else if (seg == 1) { idx = item_idx[r]; zb = zi; gbase = 2; }
  else               { idx = neg_idx[r];  zb = zi; gbase = 2; }
  int tnode = gbase ? (NUSERS + idx) : idx;
  float t = total[((long long)tnode << 6) + lane];
  float w0 = wsum[gbase] * (1.0f / 100000.0f);
  float w1 = wsum[gbase + 1] * (1.0f / 100000.0f);
  float mb = fmaxf(w0, w1);
  float b0 = expf(w0 - mb), b1 = expf(w1 - mb);
  float bs = b0 + b1;
  b0 /= bs; b1 /= bs;
  float z0 = zb[((long long)idx << 6) + lane];
  float z1 = zb[(((long long)NUSERS + idx) << 6) + lane];
  float h2 = b0 * z0 + b1 * z1;
  out[((long long)row << 6) + lane] = 0.5f * t + 0.5f * h2;
  if (seg < 2) {
    float n1 = h2 * h2, n2 = t * t;
    for (int m = 32; m; m >>= 1) { n1 += __shfl_xor(n1, m); n2 += __shfl_xor(n2, m); }
    n1 = sqrtf(n1); n2 = sqrtf(n2);
    float a = h2 / n1, b = t / n2;
    float d = a * b;
    for (int m = 32; m; m >>= 1) d += __shfl_xor(d, m);
    short* e1 = seg ? e1i : e1u;
    short* e2 = seg ? e2i : e2u;
    e1[((long long)r << 6) + lane] = f2bf(a);
    e2[((long long)r << 6) + lane] = f2bf(b);
    if (lane == 0) pos[seg * BB + r] = 2.0f * d;
  }
}

// ---------------- ssl similarity via MFMA: wave = 64 rows x 64 cols of S ----------------
__global__ __launch_bounds__(256) void k_gemm(const short* __restrict__ e1u, const short* __restrict__ e2u,
                                              const short* __restrict__ e1i, const short* __restrict__ e2i,
                                              float* __restrict__ sumexp) {
  int side = blockIdx.z;
  const short* A = side ? e1i : e1u;
  const short* B = side ? e2i : e2u;
  int w = threadIdx.x >> 6, lane = threadIdx.x & 63;
  int quad = lane >> 4, mrow = lane & 15;
  int rbase = blockIdx.y * 64;
  int cbase = blockIdx.x * 256 + w * 64;

  short8 a0[4], a1[4], b0[4], b1[4];
#pragma unroll
  for (int ri = 0; ri < 4; ri++) {
    const short* ar = A + ((long long)(rbase + ri * 16 + mrow) << 6) + quad * 8;
    a0[ri] = *(const short8*)ar;
    a1[ri] = *(const short8*)(ar + 32);
  }
#pragma unroll
  for (int ci = 0; ci < 4; ci++) {
    const short* br = B + ((long long)(cbase + ci * 16 + mrow) << 6) + quad * 8;
    b0[ci] = *(const short8*)br;
    b1[ci] = *(const short8*)(br + 32);
  }
  float rs0[4] = {0.f, 0.f, 0.f, 0.f};
  float rs1[4] = {0.f, 0.f, 0.f, 0.f};
  float rs2[4] = {0.f, 0.f, 0.f, 0.f};
  float rs3[4] = {0.f, 0.f, 0.f, 0.f};
#pragma unroll
  for (int ri = 0; ri < 4; ri++) {
#pragma unroll
    for (int ci = 0; ci < 4; ci++) {
      f32x4 acc = {0.f, 0.f, 0.f, 0.f};
      acc = __builtin_amdgcn_mfma_f32_16x16x32_bf16(a0[ri], b0[ci], acc, 0, 0, 0);
      acc = __builtin_amdgcn_mfma_f32_16x16x32_bf16(a1[ri], b1[ci], acc, 0, 0, 0);
      float e0 = __expf(2.0f * acc[0]);
      float e1 = __expf(2.0f * acc[1]);
      float e2 = __expf(2.0f * acc[2]);
      float e3 = __expf(2.0f * acc[3]);
      if (ri == 0) { rs0[0] += e0; rs0[1] += e1; rs0[2] += e2; rs0[3] += e3; }
      if (ri == 1) { rs1[0] += e0; rs1[1] += e1; rs1[2] += e2; rs1[3] += e3; }
      if (ri == 2) { rs2[0] += e0; rs2[1] += e1; rs2[2] += e2; rs2[3] += e3; }
      if (ri == 3) { rs3[0] += e0; rs3[1] += e1; rs3[2] += e2; rs3[3] += e3; }
    }
  }
#pragma unroll
  for (int mask = 1; mask <= 8; mask <<= 1) {
#pragma unroll
    for (int r = 0; r < 4; r++) {
      rs0[r] += __shfl_xor(rs0[r], mask);
      rs1[r] += __shfl_xor(rs1[r], mask);
      rs2[r] += __shfl_xor(rs2[r], mask);
      rs3[r] += __shfl_xor(rs3[r], mask);
    }
  }
  if (mrow == 0) {
    float* sb = sumexp + side * BB + rbase + quad * 4;
#pragma unroll
    for (int r = 0; r < 4; r++) {
      __hip_atomic_fetch_add(&sb[r], rs0[r], __ATOMIC_RELAXED, __HIP_MEMORY_SCOPE_AGENT);
      __hip_atomic_fetch_add(&sb[16 + r], rs1[r], __ATOMIC_RELAXED, __HIP_MEMORY_SCOPE_AGENT);
      __hip_atomic_fetch_add(&sb[32 + r], rs2[r], __ATOMIC_RELAXED, __HIP_MEMORY_SCOPE_AGENT);
      __hip_atomic_fetch_add(&sb[48 + r], rs3[r], __ATOMIC_RELAXED, __HIP_MEMORY_SCOPE_AGENT);
    }
  }
}

__global__ void k_loss(const float* __restrict__ sumexp, const float* __restrict__ pos,
                       float* __restrict__ out) {
  float s = 0.0f;
  for (int i = threadIdx.x; i < 2 * BB; i += 256) s += logf(sumexp[i]) - pos[i];
  for (int m = 32; m; m >>= 1) s += __shfl_xor(s, m);
  __shared__ float r[4];
  if ((threadIdx.x & 63) == 0) r[threadIdx.x >> 6] = s;
  __syncthreads();
  if (threadIdx.x == 0) out[3 * BB * DD] = (r[0] + r[1] + r[2] + r[3]) * (1.0f / (float)BB);
}

// ---------------- launch ----------------
extern "C" void kernel_launch(void* const* d_in, const int* in_sizes, int n_in,
                              void* d_out, int out_size, void* d_ws, size_t ws_size,
                              hipStream_t stream) {
  const float* uf  = (const float*)d_in[0];
  const float* itf = (const float*)d_in[1];
  const float* UIu = (const float*)d_in[2];
  const float* UIi = (const float*)d_in[3];
  const float* W1u = (const float*)d_in[4];
  const float* b1u = (const float*)d_in[5];
  const float* w2u = (const float*)d_in[6];
  const float* W1i = (const float*)d_in[7];
  const float* b1i = (const float*)d_in[8];
  const float* w2i = (const float*)d_in[9];
  const int* ui_src   = (const int*)d_in[10];
  const int* ui_dst   = (const int*)d_in[11];
  const int* mpu      = (const int*)d_in[12];
  const int* mpi      = (const int*)d_in[13];
  const int* user_idx = (const int*)d_in[14];
  const int* item_idx = (const int*)d_in[15];
  const int* neg_idx  = (const int*)d_in[16];
  float* out = (float*)d_out;

  float* wf = (float*)d_ws;
  int*   wi = (int*)d_ws;

  int*   cnt      = wi + O_CNT;
  int*   outcnt   = wi + O_OUTCNT;
  int*   cursor   = wi + O_CURSOR;
  float* partials = wf + O_PARTIALS;
  short* UITBu    = (short*)(wf + O_UITB_U);
  short* UITBi    = (short*)(wf + O_UITB_I);
  short* UIBu     = (short*)(wf + O_UIB_U);
  short* UIBi     = (short*)(wf + O_UIB_I);
  short* W1Bu     = (short*)(wf + O_W1B_U);
  short* W1Bi     = (short*)(wf + O_W1B_I);
  float* sumexp   = wf + O_SUMEXP;
  float* pos      = wf + O_POS;
  int*   off      = wi + O_OFF;
  int*   bsum     = wi + O_BSUM;
  float* dinv     = wf + O_DINV;
  float* oinv     = wf + O_OINV;
  float* iinv     = wf + O_IINV;
  int*   adj      = wi + O_ADJ;
  float* wsum     = wf + O_WSUM;
  float* emba     = wf + O_EMBA;
  float* total    = wf + O_TOTAL;
  float* embb     = wf + O_EMBB;
  short* e1u      = (short*)(wf + O_E1U);
  short* e2u      = (short*)(wf + O_E2U);
  short* e1i      = (short*)(wf + O_E1I);
  short* e2i      = (short*)(wf + O_E2I);

  hipMemsetAsync(d_ws, 0, (size_t)ZEND * 4, stream);

  k_hist_main<<<(E_UI + 255) / 256, 256, 0, stream>>>(ui_src, ui_dst, cnt);
  k_hist_mp<<<dim3((E_MP + 255) / 256, 4), 256, 0, stream>>>(mpu, mpi, cnt, outcnt);

  const int NSCAN = 600000;
  const int NB = (NSCAN + 1023) / 1024;
  k_scan1<<<NB, 1024, 0, stream>>>(cnt, off, bsum, NSCAN);
  k_scan2<<<1, 1024, 0, stream>>>(bsum, NB);
  k_scan3<<<NB, 1024, 0, stream>>>(off, bsum, NSCAN);

  k_inv<<<(600000 + 255) / 256, 256, 0, stream>>>(cnt, outcnt, dinv, iinv, oinv);

  k_scatter_main<<<(E_UI + 255) / 256, 256, 0, stream>>>(ui_src, ui_dst, off, cursor, adj);
  k_scatter_mp<<<dim3((E_MP + 255) / 256, 4), 256, 0, stream>>>(mpu, mpi, off, cursor, adj);

  k_init<<<(3200000 + 255) / 256, 256, 0, stream>>>((const float4*)uf, (const float4*)itf,
                                                    (float4*)emba);
  k_tw<<<32, 256, 0, stream>>>(UIu, UIi, W1u, W1i, UITBu, UITBi, UIBu, UIBi, W1Bu, W1Bi);

  // fused layers (spmm + MFMA attention + residual + total), 2-wave blocks
  k_layer<<<6250, 128, 0, stream>>>(emba, embb, total, adj, off, cnt, dinv,
                                    UITBu, UITBi, UIBu, UIBi, 0);
  k_layer<<<6250, 128, 0, stream>>>(embb, emba, total, adj, off, cnt, dinv,
                                    UITBu, UITBi, UIBu, UIBi, 1);

  // metapath: gather z into reused emba (graphs 0,1) / embb (graphs 2,3), then MFMA MLP score
  k_mp_gather<<<dim3(6250, 4), 256, 0, stream>>>(uf, itf, adj, off, cnt, oinv, iinv,
                                                 emba, embb);
  k_mp_mlp<<<dim3((NSTRIP + 3) / 4, 4), 256, 0, stream>>>(emba, embb, W1Bu, b1u, w2u,
                                                          W1Bi, b1i, w2i, partials);
  k_beta<<<4, 256, 0, stream>>>(partials, wsum);

  k_h2out<<<3072, 256, 0, stream>>>(emba, embb, user_idx, item_idx, neg_idx, total,
                                    wsum, out, e1u, e2u, e1i, e2i, pos);

  k_gemm<<<dim3(16, 64, 2), 256, 0, stream>>>(e1u, e2u, e1i, e2i, sumexp);
  k_loss<<<1, 256, 0, stream>>>(sumexp, pos, out);
}

// Round 10
// 1124.639 us; speedup vs baseline: 1.0700x; 1.0093x over previous
//
#include <hip/hip_runtime.h>
#include <math.h>

// ---------------- problem constants ----------------
#define NUSERS   100000
#define NITEMS   100000
#define NNODES   200000
#define DD       64
#define NI       128
#define E_UI     1000000
#define E_MP     500000
#define BB       4096
#define NSTRIP   6250          // 100000 / 16

// ---------------- workspace layout (float/int elements, 4B each) ----------------
#define O_CNT       0LL
#define O_OUTCNT    600000LL
#define O_CURSOR    1000000LL
#define O_PARTIALS  1600000LL   // 25000 used (4 graphs x 6250 strips)
#define O_UITB_U    1625600LL   // 4096 f32 slots = 8192 bf16 (UI^T j-major)
#define O_UITB_I    1629696LL
#define O_UIB_U     1633792LL   // 4096 (UI d-major)
#define O_UIB_I     1637888LL
#define O_W1B_U     1641984LL   // 4096 (W1^T j-major)
#define O_W1B_I     1646080LL
#define O_SUMEXP    1700000LL
#define O_POS       1708192LL
#define ZEND        1716384LL
#define O_OFF       1716384LL
#define O_BSUM      2316448LL
#define O_DINV      2317472LL
#define O_OINV      2517472LL
#define O_IINV      2917472LL
#define O_ADJ       3317472LL
#define O_WSUM      7317472LL
#define O_EMBA      7317480LL   // 12.8M: layer ping; reused as zbuf for mp graphs 0,1
#define O_TOTAL     20117480LL
#define O_EMBB      32917480LL  // 12.8M: layer pong; reused as zbuf for mp graphs 2,3
#define O_E1U       45717480LL  // stored as bf16 shorts
#define O_E2U       45979624LL
#define O_E1I       46241768LL
#define O_E2I       46503912LL

typedef __attribute__((ext_vector_type(8))) short short8;
typedef __attribute__((ext_vector_type(4))) float f32x4;

__device__ __forceinline__ short f2bf(float x) {
  unsigned u = __float_as_uint(x);
  unsigned r = (u + 0x7FFFu + ((u >> 16) & 1u)) >> 16;
  return (short)r;
}

// ---------------- degree histograms ----------------
__global__ void k_hist_main(const int* __restrict__ src, const int* __restrict__ dst,
                            int* __restrict__ cnt) {
  int e = blockIdx.x * 256 + threadIdx.x;
  if (e < E_UI) {
    atomicAdd(&cnt[src[e]], 1);
    atomicAdd(&cnt[NUSERS + dst[e]], 1);
  }
}

__global__ void k_hist_mp(const int* __restrict__ mpu, const int* __restrict__ mpi,
                          int* __restrict__ cnt, int* __restrict__ outcnt) {
  int e = blockIdx.x * 256 + threadIdx.x;
  int g = blockIdx.y;
  if (e < E_MP) {
    const int* base = (g < 2) ? (mpu + (long long)g * 2 * E_MP)
                              : (mpi + (long long)(g - 2) * 2 * E_MP);
    int s = base[e];
    int d = base[E_MP + e];
    atomicAdd(&outcnt[g * NUSERS + s], 1);
    atomicAdd(&cnt[NNODES + g * NUSERS + d], 1);
  }
}

// ---------------- exclusive scan ----------------
__global__ __launch_bounds__(1024) void k_scan1(const int* __restrict__ in, int* __restrict__ out,
                                                int* __restrict__ bsum, int n) {
  __shared__ int s[1024];
  int i = blockIdx.x * 1024 + threadIdx.x;
  int v = (i < n) ? in[i] : 0;
  s[threadIdx.x] = v;
  __syncthreads();
  for (int off = 1; off < 1024; off <<= 1) {
    int x = (threadIdx.x >= off) ? s[threadIdx.x - off] : 0;
    __syncthreads();
    s[threadIdx.x] += x;
    __syncthreads();
  }
  if (i < n) out[i] = s[threadIdx.x] - v;
  if (threadIdx.x == 1023) bsum[blockIdx.x] = s[1023];
}

__global__ __launch_bounds__(1024) void k_scan2(int* __restrict__ bsum, int nb) {
  __shared__ int s[1024];
  int v = (threadIdx.x < nb) ? bsum[threadIdx.x] : 0;
  s[threadIdx.x] = v;
  __syncthreads();
  for (int off = 1; off < 1024; off <<= 1) {
    int x = (threadIdx.x >= off) ? s[threadIdx.x - off] : 0;
    __syncthreads();
    s[threadIdx.x] += x;
    __syncthreads();
  }
  if (threadIdx.x < nb) bsum[threadIdx.x] = s[threadIdx.x] - v;
}

__global__ __launch_bounds__(1024) void k_scan3(int* __restrict__ out, const int* __restrict__ bsum, int n) {
  int i = blockIdx.x * 1024 + threadIdx.x;
  if (i < n) out[i] += bsum[blockIdx.x];
}

// ---------------- inverse-sqrt degrees ----------------
__global__ void k_inv(const int* __restrict__ cnt, const int* __restrict__ outcnt,
                      float* __restrict__ dinv, float* __restrict__ iinv, float* __restrict__ oinv) {
  int i = blockIdx.x * 256 + threadIdx.x;
  if (i < NNODES) {
    int c = cnt[i]; if (c < 1) c = 1;
    dinv[i] = 1.0f / sqrtf((float)c);
  } else if (i < 600000) {
    int c = cnt[i]; if (c < 1) c = 1;
    iinv[i - NNODES] = 1.0f / sqrtf((float)c);
  }
  if (i < 400000) {
    int c = outcnt[i]; if (c < 1) c = 1;
    oinv[i] = 1.0f / sqrtf((float)c);
  }
}

// ---------------- CSR scatter ----------------
__global__ void k_scatter_main(const int* __restrict__ src, const int* __restrict__ dst,
                               const int* __restrict__ off, int* __restrict__ cursor,
                               int* __restrict__ adj) {
  int e = blockIdx.x * 256 + threadIdx.x;
  if (e < E_UI) {
    int u = src[e];
    int it = NUSERS + dst[e];
    int p = atomicAdd(&cursor[u], 1);
    adj[off[u] + p] = it;
    int q = atomicAdd(&cursor[it], 1);
    adj[off[it] + q] = u;
  }
}

__global__ void k_scatter_mp(const int* __restrict__ mpu, const int* __restrict__ mpi,
                             const int* __restrict__ off, int* __restrict__ cursor,
                             int* __restrict__ adj) {
  int e = blockIdx.x * 256 + threadIdx.x;
  int g = blockIdx.y;
  if (e < E_MP) {
    const int* base = (g < 2) ? (mpu + (long long)g * 2 * E_MP)
                              : (mpi + (long long)(g - 2) * 2 * E_MP);
    int s = base[e];
    int d = base[E_MP + e];
    int node = NNODES + g * NUSERS + d;
    int p = atomicAdd(&cursor[node], 1);
    adj[off[node] + p] = s;
  }
}

// ---------------- emb init ----------------
__global__ void k_init(const float4* __restrict__ uf, const float4* __restrict__ itf,
                       float4* __restrict__ emb) {
  int i = blockIdx.x * 256 + threadIdx.x;
  if (i < 3200000) {
    emb[i] = (i < 1600000) ? uf[i] : itf[i - 1600000];
  }
}

// ---------------- weight prep (bf16 variants) ----------------
__global__ void k_tw(const float* __restrict__ UIu, const float* __restrict__ UIi,
                     const float* __restrict__ W1u, const float* __restrict__ W1i,
                     short* __restrict__ UITBu, short* __restrict__ UITBi,
                     short* __restrict__ UIBu,  short* __restrict__ UIBi,
                     short* __restrict__ W1Bu,  short* __restrict__ W1Bi) {
  int t = blockIdx.x * 256 + threadIdx.x;
  if (t < 8192) {
    int d = t >> 7, j = t & 127;
    UITBu[j * 64 + d] = f2bf(UIu[t]);
    UITBi[j * 64 + d] = f2bf(UIi[t]);
    UIBu[t] = f2bf(UIu[t]);
    UIBi[t] = f2bf(UIi[t]);
    W1Bu[j * 64 + d] = f2bf(W1u[t]);
    W1Bi[j * 64 + d] = f2bf(W1i[t]);
  }
}

// ---------------- 8-row accumulate via readlane (wave-uniform broadcast -> SGPR base) ----------------
// Best for deg ~10 full-wave rows (k_layer): scalar-base loads, no LDS-pipe bpermute on
// the address path. Runtime-rem version (fallback for deg > 24).
__device__ __forceinline__ float acc8(const float* __restrict__ tbl, int miv, float mwv,
                                      int rem, int lane, float acc) {
  unsigned wb = __float_as_uint(mwv);
  for (int k = 0; k < rem; k += 8) {
    int n0 = __builtin_amdgcn_readlane(miv, k + 0);
    int n1 = __builtin_amdgcn_readlane(miv, k + 1);
    int n2 = __builtin_amdgcn_readlane(miv, k + 2);
    int n3 = __builtin_amdgcn_readlane(miv, k + 3);
    int n4 = __builtin_amdgcn_readlane(miv, k + 4);
    int n5 = __builtin_amdgcn_readlane(miv, k + 5);
    int n6 = __builtin_amdgcn_readlane(miv, k + 6);
    int n7 = __builtin_amdgcn_readlane(miv, k + 7);
    float w0 = __uint_as_float(__builtin_amdgcn_readlane(wb, k + 0));
    float w1 = __uint_as_float(__builtin_amdgcn_readlane(wb, k + 1));
    float w2 = __uint_as_float(__builtin_amdgcn_readlane(wb, k + 2));
    float w3 = __uint_as_float(__builtin_amdgcn_readlane(wb, k + 3));
    float w4 = __uint_as_float(__builtin_amdgcn_readlane(wb, k + 4));
    float w5 = __uint_as_float(__builtin_amdgcn_readlane(wb, k + 5));
    float w6 = __uint_as_float(__builtin_amdgcn_readlane(wb, k + 6));
    float w7 = __uint_as_float(__builtin_amdgcn_readlane(wb, k + 7));
    float v0 = tbl[((long long)n0 << 6) + lane], v1 = tbl[((long long)n1 << 6) + lane];
    float v2 = tbl[((long long)n2 << 6) + lane], v3 = tbl[((long long)n3 << 6) + lane];
    float v4 = tbl[((long long)n4 << 6) + lane], v5 = tbl[((long long)n5 << 6) + lane];
    float v6 = tbl[((long long)n6 << 6) + lane], v7 = tbl[((long long)n7 << 6) + lane];
    acc += w0 * v0; acc += w1 * v1; acc += w2 * v2; acc += w3 * v3;
    acc += w4 * v4; acc += w5 * v5; acc += w6 * v6; acc += w7 * v7;
  }
  return acc;
}

// Fixed-trip straight-line version: all R loads issue back-to-back (no runtime loop
// boundary). Padded lanes carry mi=0/mw=0 -> exact +0 adds, order identical.
template <int R>
__device__ __forceinline__ float acc8f(const float* __restrict__ tbl, int miv, float mwv,
                                       int lane) {
  unsigned wb = __float_as_uint(mwv);
  float acc = 0.0f;
#pragma unroll
  for (int k = 0; k < R; k += 8) {
    int n0 = __builtin_amdgcn_readlane(miv, k + 0);
    int n1 = __builtin_amdgcn_readlane(miv, k + 1);
    int n2 = __builtin_amdgcn_readlane(miv, k + 2);
    int n3 = __builtin_amdgcn_readlane(miv, k + 3);
    int n4 = __builtin_amdgcn_readlane(miv, k + 4);
    int n5 = __builtin_amdgcn_readlane(miv, k + 5);
    int n6 = __builtin_amdgcn_readlane(miv, k + 6);
    int n7 = __builtin_amdgcn_readlane(miv, k + 7);
    float w0 = __uint_as_float(__builtin_amdgcn_readlane(wb, k + 0));
    float w1 = __uint_as_float(__builtin_amdgcn_readlane(wb, k + 1));
    float w2 = __uint_as_float(__builtin_amdgcn_readlane(wb, k + 2));
    float w3 = __uint_as_float(__builtin_amdgcn_readlane(wb, k + 3));
    float w4 = __uint_as_float(__builtin_amdgcn_readlane(wb, k + 4));
    float w5 = __uint_as_float(__builtin_amdgcn_readlane(wb, k + 5));
    float w6 = __uint_as_float(__builtin_amdgcn_readlane(wb, k + 6));
    float w7 = __uint_as_float(__builtin_amdgcn_readlane(wb, k + 7));
    float v0 = tbl[((long long)n0 << 6) + lane], v1 = tbl[((long long)n1 << 6) + lane];
    float v2 = tbl[((long long)n2 << 6) + lane], v3 = tbl[((long long)n3 << 6) + lane];
    float v4 = tbl[((long long)n4 << 6) + lane], v5 = tbl[((long long)n5 << 6) + lane];
    float v6 = tbl[((long long)n6 << 6) + lane], v7 = tbl[((long long)n7 << 6) + lane];
    acc += w0 * v0; acc += w1 * v1; acc += w2 * v2; acc += w3 * v3;
    acc += w4 * v4; acc += w5 * v5; acc += w6 * v6; acc += w7 * v7;
  }
  return acc;
}

// tail for degree > 64 (rare)
__device__ __forceinline__ float gather_tail(const float* __restrict__ tbl,
                                             const int* __restrict__ adj,
                                             int start, int c,
                                             const float* __restrict__ warr, int wofs,
                                             int lane, float acc) {
  for (int kb = 64; kb < c; kb += 64) {
    int rem = c - kb; if (rem > 64) rem = 64;
    int ti = 0; float tw = 0.0f;
    if (lane < rem) { ti = adj[start + kb + lane]; tw = warr[wofs + ti]; }
    acc = acc8(tbl, ti, tw, rem, lane, acc);
  }
  return acc;
}

// Per-node tiered dispatch (fallback when the wave-level fused paths don't apply).
__device__ __forceinline__ float gather_node(const float* __restrict__ tbl,
                                             const int* __restrict__ adj,
                                             int ofs, int c, int miv, float mwv,
                                             const float* __restrict__ warr, int wofs,
                                             int lane) {
  if (c <= 8)  return acc8f<8>(tbl, miv, mwv, lane);
  if (c <= 16) return acc8f<16>(tbl, miv, mwv, lane);
  if (c <= 24) return acc8f<24>(tbl, miv, mwv, lane);
  int rem = c < 64 ? c : 64;
  float acc = acc8(tbl, miv, mwv, rem, lane, 0.0f);
  if (c > 64) acc = gather_tail(tbl, adj, ofs, c, warr, wofs, lane, acc);
  return acc;
}

// ---------------- float4 group gather (16-lane group owns a row, lane loads 16B) ----------------
// Best for deg ~5 overhead-bound gathers (k_mp_gather). Runtime-rem fallback.
__device__ __forceinline__ void acc4x(const float* __restrict__ tbl, int miv, float mwv,
                                      int rem, int grp, int dq, f32x4& acc) {
  for (int k = 0; k < rem; k += 16) {
    int s0 = k + grp, s1 = k + 4 + grp, s2 = k + 8 + grp, s3 = k + 12 + grp;
    int n0 = __shfl(miv, s0), n1 = __shfl(miv, s1);
    int n2 = __shfl(miv, s2), n3 = __shfl(miv, s3);
    float w0 = __shfl(mwv, s0), w1 = __shfl(mwv, s1);
    float w2 = __shfl(mwv, s2), w3 = __shfl(mwv, s3);
    float4 v0 = *(const float4*)(tbl + ((long long)n0 << 6) + dq);
    float4 v1 = *(const float4*)(tbl + ((long long)n1 << 6) + dq);
    float4 v2 = *(const float4*)(tbl + ((long long)n2 << 6) + dq);
    float4 v3 = *(const float4*)(tbl + ((long long)n3 << 6) + dq);
    acc.x += w0 * v0.x; acc.y += w0 * v0.y; acc.z += w0 * v0.z; acc.w += w0 * v0.w;
    acc.x += w1 * v1.x; acc.y += w1 * v1.y; acc.z += w1 * v1.z; acc.w += w1 * v1.w;
    acc.x += w2 * v2.x; acc.y += w2 * v2.y; acc.z += w2 * v2.z; acc.w += w2 * v2.w;
    acc.x += w3 * v3.x; acc.y += w3 * v3.y; acc.z += w3 * v3.z; acc.w += w3 * v3.w;
  }
}

// Fixed-trip straight-line variant (compile-time single iteration for deg <= 16).
__device__ __forceinline__ void acc4f16(const float* __restrict__ tbl, int miv, float mwv,
                                        int grp, int dq, f32x4& acc) {
  int s0 = grp, s1 = 4 + grp, s2 = 8 + grp, s3 = 12 + grp;
  int n0 = __shfl(miv, s0), n1 = __shfl(miv, s1);
  int n2 = __shfl(miv, s2), n3 = __shfl(miv, s3);
  float w0 = __shfl(mwv, s0), w1 = __shfl(mwv, s1);
  float w2 = __shfl(mwv, s2), w3 = __shfl(mwv, s3);
  float4 v0 = *(const float4*)(tbl + ((long long)n0 << 6) + dq);
  float4 v1 = *(const float4*)(tbl + ((long long)n1 << 6) + dq);
  float4 v2 = *(const float4*)(tbl + ((long long)n2 << 6) + dq);
  float4 v3 = *(const float4*)(tbl + ((long long)n3 << 6) + dq);
  acc.x += w0 * v0.x; acc.y += w0 * v0.y; acc.z += w0 * v0.z; acc.w += w0 * v0.w;
  acc.x += w1 * v1.x; acc.y += w1 * v1.y; acc.z += w1 * v1.z; acc.w += w1 * v1.w;
  acc.x += w2 * v2.x; acc.y += w2 * v2.y; acc.z += w2 * v2.z; acc.w += w2 * v2.w;
  acc.x += w3 * v3.x; acc.y += w3 * v3.y; acc.z += w3 * v3.z; acc.w += w3 * v3.w;
}

__device__ __forceinline__ void gather_tail4(const float* __restrict__ tbl,
                                             const int* __restrict__ adj,
                                             int start, int c,
                                             const float* __restrict__ warr, int wofs,
                                             int lane, int grp, int dq, f32x4& acc) {
  for (int kb = 64; kb < c; kb += 64) {
    int rem = c - kb; if (rem > 64) rem = 64;
    int ti = 0; float tw = 0.0f;
    if (lane < rem) { ti = adj[start + kb + lane]; tw = warr[wofs + ti]; }
    acc4x(tbl, ti, tw, rem, grp, dq, acc);
  }
}

__device__ __forceinline__ float bcastf(float x) {
  return __uint_as_float(__builtin_amdgcn_readfirstlane(__float_as_uint(x)));
}

// ---------------- fused layer: spmm + MFMA intent attention + residual + total ----------------
// Block = 2 waves; wave = one 16-node strip (16 | 100000 so strips never straddle sides).
// sZ: gathered gnn rows (dim-major). sP: exp(S) rows as bf16 (node-major, stride 136 shorts).
// No __syncthreads needed: all LDS producer/consumer pairs are same-wave.
// LDS = 17.4K/block -> 18 waves/CU cap; proven best structural point (R4: 180us, no spill).
// R8 change: WAVE-LEVEL fused gather. The per-node tier branches fenced load scheduling
// (only ~8-16 loads in flight, VGPR 44). Hoisting the branch to wave granularity lets the
// compiler issue all 16 nodes' loads straight-line (cross-node ILP). Poisson(10):
// P(all 16 <= 16) ~ 0.65, P(all <= 24) ~ 0.995; fallback per-node path ~0.5% of waves.
// Padded slots add exact +0.0f -> bit-identical output.
__global__ __launch_bounds__(128, 4) void k_layer(
    const float* __restrict__ ecur, float* __restrict__ enext, float* __restrict__ total,
    const int* __restrict__ adj, const int* __restrict__ off, const int* __restrict__ cnt,
    const float* __restrict__ dinv,
    const short* __restrict__ UITBu, const short* __restrict__ UITBi,
    const short* __restrict__ UIBu,  const short* __restrict__ UIBi, int layer) {
  __shared__ float sZ[2][16 * 68];
  __shared__ short sP[2][16 * 136];
  int w = threadIdx.x >> 6, lane = threadIdx.x & 63;
  int nb = blockIdx.x * 32 + w * 16;
  const short* UITB = (nb < NUSERS) ? UITBu : UITBi;
  const short* UIB  = (nb < NUSERS) ? UIBu  : UIBi;
  float* rowZ = sZ[w];
  short* rowP = sP[w];
  int quad = lane >> 4, mrow = lane & 15;

  // ---- hoisted phase-1 row load + bf16 convert (overlaps gather latency) ----
  const float* vrow = ecur + (((long long)(nb + mrow)) << 6) + quad * 8;
  float4 va0 = *(const float4*)(vrow);
  float4 va1 = *(const float4*)(vrow + 4);
  float4 vc0 = *(const float4*)(vrow + 32);
  float4 vc1 = *(const float4*)(vrow + 36);
  short8 a0 = { f2bf(va0.x), f2bf(va0.y), f2bf(va0.z), f2bf(va0.w),
                f2bf(va1.x), f2bf(va1.y), f2bf(va1.z), f2bf(va1.w) };
  short8 a1 = { f2bf(vc0.x), f2bf(vc0.y), f2bf(vc0.z), f2bf(vc0.w),
                f2bf(vc1.x), f2bf(vc1.y), f2bf(vc1.z), f2bf(vc1.w) };

  // ---- gather: gnn rows -> sZ, single 16-node prefetch batch + wave-level fused bodies ----
  {
    int ofs[16], cns[16];
    float dn[16];
    int mi[16]; float mw[16];
    int cmax = 0;
#pragma unroll
    for (int m = 0; m < 16; m++) {
      ofs[m] = __builtin_amdgcn_readfirstlane(off[nb + m]);
      cns[m] = __builtin_amdgcn_readfirstlane(cnt[nb + m]);
      dn[m]  = bcastf(dinv[nb + m]);
      cmax = cns[m] > cmax ? cns[m] : cmax;
    }
#pragma unroll
    for (int m = 0; m < 16; m++)
      mi[m] = (lane < cns[m]) ? adj[ofs[m] + lane] : 0;
#pragma unroll
    for (int m = 0; m < 16; m++)
      mw[m] = (lane < cns[m]) ? dinv[mi[m]] : 0.0f;

    if (cmax <= 16) {
      // fused straight-line: 256 loads, no branches between nodes
#pragma unroll
      for (int m = 0; m < 16; m++) {
        float acc = acc8f<16>(ecur, mi[m], mw[m], lane);
        rowZ[m * 68 + lane] = dn[m] * acc;
      }
    } else if (cmax <= 24) {
#pragma unroll
      for (int m = 0; m < 16; m++) {
        float acc = acc8f<24>(ecur, mi[m], mw[m], lane);
        rowZ[m * 68 + lane] = dn[m] * acc;
      }
    } else {
#pragma unroll
      for (int m = 0; m < 16; m++) {
        float acc = gather_node(ecur, adj, ofs[m], cns[m], mi[m], mw[m], dinv, 0, lane);
        rowZ[m * 68 + lane] = dn[m] * acc;
      }
    }
  }

  // ---- phase 1: S = v @ UI ; P = exp(S) -> sP (bf16) ; den per node ----
  float den0 = 0.f, den1 = 0.f, den2 = 0.f, den3 = 0.f;
  short* pw = rowP + (quad * 4) * 136 + mrow;
#pragma unroll
  for (int jt = 0; jt < 8; jt++) {
    const short* wr = UITB + ((jt * 16 + mrow) << 6) + quad * 8;
    short8 b0 = *(const short8*)(wr);
    short8 bh = *(const short8*)(wr + 32);
    f32x4 acc = {0.f, 0.f, 0.f, 0.f};
    acc = __builtin_amdgcn_mfma_f32_16x16x32_bf16(a0, b0, acc, 0, 0, 0);
    acc = __builtin_amdgcn_mfma_f32_16x16x32_bf16(a1, bh, acc, 0, 0, 0);
    float e0 = __expf(acc[0]), e1 = __expf(acc[1]);
    float e2 = __expf(acc[2]), e3 = __expf(acc[3]);
    den0 += e0; den1 += e1; den2 += e2; den3 += e3;
    short* pj = pw + jt * 16;
    pj[0] = f2bf(e0); pj[136] = f2bf(e1); pj[272] = f2bf(e2); pj[408] = f2bf(e3);
  }
  for (int mask = 1; mask <= 8; mask <<= 1) {
    den0 += __shfl_xor(den0, mask); den1 += __shfl_xor(den1, mask);
    den2 += __shfl_xor(den2, mask); den3 += __shfl_xor(den3, mask);
  }
  float rd0 = 1.f / den0, rd1 = 1.f / den1, rd2 = 1.f / den2, rd3 = 1.f / den3;

  // ---- phase 2: O = P @ UI^T (K=128) ; combine + store ----
#pragma unroll
  for (int dt = 0; dt < 4; dt++) {
    f32x4 acc = {0.f, 0.f, 0.f, 0.f};
#pragma unroll
    for (int c = 0; c < 4; c++) {
      const short* pr = rowP + mrow * 136 + c * 32 + quad * 8;
      short8 af = *(const short8*)(pr);
      const short* br = UIB + ((dt * 16 + mrow) << 7) + c * 32 + quad * 8;
      short8 bf = *(const short8*)(br);
      acc = __builtin_amdgcn_mfma_f32_16x16x32_bf16(af, bf, acc, 0, 0, 0);
    }
    int d = dt * 16 + mrow;
#define COMB(r, rd)                                                            \
    { int node = nb + quad * 4 + r;                                            \
      long long base = (((long long)node) << 6) + d;                           \
      float o = acc[r] * rd;                                                   \
      float gn = rowZ[(quad * 4 + r) * 68 + d];                                \
      float vv = ecur[base];                                                   \
      float ne = gn + o + vv;                                                  \
      enext[base] = ne;                                                        \
      total[base] = (layer == 0) ? (vv + ne) : (total[base] + ne); }
    COMB(0, rd0) COMB(1, rd1) COMB(2, rd2) COMB(3, rd3)
#undef COMB
  }
}

// ---------------- metapath graphconv gather: z (x iinv) -> zbuf ----------------
// 4 nodes per wave, float4 group-gather; wave-level fused fast path
// (Poisson(5): P(all 4 <= 16) ~ 0.9999).
__global__ __launch_bounds__(256, 6) void k_mp_gather(
    const float* __restrict__ uf, const float* __restrict__ itf,
    const int* __restrict__ adj, const int* __restrict__ off, const int* __restrict__ cnt,
    const float* __restrict__ oinv, const float* __restrict__ iinv,
    float* __restrict__ zu, float* __restrict__ zi) {
  int g = blockIdx.y;
  const float* feat = (g < 2) ? uf : itf;
  float* zb = (g < 2) ? zu + ((long long)g * NUSERS << 6)
                      : zi + ((long long)(g - 2) * NUSERS << 6);
  int w = threadIdx.x >> 6, lane = threadIdx.x & 63;
  int n0 = (blockIdx.x * 4 + w) * 4;
  int gofs = g * NUSERS;
  int grp = lane >> 4, dq = (lane & 15) << 2;
  int ofs[4], cns[4];
  float iv[4];
  int mi[4]; float mw[4];
  int cmax = 0;
#pragma unroll
  for (int m = 0; m < 4; m++) {
    int node = NNODES + gofs + n0 + m;
    ofs[m] = __builtin_amdgcn_readfirstlane(off[node]);
    cns[m] = __builtin_amdgcn_readfirstlane(cnt[node]);
    iv[m]  = bcastf(iinv[gofs + n0 + m]);
    cmax = cns[m] > cmax ? cns[m] : cmax;
  }
#pragma unroll
  for (int m = 0; m < 4; m++)
    mi[m] = (lane < cns[m]) ? adj[ofs[m] + lane] : 0;
#pragma unroll
  for (int m = 0; m < 4; m++)
    mw[m] = (lane < cns[m]) ? oinv[gofs + mi[m]] : 0.0f;

  f32x4 za[4];
  if (cmax <= 16) {
    // fused straight-line: all 4 nodes' loads issue without intervening branches
#pragma unroll
    for (int m = 0; m < 4; m++) {
      f32x4 acc = {0.f, 0.f, 0.f, 0.f};
      acc4f16(feat, mi[m], mw[m], grp, dq, acc);
      za[m] = acc;
    }
  } else {
#pragma unroll
    for (int m = 0; m < 4; m++) {
      int c = cns[m];
      f32x4 acc = {0.f, 0.f, 0.f, 0.f};
      if (c <= 16) {
        acc4f16(feat, mi[m], mw[m], grp, dq, acc);
      } else {
        int rem = c < 64 ? c : 64;
        acc4x(feat, mi[m], mw[m], rem, grp, dq, acc);
        if (c > 64) gather_tail4(feat, adj, ofs[m], c, oinv, gofs, lane, grp, dq, acc);
      }
      za[m] = acc;
    }
  }
#pragma unroll
  for (int m = 0; m < 4; m++) {
    f32x4 acc = za[m];
    acc.x += __shfl_xor(acc.x, 16); acc.y += __shfl_xor(acc.y, 16);
    acc.z += __shfl_xor(acc.z, 16); acc.w += __shfl_xor(acc.w, 16);
    acc.x += __shfl_xor(acc.x, 32); acc.y += __shfl_xor(acc.y, 32);
    acc.z += __shfl_xor(acc.z, 32); acc.w += __shfl_xor(acc.w, 32);
    if (lane < 16) {
      float s = iv[m];
      float4 o = { acc.x * s, acc.y * s, acc.z * s, acc.w * s };
      *(float4*)&zb[((long long)(n0 + m) << 6) + dq] = o;
    }
  }
}

// ---------------- metapath MLP score via MFMA ----------------
__global__ __launch_bounds__(256, 4) void k_mp_mlp(
    const float* __restrict__ zu, const float* __restrict__ zi,
    const short* __restrict__ W1Bu, const float* __restrict__ b1u, const float* __restrict__ w2u,
    const short* __restrict__ W1Bi, const float* __restrict__ b1i, const float* __restrict__ w2i,
    float* __restrict__ partials) {
  int g = blockIdx.y;
  const short* W1B = (g < 2) ? W1Bu : W1Bi;
  const float* b1  = (g < 2) ? b1u : b1i;
  const float* w2  = (g < 2) ? w2u : w2i;
  const float* zb  = (g < 2) ? zu + ((long long)g * NUSERS << 6)
                             : zi + ((long long)(g - 2) * NUSERS << 6);
  int w = threadIdx.x >> 6, lane = threadIdx.x & 63;
  int strip = blockIdx.x * 4 + w;
  if (strip >= NSTRIP) return;
  int quad = lane >> 4, mrow = lane & 15;
  const float* zrow = zb + (((long long)(strip * 16 + mrow)) << 6) + quad * 8;
  float4 za0 = *(const float4*)(zrow);
  float4 za1 = *(const float4*)(zrow + 4);
  float4 zc0 = *(const float4*)(zrow + 32);
  float4 zc1 = *(const float4*)(zrow + 36);
  short8 a0 = { f2bf(za0.x), f2bf(za0.y), f2bf(za0.z), f2bf(za0.w),
                f2bf(za1.x), f2bf(za1.y), f2bf(za1.z), f2bf(za1.w) };
  short8 a1 = { f2bf(zc0.x), f2bf(zc0.y), f2bf(zc0.z), f2bf(zc0.w),
                f2bf(zc1.x), f2bf(zc1.y), f2bf(zc1.z), f2bf(zc1.w) };
  float psum = 0.0f;
#pragma unroll
  for (int jt = 0; jt < 8; jt++) {
    const short* wr = W1B + ((jt * 16 + mrow) << 6) + quad * 8;
    short8 b0 = *(const short8*)(wr);
    short8 bh = *(const short8*)(wr + 32);
    f32x4 acc = {0.f, 0.f, 0.f, 0.f};
    acc = __builtin_amdgcn_mfma_f32_16x16x32_bf16(a0, b0, acc, 0, 0, 0);
    acc = __builtin_amdgcn_mfma_f32_16x16x32_bf16(a1, bh, acc, 0, 0, 0);
    int j = jt * 16 + mrow;
    float bj = b1[j], wj = w2[j];
#pragma unroll
    for (int r = 0; r < 4; r++) {
      float s = acc[r] + bj;
      psum += wj * (1.0f - 2.0f / (__expf(2.0f * s) + 1.0f));
    }
  }
  for (int m = 32; m; m >>= 1) psum += __shfl_xor(psum, m);
  if (lane == 0) partials[g * NSTRIP + strip] = psum;
}

__global__ void k_beta(const float* __restrict__ partials, float* __restrict__ wsum) {
  int g = blockIdx.x;
  float s = 0.0f;
  for (int i = threadIdx.x; i < NSTRIP; i += 256) s += partials[g * NSTRIP + i];
  for (int m = 32; m; m >>= 1) s += __shfl_xor(s, m);
  __shared__ float r[4];
  if ((threadIdx.x & 63) == 0) r[threadIdx.x >> 6] = s;
  __syncthreads();
  if (threadIdx.x == 0) wsum[g] = r[0] + r[1] + r[2] + r[3];
}

// ---------------- gather outputs + ssl embedding prep (z precomputed) ----------------
// e1/e2 stored as bf16 for the MFMA similarity GEMM.
__global__ __launch_bounds__(256) void k_h2out(
    const float* __restrict__ zu, const float* __restrict__ zi,
    const int* __restrict__ user_idx, const int* __restrict__ item_idx, const int* __restrict__ neg_idx,
    const float* __restrict__ total,
    const float* __restrict__ wsum, float* __restrict__ out,
    short* __restrict__ e1u, short* __restrict__ e2u,
    short* __restrict__ e1i, short* __restrict__ e2i, float* __restrict__ pos) {
  int lane = threadIdx.x & 63;
  int row = (blockIdx.x << 2) + (threadIdx.x >> 6);
  int seg = row >> 12;
  int r = row & 4095;
  int idx;
  const float* zb;
  int gbase;
  if (seg == 0)      { idx = user_idx[r]; zb = zu; gbase = 0; }
  else if (seg == 1) { idx = item_idx[r]; zb = zi; gbase = 2; }
  else               { idx = neg_idx[r];  zb = zi; gbase = 2; }
  int tnode = gbase ? (NUSERS + idx) : idx;
  float t = total[((long long)tnode << 6) + lane];
  float w0 = wsum[gbase] * (1.0f / 100000.0f);
  float w1 = wsum[gbase + 1] * (1.0f / 100000.0f);
  float mb = fmaxf(w0, w1);
  float b0 = expf(w0 - mb), b1 = expf(w1 - mb);
  float bs = b0 + b1;
  b0 /= bs; b1 /= bs;
  float z0 = zb[((long long)idx << 6) + lane];
  float z1 = zb[(((long long)NUSERS + idx) << 6) + lane];
  float h2 = b0 * z0 + b1 * z1;
  out[((long long)row << 6) + lane] = 0.5f * t + 0.5f * h2;
  if (seg < 2) {
    float n1 = h2 * h2, n2 = t * t;
    for (int m = 32; m; m >>= 1) { n1 += __shfl_xor(n1, m); n2 += __shfl_xor(n2, m); }
    n1 = sqrtf(n1); n2 = sqrtf(n2);
    float a = h2 / n1, b = t / n2;
    float d = a * b;
    for (int m = 32; m; m >>= 1) d += __shfl_xor(d, m);
    short* e1 = seg ? e1i : e1u;
    short* e2 = seg ? e2i : e2u;
    e1[((long long)r << 6) + lane] = f2bf(a);
    e2[((long long)r << 6) + lane] = f2bf(b);
    if (lane == 0) pos[seg * BB + r] = 2.0f * d;
  }
}

// ---------------- ssl similarity via MFMA: wave = 64 rows x 64 cols of S ----------------
__global__ __launch_bounds__(256) void k_gemm(const short* __restrict__ e1u, const short* __restrict__ e2u,
                                              const short* __restrict__ e1i, const short* __restrict__ e2i,
                                              float* __restrict__ sumexp) {
  int side = blockIdx.z;
  const short* A = side ? e1i : e1u;
  const short* B = side ? e2i : e2u;
  int w = threadIdx.x >> 6, lane = threadIdx.x & 63;
  int quad = lane >> 4, mrow = lane & 15;
  int rbase = blockIdx.y * 64;
  int cbase = blockIdx.x * 256 + w * 64;

  short8 a0[4], a1[4], b0[4], b1[4];
#pragma unroll
  for (int ri = 0; ri < 4; ri++) {
    const short* ar = A + ((long long)(rbase + ri * 16 + mrow) << 6) + quad * 8;
    a0[ri] = *(const short8*)ar;
    a1[ri] = *(const short8*)(ar + 32);
  }
#pragma unroll
  for (int ci = 0; ci < 4; ci++) {
    const short* br = B + ((long long)(cbase + ci * 16 + mrow) << 6) + quad * 8;
    b0[ci] = *(const short8*)br;
    b1[ci] = *(const short8*)(br + 32);
  }
  float rs0[4] = {0.f, 0.f, 0.f, 0.f};
  float rs1[4] = {0.f, 0.f, 0.f, 0.f};
  float rs2[4] = {0.f, 0.f, 0.f, 0.f};
  float rs3[4] = {0.f, 0.f, 0.f, 0.f};
#pragma unroll
  for (int ri = 0; ri < 4; ri++) {
#pragma unroll
    for (int ci = 0; ci < 4; ci++) {
      f32x4 acc = {0.f, 0.f, 0.f, 0.f};
      acc = __builtin_amdgcn_mfma_f32_16x16x32_bf16(a0[ri], b0[ci], acc, 0, 0, 0);
      acc = __builtin_amdgcn_mfma_f32_16x16x32_bf16(a1[ri], b1[ci], acc, 0, 0, 0);
      float e0 = __expf(2.0f * acc[0]);
      float e1 = __expf(2.0f * acc[1]);
      float e2 = __expf(2.0f * acc[2]);
      float e3 = __expf(2.0f * acc[3]);
      if (ri == 0) { rs0[0] += e0; rs0[1] += e1; rs0[2] += e2; rs0[3] += e3; }
      if (ri == 1) { rs1[0] += e0; rs1[1] += e1; rs1[2] += e2; rs1[3] += e3; }
      if (ri == 2) { rs2[0] += e0; rs2[1] += e1; rs2[2] += e2; rs2[3] += e3; }
      if (ri == 3) { rs3[0] += e0; rs3[1] += e1; rs3[2] += e2; rs3[3] += e3; }
    }
  }
#pragma unroll
  for (int mask = 1; mask <= 8; mask <<= 1) {
#pragma unroll
    for (int r = 0; r < 4; r++) {
      rs0[r] += __shfl_xor(rs0[r], mask);
      rs1[r] += __shfl_xor(rs1[r], mask);
      rs2[r] += __shfl_xor(rs2[r], mask);
      rs3[r] += __shfl_xor(rs3[r], mask);
    }
  }
  if (mrow == 0) {
    float* sb = sumexp + side * BB + rbase + quad * 4;
#pragma unroll
    for (int r = 0; r < 4; r++) {
      __hip_atomic_fetch_add(&sb[r], rs0[r], __ATOMIC_RELAXED, __HIP_MEMORY_SCOPE_AGENT);
      __hip_atomic_fetch_add(&sb[16 + r], rs1[r], __ATOMIC_RELAXED, __HIP_MEMORY_SCOPE_AGENT);
      __hip_atomic_fetch_add(&sb[32 + r], rs2[r], __ATOMIC_RELAXED, __HIP_MEMORY_SCOPE_AGENT);
      __hip_atomic_fetch_add(&sb[48 + r], rs3[r], __ATOMIC_RELAXED, __HIP_MEMORY_SCOPE_AGENT);
    }
  }
}

__global__ void k_loss(const float* __restrict__ sumexp, const float* __restrict__ pos,
                       float* __restrict__ out) {
  float s = 0.0f;
  for (int i = threadIdx.x; i < 2 * BB; i += 256) s += logf(sumexp[i]) - pos[i];
  for (int m = 32; m; m >>= 1) s += __shfl_xor(s, m);
  __shared__ float r[4];
  if ((threadIdx.x & 63) == 0) r[threadIdx.x >> 6] = s;
  __syncthreads();
  if (threadIdx.x == 0) out[3 * BB * DD] = (r[0] + r[1] + r[2] + r[3]) * (1.0f / (float)BB);
}

// ---------------- launch ----------------
extern "C" void kernel_launch(void* const* d_in, const int* in_sizes, int n_in,
                              void* d_out, int out_size, void* d_ws, size_t ws_size,
                              hipStream_t stream) {
  const float* uf  = (const float*)d_in[0];
  const float* itf = (const float*)d_in[1];
  const float* UIu = (const float*)d_in[2];
  const float* UIi = (const float*)d_in[3];
  const float* W1u = (const float*)d_in[4];
  const float* b1u = (const float*)d_in[5];
  const float* w2u = (const float*)d_in[6];
  const float* W1i = (const float*)d_in[7];
  const float* b1i = (const float*)d_in[8];
  const float* w2i = (const float*)d_in[9];
  const int* ui_src   = (const int*)d_in[10];
  const int* ui_dst   = (const int*)d_in[11];
  const int* mpu      = (const int*)d_in[12];
  const int* mpi      = (const int*)d_in[13];
  const int* user_idx = (const int*)d_in[14];
  const int* item_idx = (const int*)d_in[15];
  const int* neg_idx  = (const int*)d_in[16];
  float* out = (float*)d_out;

  float* wf = (float*)d_ws;
  int*   wi = (int*)d_ws;

  int*   cnt      = wi + O_CNT;
  int*   outcnt   = wi + O_OUTCNT;
  int*   cursor   = wi + O_CURSOR;
  float* partials = wf + O_PARTIALS;
  short* UITBu    = (short*)(wf + O_UITB_U);
  short* UITBi    = (short*)(wf + O_UITB_I);
  short* UIBu     = (short*)(wf + O_UIB_U);
  short* UIBi     = (short*)(wf + O_UIB_I);
  short* W1Bu     = (short*)(wf + O_W1B_U);
  short* W1Bi     = (short*)(wf + O_W1B_I);
  float* sumexp   = wf + O_SUMEXP;
  float* pos      = wf + O_POS;
  int*   off      = wi + O_OFF;
  int*   bsum     = wi + O_BSUM;
  float* dinv     = wf + O_DINV;
  float* oinv     = wf + O_OINV;
  float* iinv     = wf + O_IINV;
  int*   adj      = wi + O_ADJ;
  float* wsum     = wf + O_WSUM;
  float* emba     = wf + O_EMBA;
  float* total    = wf + O_TOTAL;
  float* embb     = wf + O_EMBB;
  short* e1u      = (short*)(wf + O_E1U);
  short* e2u      = (short*)(wf + O_E2U);
  short* e1i      = (short*)(wf + O_E1I);
  short* e2i      = (short*)(wf + O_E2I);

  hipMemsetAsync(d_ws, 0, (size_t)ZEND * 4, stream);

  k_hist_main<<<(E_UI + 255) / 256, 256, 0, stream>>>(ui_src, ui_dst, cnt);
  k_hist_mp<<<dim3((E_MP + 255) / 256, 4), 256, 0, stream>>>(mpu, mpi, cnt, outcnt);

  const int NSCAN = 600000;
  const int NB = (NSCAN + 1023) / 1024;
  k_scan1<<<NB, 1024, 0, stream>>>(cnt, off, bsum, NSCAN);
  k_scan2<<<1, 1024, 0, stream>>>(bsum, NB);
  k_scan3<<<NB, 1024, 0, stream>>>(off, bsum, NSCAN);

  k_inv<<<(600000 + 255) / 256, 256, 0, stream>>>(cnt, outcnt, dinv, iinv, oinv);

  k_scatter_main<<<(E_UI + 255) / 256, 256, 0, stream>>>(ui_src, ui_dst, off, cursor, adj);
  k_scatter_mp<<<dim3((E_MP + 255) / 256, 4), 256, 0, stream>>>(mpu, mpi, off, cursor, adj);

  k_init<<<(3200000 + 255) / 256, 256, 0, stream>>>((const float4*)uf, (const float4*)itf,
                                                    (float4*)emba);
  k_tw<<<32, 256, 0, stream>>>(UIu, UIi, W1u, W1i, UITBu, UITBi, UIBu, UIBi, W1Bu, W1Bi);

  // fused layers (spmm + MFMA attention + residual + total), 2-wave blocks
  k_layer<<<6250, 128, 0, stream>>>(emba, embb, total, adj, off, cnt, dinv,
                                    UITBu, UITBi, UIBu, UIBi, 0);
  k_layer<<<6250, 128, 0, stream>>>(embb, emba, total, adj, off, cnt, dinv,
                                    UITBu, UITBi, UIBu, UIBi, 1);

  // metapath: gather z into reused emba (graphs 0,1) / embb (graphs 2,3), then MFMA MLP score
  k_mp_gather<<<dim3(6250, 4), 256, 0, stream>>>(uf, itf, adj, off, cnt, oinv, iinv,
                                                 emba, embb);
  k_mp_mlp<<<dim3((NSTRIP + 3) / 4, 4), 256, 0, stream>>>(emba, embb, W1Bu, b1u, w2u,
                                                          W1Bi, b1i, w2i, partials);
  k_beta<<<4, 256, 0, stream>>>(partials, wsum);

  k_h2out<<<3072, 256, 0, stream>>>(emba, embb, user_idx, item_idx, neg_idx, total,
                                    wsum, out, e1u, e2u, e1i, e2i, pos);

  k_gemm<<<dim3(16, 64, 2), 256, 0, stream>>>(e1u, e2u, e1i, e2i, sumexp);
  k_loss<<<1, 256, 0, stream>>>(sumexp, pos, out);
}

// Round 11
// 1100.888 us; speedup vs baseline: 1.0931x; 1.0216x over previous
//
#include <hip/hip_runtime.h>
#include <math.h>

// ---------------- problem constants ----------------
#define NUSERS   100000
#define NITEMS   100000
#define NNODES   200000
#define DD       64
#define NI       128
#define E_UI     1000000
#define E_MP     500000
#define BB       4096
#define NSTRIP   6250          // 100000 / 16

// ---------------- workspace layout (float/int elements, 4B each) ----------------
#define O_CNT       0LL
#define O_OUTCNT    600000LL
#define O_CURSOR    1000000LL
#define O_PARTIALS  1600000LL   // 25000 used (4 graphs x 6250 strips)
#define O_UITB_U    1625600LL   // 4096 f32 slots = 8192 bf16 (UI^T j-major)
#define O_UITB_I    1629696LL
#define O_UIB_U     1633792LL   // 4096 (UI d-major)
#define O_UIB_I     1637888LL
#define O_W1B_U     1641984LL   // 4096 (W1^T j-major)
#define O_W1B_I     1646080LL
#define O_SUMEXP    1700000LL
#define O_POS       1708192LL
#define ZEND        1716384LL
#define O_OFF       1716384LL
#define O_BSUM      2316448LL
#define O_DINV      2317472LL
#define O_OINV      2517472LL
#define O_IINV      2917472LL
#define O_ADJ       3317472LL
#define O_WSUM      7317472LL
#define O_EMBA      7317480LL   // 12.8M: layer ping; reused as zbuf for mp graphs 0,1
#define O_TOTAL     20117480LL
#define O_EMBB      32917480LL  // 12.8M: layer pong; reused as zbuf for mp graphs 2,3
#define O_E1U       45717480LL  // stored as bf16 shorts
#define O_E2U       45979624LL
#define O_E1I       46241768LL
#define O_E2I       46503912LL

typedef __attribute__((ext_vector_type(8))) short short8;
typedef __attribute__((ext_vector_type(4))) float f32x4;

__device__ __forceinline__ short f2bf(float x) {
  unsigned u = __float_as_uint(x);
  unsigned r = (u + 0x7FFFu + ((u >> 16) & 1u)) >> 16;
  return (short)r;
}

// ---------------- degree histograms ----------------
__global__ void k_hist_main(const int* __restrict__ src, const int* __restrict__ dst,
                            int* __restrict__ cnt) {
  int e = blockIdx.x * 256 + threadIdx.x;
  if (e < E_UI) {
    atomicAdd(&cnt[src[e]], 1);
    atomicAdd(&cnt[NUSERS + dst[e]], 1);
  }
}

__global__ void k_hist_mp(const int* __restrict__ mpu, const int* __restrict__ mpi,
                          int* __restrict__ cnt, int* __restrict__ outcnt) {
  int e = blockIdx.x * 256 + threadIdx.x;
  int g = blockIdx.y;
  if (e < E_MP) {
    const int* base = (g < 2) ? (mpu + (long long)g * 2 * E_MP)
                              : (mpi + (long long)(g - 2) * 2 * E_MP);
    int s = base[e];
    int d = base[E_MP + e];
    atomicAdd(&outcnt[g * NUSERS + s], 1);
    atomicAdd(&cnt[NNODES + g * NUSERS + d], 1);
  }
}

// ---------------- exclusive scan ----------------
__global__ __launch_bounds__(1024) void k_scan1(const int* __restrict__ in, int* __restrict__ out,
                                                int* __restrict__ bsum, int n) {
  __shared__ int s[1024];
  int i = blockIdx.x * 1024 + threadIdx.x;
  int v = (i < n) ? in[i] : 0;
  s[threadIdx.x] = v;
  __syncthreads();
  for (int off = 1; off < 1024; off <<= 1) {
    int x = (threadIdx.x >= off) ? s[threadIdx.x - off] : 0;
    __syncthreads();
    s[threadIdx.x] += x;
    __syncthreads();
  }
  if (i < n) out[i] = s[threadIdx.x] - v;
  if (threadIdx.x == 1023) bsum[blockIdx.x] = s[1023];
}

__global__ __launch_bounds__(1024) void k_scan2(int* __restrict__ bsum, int nb) {
  __shared__ int s[1024];
  int v = (threadIdx.x < nb) ? bsum[threadIdx.x] : 0;
  s[threadIdx.x] = v;
  __syncthreads();
  for (int off = 1; off < 1024; off <<= 1) {
    int x = (threadIdx.x >= off) ? s[threadIdx.x - off] : 0;
    __syncthreads();
    s[threadIdx.x] += x;
    __syncthreads();
  }
  if (threadIdx.x < nb) bsum[threadIdx.x] = s[threadIdx.x] - v;
}

__global__ __launch_bounds__(1024) void k_scan3(int* __restrict__ out, const int* __restrict__ bsum, int n) {
  int i = blockIdx.x * 1024 + threadIdx.x;
  if (i < n) out[i] += bsum[blockIdx.x];
}

// ---------------- inverse-sqrt degrees ----------------
__global__ void k_inv(const int* __restrict__ cnt, const int* __restrict__ outcnt,
                      float* __restrict__ dinv, float* __restrict__ iinv, float* __restrict__ oinv) {
  int i = blockIdx.x * 256 + threadIdx.x;
  if (i < NNODES) {
    int c = cnt[i]; if (c < 1) c = 1;
    dinv[i] = 1.0f / sqrtf((float)c);
  } else if (i < 600000) {
    int c = cnt[i]; if (c < 1) c = 1;
    iinv[i - NNODES] = 1.0f / sqrtf((float)c);
  }
  if (i < 400000) {
    int c = outcnt[i]; if (c < 1) c = 1;
    oinv[i] = 1.0f / sqrtf((float)c);
  }
}

// ---------------- CSR scatter ----------------
__global__ void k_scatter_main(const int* __restrict__ src, const int* __restrict__ dst,
                               const int* __restrict__ off, int* __restrict__ cursor,
                               int* __restrict__ adj) {
  int e = blockIdx.x * 256 + threadIdx.x;
  if (e < E_UI) {
    int u = src[e];
    int it = NUSERS + dst[e];
    int p = atomicAdd(&cursor[u], 1);
    adj[off[u] + p] = it;
    int q = atomicAdd(&cursor[it], 1);
    adj[off[it] + q] = u;
  }
}

__global__ void k_scatter_mp(const int* __restrict__ mpu, const int* __restrict__ mpi,
                             const int* __restrict__ off, int* __restrict__ cursor,
                             int* __restrict__ adj) {
  int e = blockIdx.x * 256 + threadIdx.x;
  int g = blockIdx.y;
  if (e < E_MP) {
    const int* base = (g < 2) ? (mpu + (long long)g * 2 * E_MP)
                              : (mpi + (long long)(g - 2) * 2 * E_MP);
    int s = base[e];
    int d = base[E_MP + e];
    int node = NNODES + g * NUSERS + d;
    int p = atomicAdd(&cursor[node], 1);
    adj[off[node] + p] = s;
  }
}

// ---------------- emb init ----------------
__global__ void k_init(const float4* __restrict__ uf, const float4* __restrict__ itf,
                       float4* __restrict__ emb) {
  int i = blockIdx.x * 256 + threadIdx.x;
  if (i < 3200000) {
    emb[i] = (i < 1600000) ? uf[i] : itf[i - 1600000];
  }
}

// ---------------- weight prep (bf16 variants) ----------------
__global__ void k_tw(const float* __restrict__ UIu, const float* __restrict__ UIi,
                     const float* __restrict__ W1u, const float* __restrict__ W1i,
                     short* __restrict__ UITBu, short* __restrict__ UITBi,
                     short* __restrict__ UIBu,  short* __restrict__ UIBi,
                     short* __restrict__ W1Bu,  short* __restrict__ W1Bi) {
  int t = blockIdx.x * 256 + threadIdx.x;
  if (t < 8192) {
    int d = t >> 7, j = t & 127;
    UITBu[j * 64 + d] = f2bf(UIu[t]);
    UITBi[j * 64 + d] = f2bf(UIi[t]);
    UIBu[t] = f2bf(UIu[t]);
    UIBi[t] = f2bf(UIi[t]);
    W1Bu[j * 64 + d] = f2bf(W1u[t]);
    W1Bi[j * 64 + d] = f2bf(W1i[t]);
  }
}

// ---------------- 8-row accumulate via readlane (wave-uniform broadcast -> SGPR base) ----------------
// Runtime-rem version (fallback for deg > 24).
__device__ __forceinline__ float acc8(const float* __restrict__ tbl, int miv, float mwv,
                                      int rem, int lane, float acc) {
  unsigned wb = __float_as_uint(mwv);
  for (int k = 0; k < rem; k += 8) {
    int n0 = __builtin_amdgcn_readlane(miv, k + 0);
    int n1 = __builtin_amdgcn_readlane(miv, k + 1);
    int n2 = __builtin_amdgcn_readlane(miv, k + 2);
    int n3 = __builtin_amdgcn_readlane(miv, k + 3);
    int n4 = __builtin_amdgcn_readlane(miv, k + 4);
    int n5 = __builtin_amdgcn_readlane(miv, k + 5);
    int n6 = __builtin_amdgcn_readlane(miv, k + 6);
    int n7 = __builtin_amdgcn_readlane(miv, k + 7);
    float w0 = __uint_as_float(__builtin_amdgcn_readlane(wb, k + 0));
    float w1 = __uint_as_float(__builtin_amdgcn_readlane(wb, k + 1));
    float w2 = __uint_as_float(__builtin_amdgcn_readlane(wb, k + 2));
    float w3 = __uint_as_float(__builtin_amdgcn_readlane(wb, k + 3));
    float w4 = __uint_as_float(__builtin_amdgcn_readlane(wb, k + 4));
    float w5 = __uint_as_float(__builtin_amdgcn_readlane(wb, k + 5));
    float w6 = __uint_as_float(__builtin_amdgcn_readlane(wb, k + 6));
    float w7 = __uint_as_float(__builtin_amdgcn_readlane(wb, k + 7));
    float v0 = tbl[((long long)n0 << 6) + lane], v1 = tbl[((long long)n1 << 6) + lane];
    float v2 = tbl[((long long)n2 << 6) + lane], v3 = tbl[((long long)n3 << 6) + lane];
    float v4 = tbl[((long long)n4 << 6) + lane], v5 = tbl[((long long)n5 << 6) + lane];
    float v6 = tbl[((long long)n6 << 6) + lane], v7 = tbl[((long long)n7 << 6) + lane];
    acc += w0 * v0; acc += w1 * v1; acc += w2 * v2; acc += w3 * v3;
    acc += w4 * v4; acc += w5 * v5; acc += w6 * v6; acc += w7 * v7;
  }
  return acc;
}

// Fixed-trip straight-line version: all R loads issue back-to-back (no runtime loop
// boundary). Padded lanes carry mi=0/mw=0 -> exact +0 adds, order identical.
template <int R>
__device__ __forceinline__ float acc8f(const float* __restrict__ tbl, int miv, float mwv,
                                       int lane) {
  unsigned wb = __float_as_uint(mwv);
  float acc = 0.0f;
#pragma unroll
  for (int k = 0; k < R; k += 8) {
    int n0 = __builtin_amdgcn_readlane(miv, k + 0);
    int n1 = __builtin_amdgcn_readlane(miv, k + 1);
    int n2 = __builtin_amdgcn_readlane(miv, k + 2);
    int n3 = __builtin_amdgcn_readlane(miv, k + 3);
    int n4 = __builtin_amdgcn_readlane(miv, k + 4);
    int n5 = __builtin_amdgcn_readlane(miv, k + 5);
    int n6 = __builtin_amdgcn_readlane(miv, k + 6);
    int n7 = __builtin_amdgcn_readlane(miv, k + 7);
    float w0 = __uint_as_float(__builtin_amdgcn_readlane(wb, k + 0));
    float w1 = __uint_as_float(__builtin_amdgcn_readlane(wb, k + 1));
    float w2 = __uint_as_float(__builtin_amdgcn_readlane(wb, k + 2));
    float w3 = __uint_as_float(__builtin_amdgcn_readlane(wb, k + 3));
    float w4 = __uint_as_float(__builtin_amdgcn_readlane(wb, k + 4));
    float w5 = __uint_as_float(__builtin_amdgcn_readlane(wb, k + 5));
    float w6 = __uint_as_float(__builtin_amdgcn_readlane(wb, k + 6));
    float w7 = __uint_as_float(__builtin_amdgcn_readlane(wb, k + 7));
    float v0 = tbl[((long long)n0 << 6) + lane], v1 = tbl[((long long)n1 << 6) + lane];
    float v2 = tbl[((long long)n2 << 6) + lane], v3 = tbl[((long long)n3 << 6) + lane];
    float v4 = tbl[((long long)n4 << 6) + lane], v5 = tbl[((long long)n5 << 6) + lane];
    float v6 = tbl[((long long)n6 << 6) + lane], v7 = tbl[((long long)n7 << 6) + lane];
    acc += w0 * v0; acc += w1 * v1; acc += w2 * v2; acc += w3 * v3;
    acc += w4 * v4; acc += w5 * v5; acc += w6 * v6; acc += w7 * v7;
  }
  return acc;
}

// tail for degree > 64 (rare)
__device__ __forceinline__ float gather_tail(const float* __restrict__ tbl,
                                             const int* __restrict__ adj,
                                             int start, int c,
                                             const float* __restrict__ warr, int wofs,
                                             int lane, float acc) {
  for (int kb = 64; kb < c; kb += 64) {
    int rem = c - kb; if (rem > 64) rem = 64;
    int ti = 0; float tw = 0.0f;
    if (lane < rem) { ti = adj[start + kb + lane]; tw = warr[wofs + ti]; }
    acc = acc8(tbl, ti, tw, rem, lane, acc);
  }
  return acc;
}

// Per-node tiered dispatch (fallback when the wave-level fused paths don't apply).
__device__ __forceinline__ float gather_node(const float* __restrict__ tbl,
                                             const int* __restrict__ adj,
                                             int ofs, int c, int miv, float mwv,
                                             const float* __restrict__ warr, int wofs,
                                             int lane) {
  if (c <= 8)  return acc8f<8>(tbl, miv, mwv, lane);
  if (c <= 16) return acc8f<16>(tbl, miv, mwv, lane);
  if (c <= 24) return acc8f<24>(tbl, miv, mwv, lane);
  int rem = c < 64 ? c : 64;
  float acc = acc8(tbl, miv, mwv, rem, lane, 0.0f);
  if (c > 64) acc = gather_tail(tbl, adj, ofs, c, warr, wofs, lane, acc);
  return acc;
}

__device__ __forceinline__ float bcastf(float x) {
  return __uint_as_float(__builtin_amdgcn_readfirstlane(__float_as_uint(x)));
}

// ---------------- fused layer: spmm + MFMA intent attention + residual + total ----------------
// Block = 2 waves; wave = one 16-node strip. LDS 17.4K/block. Wave-level fused gather
// (R8: VGPR 44->56, 178->170us, hbm 3.15->3.71 TB/s). Proven best point.
__global__ __launch_bounds__(128, 4) void k_layer(
    const float* __restrict__ ecur, float* __restrict__ enext, float* __restrict__ total,
    const int* __restrict__ adj, const int* __restrict__ off, const int* __restrict__ cnt,
    const float* __restrict__ dinv,
    const short* __restrict__ UITBu, const short* __restrict__ UITBi,
    const short* __restrict__ UIBu,  const short* __restrict__ UIBi, int layer) {
  __shared__ float sZ[2][16 * 68];
  __shared__ short sP[2][16 * 136];
  int w = threadIdx.x >> 6, lane = threadIdx.x & 63;
  int nb = blockIdx.x * 32 + w * 16;
  const short* UITB = (nb < NUSERS) ? UITBu : UITBi;
  const short* UIB  = (nb < NUSERS) ? UIBu  : UIBi;
  float* rowZ = sZ[w];
  short* rowP = sP[w];
  int quad = lane >> 4, mrow = lane & 15;

  // ---- hoisted phase-1 row load + bf16 convert (overlaps gather latency) ----
  const float* vrow = ecur + (((long long)(nb + mrow)) << 6) + quad * 8;
  float4 va0 = *(const float4*)(vrow);
  float4 va1 = *(const float4*)(vrow + 4);
  float4 vc0 = *(const float4*)(vrow + 32);
  float4 vc1 = *(const float4*)(vrow + 36);
  short8 a0 = { f2bf(va0.x), f2bf(va0.y), f2bf(va0.z), f2bf(va0.w),
                f2bf(va1.x), f2bf(va1.y), f2bf(va1.z), f2bf(va1.w) };
  short8 a1 = { f2bf(vc0.x), f2bf(vc0.y), f2bf(vc0.z), f2bf(vc0.w),
                f2bf(vc1.x), f2bf(vc1.y), f2bf(vc1.z), f2bf(vc1.w) };

  // ---- gather: gnn rows -> sZ, single 16-node prefetch batch + wave-level fused bodies ----
  {
    int ofs[16], cns[16];
    float dn[16];
    int mi[16]; float mw[16];
    int cmax = 0;
#pragma unroll
    for (int m = 0; m < 16; m++) {
      ofs[m] = __builtin_amdgcn_readfirstlane(off[nb + m]);
      cns[m] = __builtin_amdgcn_readfirstlane(cnt[nb + m]);
      dn[m]  = bcastf(dinv[nb + m]);
      cmax = cns[m] > cmax ? cns[m] : cmax;
    }
#pragma unroll
    for (int m = 0; m < 16; m++)
      mi[m] = (lane < cns[m]) ? adj[ofs[m] + lane] : 0;
#pragma unroll
    for (int m = 0; m < 16; m++)
      mw[m] = (lane < cns[m]) ? dinv[mi[m]] : 0.0f;

    if (cmax <= 16) {
#pragma unroll
      for (int m = 0; m < 16; m++) {
        float acc = acc8f<16>(ecur, mi[m], mw[m], lane);
        rowZ[m * 68 + lane] = dn[m] * acc;
      }
    } else if (cmax <= 24) {
#pragma unroll
      for (int m = 0; m < 16; m++) {
        float acc = acc8f<24>(ecur, mi[m], mw[m], lane);
        rowZ[m * 68 + lane] = dn[m] * acc;
      }
    } else {
#pragma unroll
      for (int m = 0; m < 16; m++) {
        float acc = gather_node(ecur, adj, ofs[m], cns[m], mi[m], mw[m], dinv, 0, lane);
        rowZ[m * 68 + lane] = dn[m] * acc;
      }
    }
  }

  // ---- phase 1: S = v @ UI ; P = exp(S) -> sP (bf16) ; den per node ----
  float den0 = 0.f, den1 = 0.f, den2 = 0.f, den3 = 0.f;
  short* pw = rowP + (quad * 4) * 136 + mrow;
#pragma unroll
  for (int jt = 0; jt < 8; jt++) {
    const short* wr = UITB + ((jt * 16 + mrow) << 6) + quad * 8;
    short8 b0 = *(const short8*)(wr);
    short8 bh = *(const short8*)(wr + 32);
    f32x4 acc = {0.f, 0.f, 0.f, 0.f};
    acc = __builtin_amdgcn_mfma_f32_16x16x32_bf16(a0, b0, acc, 0, 0, 0);
    acc = __builtin_amdgcn_mfma_f32_16x16x32_bf16(a1, bh, acc, 0, 0, 0);
    float e0 = __expf(acc[0]), e1 = __expf(acc[1]);
    float e2 = __expf(acc[2]), e3 = __expf(acc[3]);
    den0 += e0; den1 += e1; den2 += e2; den3 += e3;
    short* pj = pw + jt * 16;
    pj[0] = f2bf(e0); pj[136] = f2bf(e1); pj[272] = f2bf(e2); pj[408] = f2bf(e3);
  }
  for (int mask = 1; mask <= 8; mask <<= 1) {
    den0 += __shfl_xor(den0, mask); den1 += __shfl_xor(den1, mask);
    den2 += __shfl_xor(den2, mask); den3 += __shfl_xor(den3, mask);
  }
  float rd0 = 1.f / den0, rd1 = 1.f / den1, rd2 = 1.f / den2, rd3 = 1.f / den3;

  // ---- phase 2: O = P @ UI^T (K=128) ; combine + store ----
#pragma unroll
  for (int dt = 0; dt < 4; dt++) {
    f32x4 acc = {0.f, 0.f, 0.f, 0.f};
#pragma unroll
    for (int c = 0; c < 4; c++) {
      const short* pr = rowP + mrow * 136 + c * 32 + quad * 8;
      short8 af = *(const short8*)(pr);
      const short* br = UIB + ((dt * 16 + mrow) << 7) + c * 32 + quad * 8;
      short8 bf = *(const short8*)(br);
      acc = __builtin_amdgcn_mfma_f32_16x16x32_bf16(af, bf, acc, 0, 0, 0);
    }
    int d = dt * 16 + mrow;
#define COMB(r, rd)                                                            \
    { int node = nb + quad * 4 + r;                                            \
      long long base = (((long long)node) << 6) + d;                           \
      float o = acc[r] * rd;                                                   \
      float gn = rowZ[(quad * 4 + r) * 68 + d];                                \
      float vv = ecur[base];                                                   \
      float ne = gn + o + vv;                                                  \
      enext[base] = ne;                                                        \
      total[base] = (layer == 0) ? (vv + ne) : (total[base] + ne); }
    COMB(0, rd0) COMB(1, rd1) COMB(2, rd2) COMB(3, rd3)
#undef COMB
  }
}

// ---------------- fused metapath: graphconv gather + MFMA MLP score ----------------
// R10: merges k_mp_gather + k_mp_mlp. Block = 2 waves; wave = one 16-node strip.
// Gather z rows via the k_layer-proven readlane wave-fused form (deg ~ Poisson(5):
// all-16 <= 8: 32% of waves, <= 16: ~99.9%, per-node fallback ~0.1%) into LDS AND
// global zb (h2out needs indexed rows), then run the MLP MFMA straight from LDS —
// eliminates mp_mlp's 102 MB z re-read + one launch. Same-wave LDS: no syncthreads.
__global__ __launch_bounds__(128, 4) void k_mp_fused(
    const float* __restrict__ uf, const float* __restrict__ itf,
    const int* __restrict__ adj, const int* __restrict__ off, const int* __restrict__ cnt,
    const float* __restrict__ oinv, const float* __restrict__ iinv,
    float* __restrict__ zu, float* __restrict__ zi,
    const short* __restrict__ W1Bu, const float* __restrict__ b1u, const float* __restrict__ w2u,
    const short* __restrict__ W1Bi, const float* __restrict__ b1i, const float* __restrict__ w2i,
    float* __restrict__ partials) {
  __shared__ float sZ[2][16 * 68];
  int g = blockIdx.y;
  const float* feat = (g < 2) ? uf : itf;
  float* zb = (g < 2) ? zu + ((long long)g * NUSERS << 6)
                      : zi + ((long long)(g - 2) * NUSERS << 6);
  const short* W1B = (g < 2) ? W1Bu : W1Bi;
  const float* b1  = (g < 2) ? b1u : b1i;
  const float* w2  = (g < 2) ? w2u : w2i;
  int w = threadIdx.x >> 6, lane = threadIdx.x & 63;
  int strip = blockIdx.x * 2 + w;
  int nb = strip * 16;
  int gofs = g * NUSERS;
  float* rowZ = sZ[w];

  // ---- gather: z rows -> LDS + global, 16-node prefetch + wave-level fused bodies ----
  {
    int ofs[16], cns[16];
    float dn[16];
    int mi[16]; float mw[16];
    int cmax = 0;
#pragma unroll
    for (int m = 0; m < 16; m++) {
      int node = NNODES + gofs + nb + m;
      ofs[m] = __builtin_amdgcn_readfirstlane(off[node]);
      cns[m] = __builtin_amdgcn_readfirstlane(cnt[node]);
      dn[m]  = bcastf(iinv[gofs + nb + m]);
      cmax = cns[m] > cmax ? cns[m] : cmax;
    }
#pragma unroll
    for (int m = 0; m < 16; m++)
      mi[m] = (lane < cns[m]) ? adj[ofs[m] + lane] : 0;
#pragma unroll
    for (int m = 0; m < 16; m++)
      mw[m] = (lane < cns[m]) ? oinv[gofs + mi[m]] : 0.0f;

    if (cmax <= 8) {
#pragma unroll
      for (int m = 0; m < 16; m++) {
        float zv = dn[m] * acc8f<8>(feat, mi[m], mw[m], lane);
        rowZ[m * 68 + lane] = zv;
        zb[((long long)(nb + m) << 6) + lane] = zv;
      }
    } else if (cmax <= 16) {
#pragma unroll
      for (int m = 0; m < 16; m++) {
        float zv = dn[m] * acc8f<16>(feat, mi[m], mw[m], lane);
        rowZ[m * 68 + lane] = zv;
        zb[((long long)(nb + m) << 6) + lane] = zv;
      }
    } else {
#pragma unroll
      for (int m = 0; m < 16; m++) {
        float zv = dn[m] * gather_node(feat, adj, ofs[m], cns[m], mi[m], mw[m],
                                       oinv, gofs, lane);
        rowZ[m * 68 + lane] = zv;
        zb[((long long)(nb + m) << 6) + lane] = zv;
      }
    }
  }

  // ---- MLP score from LDS (same math as old k_mp_mlp) ----
  int quad = lane >> 4, mrow = lane & 15;
  const float* zrow = rowZ + mrow * 68 + quad * 8;
  short8 a0 = { f2bf(zrow[0]), f2bf(zrow[1]), f2bf(zrow[2]), f2bf(zrow[3]),
                f2bf(zrow[4]), f2bf(zrow[5]), f2bf(zrow[6]), f2bf(zrow[7]) };
  short8 a1 = { f2bf(zrow[32]), f2bf(zrow[33]), f2bf(zrow[34]), f2bf(zrow[35]),
                f2bf(zrow[36]), f2bf(zrow[37]), f2bf(zrow[38]), f2bf(zrow[39]) };
  float psum = 0.0f;
#pragma unroll
  for (int jt = 0; jt < 8; jt++) {
    const short* wr = W1B + ((jt * 16 + mrow) << 6) + quad * 8;
    short8 b0 = *(const short8*)(wr);
    short8 bh = *(const short8*)(wr + 32);
    f32x4 acc = {0.f, 0.f, 0.f, 0.f};
    acc = __builtin_amdgcn_mfma_f32_16x16x32_bf16(a0, b0, acc, 0, 0, 0);
    acc = __builtin_amdgcn_mfma_f32_16x16x32_bf16(a1, bh, acc, 0, 0, 0);
    int j = jt * 16 + mrow;
    float bj = b1[j], wj = w2[j];
#pragma unroll
    for (int r = 0; r < 4; r++) {
      float s = acc[r] + bj;
      psum += wj * (1.0f - 2.0f / (__expf(2.0f * s) + 1.0f));
    }
  }
  for (int m = 32; m; m >>= 1) psum += __shfl_xor(psum, m);
  if (lane == 0) partials[g * NSTRIP + strip] = psum;
}

__global__ void k_beta(const float* __restrict__ partials, float* __restrict__ wsum) {
  int g = blockIdx.x;
  float s = 0.0f;
  for (int i = threadIdx.x; i < NSTRIP; i += 256) s += partials[g * NSTRIP + i];
  for (int m = 32; m; m >>= 1) s += __shfl_xor(s, m);
  __shared__ float r[4];
  if ((threadIdx.x & 63) == 0) r[threadIdx.x >> 6] = s;
  __syncthreads();
  if (threadIdx.x == 0) wsum[g] = r[0] + r[1] + r[2] + r[3];
}

// ---------------- gather outputs + ssl embedding prep (z precomputed) ----------------
// e1/e2 stored as bf16 for the MFMA similarity GEMM.
__global__ __launch_bounds__(256) void k_h2out(
    const float* __restrict__ zu, const float* __restrict__ zi,
    const int* __restrict__ user_idx, const int* __restrict__ item_idx, const int* __restrict__ neg_idx,
    const float* __restrict__ total,
    const float* __restrict__ wsum, float* __restrict__ out,
    short* __restrict__ e1u, short* __restrict__ e2u,
    short* __restrict__ e1i, short* __restrict__ e2i, float* __restrict__ pos) {
  int lane = threadIdx.x & 63;
  int row = (blockIdx.x << 2) + (threadIdx.x >> 6);
  int seg = row >> 12;
  int r = row & 4095;
  int idx;
  const float* zb;
  int gbase;
  if (seg == 0)      { idx = user_idx[r]; zb = zu; gbase = 0; }
  else if (seg == 1) { idx = item_idx[r]; zb = zi; gbase = 2; }
  else               { idx = neg_idx[r];  zb = zi; gbase = 2; }
  int tnode = gbase ? (NUSERS + idx) : idx;
  float t = total[((long long)tnode << 6) + lane];
  float w0 = wsum[gbase] * (1.0f / 100000.0f);
  float w1 = wsum[gbase + 1] * (1.0f / 100000.0f);
  float mb = fmaxf(w0, w1);
  float b0 = expf(w0 - mb), b1 = expf(w1 - mb);
  float bs = b0 + b1;
  b0 /= bs; b1 /= bs;
  float z0 = zb[((long long)idx << 6) + lane];
  float z1 = zb[(((long long)NUSERS + idx) << 6) + lane];
  float h2 = b0 * z0 + b1 * z1;
  out[((long long)row << 6) + lane] = 0.5f * t + 0.5f * h2;
  if (seg < 2) {
    float n1 = h2 * h2, n2 = t * t;
    for (int m = 32; m; m >>= 1) { n1 += __shfl_xor(n1, m); n2 += __shfl_xor(n2, m); }
    n1 = sqrtf(n1); n2 = sqrtf(n2);
    float a = h2 / n1, b = t / n2;
    float d = a * b;
    for (int m = 32; m; m >>= 1) d += __shfl_xor(d, m);
    short* e1 = seg ? e1i : e1u;
    short* e2 = seg ? e2i : e2u;
    e1[((long long)r << 6) + lane] = f2bf(a);
    e2[((long long)r << 6) + lane] = f2bf(b);
    if (lane == 0) pos[seg * BB + r] = 2.0f * d;
  }
}

// ---------------- ssl similarity via MFMA: wave = 64 rows x 64 cols of S ----------------
__global__ __launch_bounds__(256) void k_gemm(const short* __restrict__ e1u, const short* __restrict__ e2u,
                                              const short* __restrict__ e1i, const short* __restrict__ e2i,
                                              float* __restrict__ sumexp) {
  int side = blockIdx.z;
  const short* A = side ? e1i : e1u;
  const short* B = side ? e2i : e2u;
  int w = threadIdx.x >> 6, lane = threadIdx.x & 63;
  int quad = lane >> 4, mrow = lane & 15;
  int rbase = blockIdx.y * 64;
  int cbase = blockIdx.x * 256 + w * 64;

  short8 a0[4], a1[4], b0[4], b1[4];
#pragma unroll
  for (int ri = 0; ri < 4; ri++) {
    const short* ar = A + ((long long)(rbase + ri * 16 + mrow) << 6) + quad * 8;
    a0[ri] = *(const short8*)ar;
    a1[ri] = *(const short8*)(ar + 32);
  }
#pragma unroll
  for (int ci = 0; ci < 4; ci++) {
    const short* br = B + ((long long)(cbase + ci * 16 + mrow) << 6) + quad * 8;
    b0[ci] = *(const short8*)br;
    b1[ci] = *(const short8*)(br + 32);
  }
  float rs0[4] = {0.f, 0.f, 0.f, 0.f};
  float rs1[4] = {0.f, 0.f, 0.f, 0.f};
  float rs2[4] = {0.f, 0.f, 0.f, 0.f};
  float rs3[4] = {0.f, 0.f, 0.f, 0.f};
#pragma unroll
  for (int ri = 0; ri < 4; ri++) {
#pragma unroll
    for (int ci = 0; ci < 4; ci++) {
      f32x4 acc = {0.f, 0.f, 0.f, 0.f};
      acc = __builtin_amdgcn_mfma_f32_16x16x32_bf16(a0[ri], b0[ci], acc, 0, 0, 0);
      acc = __builtin_amdgcn_mfma_f32_16x16x32_bf16(a1[ri], b1[ci], acc, 0, 0, 0);
      float e0 = __expf(2.0f * acc[0]);
      float e1 = __expf(2.0f * acc[1]);
      float e2 = __expf(2.0f * acc[2]);
      float e3 = __expf(2.0f * acc[3]);
      if (ri == 0) { rs0[0] += e0; rs0[1] += e1; rs0[2] += e2; rs0[3] += e3; }
      if (ri == 1) { rs1[0] += e0; rs1[1] += e1; rs1[2] += e2; rs1[3] += e3; }
      if (ri == 2) { rs2[0] += e0; rs2[1] += e1; rs2[2] += e2; rs2[3] += e3; }
      if (ri == 3) { rs3[0] += e0; rs3[1] += e1; rs3[2] += e2; rs3[3] += e3; }
    }
  }
#pragma unroll
  for (int mask = 1; mask <= 8; mask <<= 1) {
#pragma unroll
    for (int r = 0; r < 4; r++) {
      rs0[r] += __shfl_xor(rs0[r], mask);
      rs1[r] += __shfl_xor(rs1[r], mask);
      rs2[r] += __shfl_xor(rs2[r], mask);
      rs3[r] += __shfl_xor(rs3[r], mask);
    }
  }
  if (mrow == 0) {
    float* sb = sumexp + side * BB + rbase + quad * 4;
#pragma unroll
    for (int r = 0; r < 4; r++) {
      __hip_atomic_fetch_add(&sb[r], rs0[r], __ATOMIC_RELAXED, __HIP_MEMORY_SCOPE_AGENT);
      __hip_atomic_fetch_add(&sb[16 + r], rs1[r], __ATOMIC_RELAXED, __HIP_MEMORY_SCOPE_AGENT);
      __hip_atomic_fetch_add(&sb[32 + r], rs2[r], __ATOMIC_RELAXED, __HIP_MEMORY_SCOPE_AGENT);
      __hip_atomic_fetch_add(&sb[48 + r], rs3[r], __ATOMIC_RELAXED, __HIP_MEMORY_SCOPE_AGENT);
    }
  }
}

__global__ void k_loss(const float* __restrict__ sumexp, const float* __restrict__ pos,
                       float* __restrict__ out) {
  float s = 0.0f;
  for (int i = threadIdx.x; i < 2 * BB; i += 256) s += logf(sumexp[i]) - pos[i];
  for (int m = 32; m; m >>= 1) s += __shfl_xor(s, m);
  __shared__ float r[4];
  if ((threadIdx.x & 63) == 0) r[threadIdx.x >> 6] = s;
  __syncthreads();
  if (threadIdx.x == 0) out[3 * BB * DD] = (r[0] + r[1] + r[2] + r[3]) * (1.0f / (float)BB);
}

// ---------------- launch ----------------
extern "C" void kernel_launch(void* const* d_in, const int* in_sizes, int n_in,
                              void* d_out, int out_size, void* d_ws, size_t ws_size,
                              hipStream_t stream) {
  const float* uf  = (const float*)d_in[0];
  const float* itf = (const float*)d_in[1];
  const float* UIu = (const float*)d_in[2];
  const float* UIi = (const float*)d_in[3];
  const float* W1u = (const float*)d_in[4];
  const float* b1u = (const float*)d_in[5];
  const float* w2u = (const float*)d_in[6];
  const float* W1i = (const float*)d_in[7];
  const float* b1i = (const float*)d_in[8];
  const float* w2i = (const float*)d_in[9];
  const int* ui_src   = (const int*)d_in[10];
  const int* ui_dst   = (const int*)d_in[11];
  const int* mpu      = (const int*)d_in[12];
  const int* mpi      = (const int*)d_in[13];
  const int* user_idx = (const int*)d_in[14];
  const int* item_idx = (const int*)d_in[15];
  const int* neg_idx  = (const int*)d_in[16];
  float* out = (float*)d_out;

  float* wf = (float*)d_ws;
  int*   wi = (int*)d_ws;

  int*   cnt      = wi + O_CNT;
  int*   outcnt   = wi + O_OUTCNT;
  int*   cursor   = wi + O_CURSOR;
  float* partials = wf + O_PARTIALS;
  short* UITBu    = (short*)(wf + O_UITB_U);
  short* UITBi    = (short*)(wf + O_UITB_I);
  short* UIBu     = (short*)(wf + O_UIB_U);
  short* UIBi     = (short*)(wf + O_UIB_I);
  short* W1Bu     = (short*)(wf + O_W1B_U);
  short* W1Bi     = (short*)(wf + O_W1B_I);
  float* sumexp   = wf + O_SUMEXP;
  float* pos      = wf + O_POS;
  int*   off      = wi + O_OFF;
  int*   bsum     = wi + O_BSUM;
  float* dinv     = wf + O_DINV;
  float* oinv     = wf + O_OINV;
  float* iinv     = wf + O_IINV;
  int*   adj      = wi + O_ADJ;
  float* wsum     = wf + O_WSUM;
  float* emba     = wf + O_EMBA;
  float* total    = wf + O_TOTAL;
  float* embb     = wf + O_EMBB;
  short* e1u      = (short*)(wf + O_E1U);
  short* e2u      = (short*)(wf + O_E2U);
  short* e1i      = (short*)(wf + O_E1I);
  short* e2i      = (short*)(wf + O_E2I);

  hipMemsetAsync(d_ws, 0, (size_t)ZEND * 4, stream);

  k_hist_main<<<(E_UI + 255) / 256, 256, 0, stream>>>(ui_src, ui_dst, cnt);
  k_hist_mp<<<dim3((E_MP + 255) / 256, 4), 256, 0, stream>>>(mpu, mpi, cnt, outcnt);

  const int NSCAN = 600000;
  const int NB = (NSCAN + 1023) / 1024;
  k_scan1<<<NB, 1024, 0, stream>>>(cnt, off, bsum, NSCAN);
  k_scan2<<<1, 1024, 0, stream>>>(bsum, NB);
  k_scan3<<<NB, 1024, 0, stream>>>(off, bsum, NSCAN);

  k_inv<<<(600000 + 255) / 256, 256, 0, stream>>>(cnt, outcnt, dinv, iinv, oinv);

  k_scatter_main<<<(E_UI + 255) / 256, 256, 0, stream>>>(ui_src, ui_dst, off, cursor, adj);
  k_scatter_mp<<<dim3((E_MP + 255) / 256, 4), 256, 0, stream>>>(mpu, mpi, off, cursor, adj);

  k_init<<<(3200000 + 255) / 256, 256, 0, stream>>>((const float4*)uf, (const float4*)itf,
                                                    (float4*)emba);
  k_tw<<<32, 256, 0, stream>>>(UIu, UIi, W1u, W1i, UITBu, UITBi, UIBu, UIBi, W1Bu, W1Bi);

  // fused layers (spmm + MFMA attention + residual + total), 2-wave blocks
  k_layer<<<6250, 128, 0, stream>>>(emba, embb, total, adj, off, cnt, dinv,
                                    UITBu, UITBi, UIBu, UIBi, 0);
  k_layer<<<6250, 128, 0, stream>>>(embb, emba, total, adj, off, cnt, dinv,
                                    UITBu, UITBi, UIBu, UIBi, 1);

  // fused metapath: gather z (-> emba/embb) + MFMA MLP score in one pass
  k_mp_fused<<<dim3(3125, 4), 128, 0, stream>>>(uf, itf, adj, off, cnt, oinv, iinv,
                                                emba, embb,
                                                W1Bu, b1u, w2u, W1Bi, b1i, w2i, partials);
  k_beta<<<4, 256, 0, stream>>>(partials, wsum);

  k_h2out<<<3072, 256, 0, stream>>>(emba, embb, user_idx, item_idx, neg_idx, total,
                                    wsum, out, e1u, e2u, e1i, e2i, pos);

  k_gemm<<<dim3(16, 64, 2), 256, 0, stream>>>(e1u, e2u, e1i, e2i, sumexp);
  k_loss<<<1, 256, 0, stream>>>(sumexp, pos, out);
}